// Round 2
// baseline (1798.820 us; speedup 1.0000x reference)
//
#include <hip/hip_runtime.h>
#include <hip/hip_bf16.h>
#include <math.h>

#define L_SEQ 4096
#define BATCH 2
#define DIM   96
#define DI    192
#define DS    16
#define HID   192
#define NPOS  (BATCH * L_SEQ)   // 8192

__device__ __forceinline__ float silu_f(float x) { return x / (1.f + __expf(-x)); }

// ---------------------------------------------------------------------------
// K1: double layernorm over channel dim. x (B,96,L) f32 -> X1 (B,96,L) f32,
// XN (B*L, 96) f32 channel-last.
// ---------------------------------------------------------------------------
__global__ void k_ln12(const float* __restrict__ x,
                       const float* __restrict__ ln1w, const float* __restrict__ ln1b,
                       const float* __restrict__ mnw,  const float* __restrict__ mnb,
                       float* __restrict__ X1, float* __restrict__ XN) {
    int p = blockIdx.x * blockDim.x + threadIdx.x;   // 0..NPOS-1
    if (p >= NPOS) return;
    int b = p >> 12, l = p & (L_SEQ - 1);
    const float* xb = x + (size_t)b * DIM * L_SEQ + l;
    float s = 0.f, ss = 0.f;
    for (int c = 0; c < DIM; c++) { float v = xb[(size_t)c * L_SEQ]; s += v; ss += v * v; }
    float u = s / DIM;
    float r = rsqrtf(ss / DIM - u * u + 1e-6f);
    float s2 = 0.f, ss2 = 0.f;
    for (int c = 0; c < DIM; c++) {
        float v = xb[(size_t)c * L_SEQ];
        float t = ln1w[c] * (v - u) * r + ln1b[c];
        X1[((size_t)b * DIM + c) * L_SEQ + l] = t;
        s2 += t; ss2 += t * t;
    }
    float u2 = s2 / DIM;
    float r2 = rsqrtf(ss2 / DIM - u2 * u2 + 1e-5f);
    float* xnp = XN + (size_t)p * DIM;
    for (int c = 0; c < DIM; c++) {
        float t = X1[((size_t)b * DIM + c) * L_SEQ + l];
        xnp[c] = (t - u2) * r2 * mnw[c] + mnb[c];
    }
}

// ---------------------------------------------------------------------------
// GEMM NT: C[M,N] = (A1 (+A2))[M,K] @ W[N,K]^T.  all f32.
// M multiple of 64, K multiple of 32, N guarded.
// ---------------------------------------------------------------------------
__global__ void gemm_nt(const float* __restrict__ A1, const float* __restrict__ A2,
                        const float* __restrict__ W, float* __restrict__ C,
                        int M, int N, int K) {
    __shared__ float As[32][65];
    __shared__ float Bs[32][65];
    int m0 = blockIdx.x * 64, n0 = blockIdx.y * 64;
    int t = threadIdx.x;
    int tx = t & 15, ty = t >> 4;
    int lrow = t >> 2;          // 0..63
    int lk = (t & 3) * 8;       // 0,8,16,24
    float acc[4][4] = {};
    for (int k0 = 0; k0 < K; k0 += 32) {
        // A tile
        {
            const float* ap = A1 + (size_t)(m0 + lrow) * K + k0 + lk;
            float v[8];
#pragma unroll
            for (int j = 0; j < 8; j++) v[j] = ap[j];
            if (A2) {
                const float* ap2 = A2 + (size_t)(m0 + lrow) * K + k0 + lk;
#pragma unroll
                for (int j = 0; j < 8; j++) v[j] += ap2[j];
            }
#pragma unroll
            for (int j = 0; j < 8; j++) As[lk + j][lrow] = v[j];
        }
        // W tile (transposed into Bs[k][n])
        {
            int n = n0 + lrow;
            float v[8];
            if (n < N) {
                const float* wp = W + (size_t)n * K + k0 + lk;
#pragma unroll
                for (int j = 0; j < 8; j++) v[j] = wp[j];
            } else {
#pragma unroll
                for (int j = 0; j < 8; j++) v[j] = 0.f;
            }
#pragma unroll
            for (int j = 0; j < 8; j++) Bs[lk + j][lrow] = v[j];
        }
        __syncthreads();
#pragma unroll
        for (int k = 0; k < 32; k++) {
            float a[4], bb[4];
#pragma unroll
            for (int i = 0; i < 4; i++) a[i] = As[k][ty * 4 + i];
#pragma unroll
            for (int j = 0; j < 4; j++) bb[j] = Bs[k][tx * 4 + j];
#pragma unroll
            for (int i = 0; i < 4; i++)
#pragma unroll
                for (int j = 0; j < 4; j++) acc[i][j] += a[i] * bb[j];
        }
        __syncthreads();
    }
#pragma unroll
    for (int i = 0; i < 4; i++) {
        int m = m0 + ty * 4 + i;
#pragma unroll
        for (int j = 0; j < 4; j++) {
            int n = n0 + tx * 4 + j;
            if (n < N) C[(size_t)m * N + n] = acc[i][j];
        }
    }
}

// ---------------------------------------------------------------------------
// GEMM NN (batched): C[b][M,N] = W[M,K] @ Bmat[b][K,N].  all f32.
// N multiple of 64, K multiple of 32, M guarded.
// ---------------------------------------------------------------------------
__global__ void gemm_nn(const float* __restrict__ W, const float* __restrict__ Bm,
                        float* __restrict__ C, int M, int N, int K,
                        size_t strideB, size_t strideC) {
    __shared__ float As[32][65];
    __shared__ float Bs[32][65];
    int m0 = blockIdx.x * 64, n0 = blockIdx.y * 64;
    const float* Bp = Bm + strideB * blockIdx.z;
    float* Cp = C + strideC * blockIdx.z;
    int t = threadIdx.x;
    int tx = t & 15, ty = t >> 4;
    int lrow = t >> 2, lk = (t & 3) * 8;     // W load
    int bk = t >> 3, bn = (t & 7) * 8;       // B load
    float acc[4][4] = {};
    for (int k0 = 0; k0 < K; k0 += 32) {
        {
            int m = m0 + lrow;
            float v[8];
            if (m < M) {
                const float* wp = W + (size_t)m * K + k0 + lk;
#pragma unroll
                for (int j = 0; j < 8; j++) v[j] = wp[j];
            } else {
#pragma unroll
                for (int j = 0; j < 8; j++) v[j] = 0.f;
            }
#pragma unroll
            for (int j = 0; j < 8; j++) As[lk + j][lrow] = v[j];
        }
        {
            const float* bp = Bp + (size_t)(k0 + bk) * N + n0 + bn;
#pragma unroll
            for (int j = 0; j < 8; j++) Bs[bk][bn + j] = bp[j];
        }
        __syncthreads();
#pragma unroll
        for (int k = 0; k < 32; k++) {
            float a[4], bb[4];
#pragma unroll
            for (int i = 0; i < 4; i++) a[i] = As[k][ty * 4 + i];
#pragma unroll
            for (int j = 0; j < 4; j++) bb[j] = Bs[k][tx * 4 + j];
#pragma unroll
            for (int i = 0; i < 4; i++)
#pragma unroll
                for (int j = 0; j < 4; j++) acc[i][j] += a[i] * bb[j];
        }
        __syncthreads();
    }
#pragma unroll
    for (int i = 0; i < 4; i++) {
        int m = m0 + ty * 4 + i;
        if (m < M) {
#pragma unroll
            for (int j = 0; j < 4; j++) Cp[(size_t)m * N + n0 + tx * 4 + j] = acc[i][j];
        }
    }
}

// ---------------------------------------------------------------------------
// K3: causal (dir=0) / anti-causal (dir=1) depthwise conv1d k=4 + bias + silu.
// XZ (NPOS,384) -> XS (NPOS,192)
// ---------------------------------------------------------------------------
__global__ void k_conv(const float* __restrict__ XZ, const float* __restrict__ convw,
                       const float* __restrict__ convb, float* __restrict__ XS, int dirb) {
    int i = blockIdx.x * blockDim.x + threadIdx.x;   // NPOS*DI
    int d = i % DI;
    int p = i / DI;
    int b = p >> 12, l = p & (L_SEQ - 1);
    float acc = convb[d];
    if (!dirb) {
#pragma unroll
        for (int k = 0; k < 4; k++) {
            int ls = l - 3 + k;
            if (ls >= 0) acc += convw[d * 4 + k] * XZ[((size_t)(b * L_SEQ + ls)) * 384 + d];
        }
    } else {
#pragma unroll
        for (int k = 0; k < 4; k++) {
            int ls = l + 3 - k;
            if (ls < L_SEQ) acc += convw[d * 4 + k] * XZ[((size_t)(b * L_SEQ + ls)) * 384 + d];
        }
    }
    XS[(size_t)p * DI + d] = silu_f(acc);
}

// ---------------------------------------------------------------------------
// K5: delta = softplus(dt @ Wdt^T + bdt).  DBL (NPOS,38) -> DEL (NPOS,192)
// ---------------------------------------------------------------------------
__global__ void k_delta(const float* __restrict__ DBL, const float* __restrict__ Wdt,
                        const float* __restrict__ bdt, float* __restrict__ DEL) {
    int i = blockIdx.x * blockDim.x + threadIdx.x;   // NPOS*DI
    int d = i % DI;
    int p = i / DI;
    const float* dp = DBL + (size_t)p * 38;
    float acc = bdt[d];
#pragma unroll
    for (int r = 0; r < 6; r++) acc += dp[r] * Wdt[d * 6 + r];
    float sp = (acc > 0.f) ? (acc + log1pf(__expf(-acc))) : log1pf(__expf(acc));
    DEL[(size_t)p * DI + d] = sp;
}

// ---------------------------------------------------------------------------
// K6: selective scan, both directions in one launch.
// 16 lanes per (dir,b,d) hold the D_STATE=16 state. Sequential over L.
// Writes Y = (sum_s h*C + xs*Dp) * silu(z).
// ---------------------------------------------------------------------------
__global__ void k_scan(const float* __restrict__ DELF, const float* __restrict__ DELB,
                       const float* __restrict__ DBLF, const float* __restrict__ DBLB,
                       const float* __restrict__ XSF,  const float* __restrict__ XSB,
                       const float* __restrict__ XZF,  const float* __restrict__ XZB,
                       const float* __restrict__ fAlog, const float* __restrict__ bAlog,
                       const float* __restrict__ fD,    const float* __restrict__ bD,
                       float* __restrict__ YSF, float* __restrict__ YSB) {
    int t = blockIdx.x * blockDim.x + threadIdx.x;   // 2*2*192*16 = 12288
    int s = t & 15;
    int g = t >> 4;                                   // 0..767
    int d = g % DI;
    int b = (g / DI) & 1;
    int dir = g / (DI * 2);

    const float* DEL = dir ? DELB : DELF;
    const float* DBL = dir ? DBLB : DBLF;
    const float* XS  = dir ? XSB  : XSF;
    const float* XZ  = dir ? XZB  : XZF;
    const float* Alog = dir ? bAlog : fAlog;
    float Dp = dir ? bD[d] : fD[d];
    float* Y = dir ? YSB : YSF;

    float A = -__expf(Alog[d * DS + s]);
    float h = 0.f;
    int l = dir ? (L_SEQ - 1) : 0;
    int step = dir ? -1 : 1;

    size_t p = (size_t)b * L_SEQ + l;
    float del = DEL[p * DI + d];
    float Bmv = DBL[p * 38 + 6 + s];
    float Cmv = DBL[p * 38 + 22 + s];
    float xs  = XS[p * DI + d];
    float z   = XZ[p * 384 + 192 + d];

    for (int it = 0; it < L_SEQ; it++) {
        float del_n = 0.f, Bm_n = 0.f, Cm_n = 0.f, xs_n = 0.f, z_n = 0.f;
        int ln = l + step;
        if (it + 1 < L_SEQ) {
            size_t pn = (size_t)b * L_SEQ + ln;
            del_n = DEL[pn * DI + d];
            Bm_n  = DBL[pn * 38 + 6 + s];
            Cm_n  = DBL[pn * 38 + 22 + s];
            xs_n  = XS[pn * DI + d];
            z_n   = XZ[pn * 384 + 192 + d];
        }
        float dA = __expf(del * A);
        h = dA * h + del * Bmv * xs;
        float pr = h * Cmv;
        pr += __shfl_xor(pr, 1, 64);
        pr += __shfl_xor(pr, 2, 64);
        pr += __shfl_xor(pr, 4, 64);
        pr += __shfl_xor(pr, 8, 64);
        if (s == 0) {
            Y[p * DI + d] = (pr + xs * Dp) * silu_f(z);
        }
        l = ln;
        p = (size_t)b * L_SEQ + l;
        del = del_n; Bmv = Bm_n; Cmv = Cm_n; xs = xs_n; z = z_n;
    }
}

// ---------------------------------------------------------------------------
// K9: x2 = x + gamma1*(yo + x1); store XMID (B,96,L); XM2 = ln_cf(x2) planar.
// ---------------------------------------------------------------------------
__global__ void k_mid(const float* __restrict__ x, const float* __restrict__ YO,
                      const float* __restrict__ X1,
                      const float* __restrict__ gamma1,
                      const float* __restrict__ ln1w, const float* __restrict__ ln1b,
                      float* __restrict__ XMID, float* __restrict__ XM2) {
    int p = blockIdx.x * blockDim.x + threadIdx.x;
    if (p >= NPOS) return;
    int b = p >> 12, l = p & (L_SEQ - 1);
    const float* yop = YO + (size_t)p * DIM;
    float s = 0.f, ss = 0.f;
    for (int c = 0; c < DIM; c++) {
        size_t idx = ((size_t)b * DIM + c) * L_SEQ + l;
        float v = x[idx] + gamma1[c] * (yop[c] + X1[idx]);
        XMID[idx] = v;
        s += v; ss += v * v;
    }
    float u = s / DIM;
    float r = rsqrtf(ss / DIM - u * u + 1e-6f);
    for (int c = 0; c < DIM; c++) {
        size_t idx = ((size_t)b * DIM + c) * L_SEQ + l;
        float v = XMID[idx];
        XM2[idx] = ln1w[c] * (v - u) * r + ln1b[c];
    }
}

// ---------------------------------------------------------------------------
// K11: fused 3x dilated depthwise 3x3 conv + GELU gate.
// H5 (B,576,64,64) -> G (B,192,64,64);  g = gelu(h1)*h2*h3
// ---------------------------------------------------------------------------
__global__ void k_msff(const float* __restrict__ H5,
                       const float* __restrict__ dw1, const float* __restrict__ dw2,
                       const float* __restrict__ dw3, float* __restrict__ G) {
    int i = blockIdx.x * blockDim.x + threadIdx.x;   // B*HID*4096
    int l = i & (L_SEQ - 1);
    int tmp = i >> 12;
    int c = tmp % HID;
    int b = tmp / HID;
    int y = l >> 6, xc = l & 63;
    const float* p1 = H5 + ((size_t)b * 576 + c) * L_SEQ;
    const float* p2 = H5 + ((size_t)b * 576 + HID + c) * L_SEQ;
    const float* p3 = H5 + ((size_t)b * 576 + 2 * HID + c) * L_SEQ;
    float a1 = 0.f, a2 = 0.f, a3 = 0.f;
#pragma unroll
    for (int ky = 0; ky < 3; ky++) {
#pragma unroll
        for (int kx = 0; kx < 3; kx++) {
            float w1 = dw1[(c * 3 + ky) * 3 + kx];
            float w2 = dw2[(c * 3 + ky) * 3 + kx];
            float w3 = dw3[(c * 3 + ky) * 3 + kx];
            int y1 = y + (ky - 1), x1 = xc + (kx - 1);
            if (y1 >= 0 && y1 < 64 && x1 >= 0 && x1 < 64) a1 += w1 * p1[y1 * 64 + x1];
            int y2 = y + (ky - 1) * 2, x2 = xc + (kx - 1) * 2;
            if (y2 >= 0 && y2 < 64 && x2 >= 0 && x2 < 64) a2 += w2 * p2[y2 * 64 + x2];
            int y3 = y + (ky - 1) * 3, x3 = xc + (kx - 1) * 3;
            if (y3 >= 0 && y3 < 64 && x3 >= 0 && x3 < 64) a3 += w3 * p3[y3 * 64 + x3];
        }
    }
    float ge = 0.5f * a1 * (1.f + erff(a1 * 0.70710678118f));
    G[((size_t)b * HID + c) * L_SEQ + l] = ge * a2 * a3;
}

// ---------------------------------------------------------------------------
// K13: out = XMID + gamma2[c] * OXM  (f32 output)
// ---------------------------------------------------------------------------
__global__ void k_out(const float* __restrict__ XMID, const float* __restrict__ OXM,
                      const float* __restrict__ gamma2, float* __restrict__ out) {
    int i = blockIdx.x * blockDim.x + threadIdx.x;   // B*96*4096
    int c = (i >> 12) % DIM;
    out[i] = XMID[i] + gamma2[c] * OXM[i];
}

// ---------------------------------------------------------------------------
extern "C" void kernel_launch(void* const* d_in, const int* in_sizes, int n_in,
                              void* d_out, int out_size, void* d_ws, size_t ws_size,
                              hipStream_t stream) {
    const float* x      = (const float*)d_in[0];
    const float* gamma1 = (const float*)d_in[1];
    const float* gamma2 = (const float*)d_in[2];
    const float* ln1w   = (const float*)d_in[3];
    const float* ln1b   = (const float*)d_in[4];
    const float* mnw    = (const float*)d_in[5];
    const float* mnb    = (const float*)d_in[6];
    const float* fWin   = (const float*)d_in[7];
    const float* fconvw = (const float*)d_in[8];
    const float* fconvb = (const float*)d_in[9];
    const float* fWx    = (const float*)d_in[10];
    const float* fWdt   = (const float*)d_in[11];
    const float* fbdt   = (const float*)d_in[12];
    const float* fAlog  = (const float*)d_in[13];
    const float* fD     = (const float*)d_in[14];
    const float* bWin   = (const float*)d_in[15];
    const float* bconvw = (const float*)d_in[16];
    const float* bconvb = (const float*)d_in[17];
    const float* bWx    = (const float*)d_in[18];
    const float* bWdt   = (const float*)d_in[19];
    const float* bbdt   = (const float*)d_in[20];
    const float* bAlog  = (const float*)d_in[21];
    const float* bD     = (const float*)d_in[22];
    const float* Wout   = (const float*)d_in[23];
    const float* mwin   = (const float*)d_in[24];
    const float* mdw1   = (const float*)d_in[25];
    const float* mdw2   = (const float*)d_in[26];
    const float* mdw3   = (const float*)d_in[27];
    const float* mwout  = (const float*)d_in[28];
    float* out = (float*)d_out;

    float* ws = (float*)d_ws;
    float* XN   = ws;                       // 786432
    float* X1   = XN   + 786432;            // 786432
    float* XZF  = X1   + 786432;            // 3145728
    float* XZB  = XZF  + 3145728;           // 3145728
    float* XSF  = XZB  + 3145728;           // 1572864
    float* XSB  = XSF  + 1572864;           // 1572864
    float* DBLF = XSB  + 1572864;           // 311296
    float* DBLB = DBLF + 311296;            // 311296
    float* DELF = DBLB + 311296;            // 1572864
    float* DELB = DELF + 1572864;           // 1572864
    float* YSF  = DELB + 1572864;           // 1572864
    float* YSB  = YSF  + 1572864;           // 1572864
    // overlays (dead buffers reused; scan consumers XZ/XS/DEL/DBL die at k_scan,
    // YS dies after out-projection, XN dies after in-projections):
    float* YO   = XN;                       // 786432  (XN dead after steps 2-3)
    float* XMID = DELF;                     // 786432  (DEL dead after scan)
    float* XM2  = DELB;                     // 786432
    float* H576 = XZF;                      // 4718592 (spans XZF+XZB, dead after scan)
    float* G    = YSF;                      // 1572864 (YS dead after out-proj)
    float* OXM  = XSF;                      // 786432  (XS dead after scan)

    // 1. double LN
    k_ln12<<<NPOS / 256, 256, 0, stream>>>(x, ln1w, ln1b, mnw, mnb, X1, XN);
    // 2-3. in-projections (both directions, natural order)
    gemm_nt<<<dim3(128, 6), 256, 0, stream>>>(XN, nullptr, fWin, XZF, NPOS, 384, DIM);
    gemm_nt<<<dim3(128, 6), 256, 0, stream>>>(XN, nullptr, bWin, XZB, NPOS, 384, DIM);
    // 4-5. causal / anti-causal dwconv + silu
    k_conv<<<NPOS * DI / 256, 256, 0, stream>>>(XZF, fconvw, fconvb, XSF, 0);
    k_conv<<<NPOS * DI / 256, 256, 0, stream>>>(XZB, bconvw, bconvb, XSB, 1);
    // 6-7. x_dbl projections
    gemm_nt<<<dim3(128, 1), 256, 0, stream>>>(XSF, nullptr, fWx, DBLF, NPOS, 38, DI);
    gemm_nt<<<dim3(128, 1), 256, 0, stream>>>(XSB, nullptr, bWx, DBLB, NPOS, 38, DI);
    // 8-9. delta
    k_delta<<<NPOS * DI / 256, 256, 0, stream>>>(DBLF, fWdt, fbdt, DELF);
    k_delta<<<NPOS * DI / 256, 256, 0, stream>>>(DBLB, bWdt, bbdt, DELB);
    // 10. selective scan (both dirs concurrently) + gating epilogue
    k_scan<<<48, 256, 0, stream>>>(DELF, DELB, DBLF, DBLB, XSF, XSB, XZF, XZB,
                                   fAlog, bAlog, fD, bD, YSF, YSB);
    // 11. out-projection with fused yf+yb add
    gemm_nt<<<dim3(128, 2), 256, 0, stream>>>(YSF, YSB, Wout, YO, NPOS, DIM, DI);
    // 12. residual + LN   (XMID/XM2 overlay DEL buffers — dead after scan)
    k_mid<<<NPOS / 256, 256, 0, stream>>>(x, YO, X1, gamma1, ln1w, ln1b, XMID, XM2);
    // 13. msff in-projection (planar): H576[b] = mwin(576,96) @ XM2[b](96,4096)
    gemm_nn<<<dim3(9, 64, 2), 256, 0, stream>>>(mwin, XM2, H576, 576, L_SEQ, DIM,
                                                (size_t)DIM * L_SEQ, (size_t)576 * L_SEQ);
    // 14. fused dilated dwconvs + GELU gate
    k_msff<<<BATCH * HID * L_SEQ / 256, 256, 0, stream>>>(H576, mdw1, mdw2, mdw3, G);
    // 15. msff out-projection: OXM[b] = mwout(96,192) @ G[b](192,4096)
    gemm_nn<<<dim3(2, 64, 2), 256, 0, stream>>>(mwout, G, OXM, DIM, L_SEQ, HID,
                                                (size_t)HID * L_SEQ, (size_t)DIM * L_SEQ);
    // 16. final residual -> f32 out
    k_out<<<BATCH * DIM * L_SEQ / 256, 256, 0, stream>>>(XMID, OXM, gamma2, out);
}

// Round 3
// 506.445 us; speedup vs baseline: 3.5519x; 3.5519x over previous
//
#include <hip/hip_runtime.h>
#include <hip/hip_bf16.h>
#include <math.h>

#define L_SEQ 4096
#define BATCH 2
#define DIM   96
#define DI    192
#define DS    16
#define HID   192
#define NPOS  (BATCH * L_SEQ)   // 8192
#define NCH   64                // chunks per sequence
#define CHUNK 64                // L_SEQ / NCH
#define NREC  (2 * BATCH * DI)  // 768 recurrences (dir,b,d)

__device__ __forceinline__ float silu_f(float x) { return x / (1.f + __expf(-x)); }

// ---------------------------------------------------------------------------
// K1: double layernorm over channel dim. x (B,96,L) f32 -> X1 (B,96,L) f32,
// XN (B*L, 96) f32 channel-last.
// ---------------------------------------------------------------------------
__global__ void k_ln12(const float* __restrict__ x,
                       const float* __restrict__ ln1w, const float* __restrict__ ln1b,
                       const float* __restrict__ mnw,  const float* __restrict__ mnb,
                       float* __restrict__ X1, float* __restrict__ XN) {
    int p = blockIdx.x * blockDim.x + threadIdx.x;   // 0..NPOS-1
    if (p >= NPOS) return;
    int b = p >> 12, l = p & (L_SEQ - 1);
    const float* xb = x + (size_t)b * DIM * L_SEQ + l;
    float s = 0.f, ss = 0.f;
    for (int c = 0; c < DIM; c++) { float v = xb[(size_t)c * L_SEQ]; s += v; ss += v * v; }
    float u = s / DIM;
    float r = rsqrtf(ss / DIM - u * u + 1e-6f);
    float s2 = 0.f, ss2 = 0.f;
    for (int c = 0; c < DIM; c++) {
        float v = xb[(size_t)c * L_SEQ];
        float t = ln1w[c] * (v - u) * r + ln1b[c];
        X1[((size_t)b * DIM + c) * L_SEQ + l] = t;
        s2 += t; ss2 += t * t;
    }
    float u2 = s2 / DIM;
    float r2 = rsqrtf(ss2 / DIM - u2 * u2 + 1e-5f);
    float* xnp = XN + (size_t)p * DIM;
    for (int c = 0; c < DIM; c++) {
        float t = X1[((size_t)b * DIM + c) * L_SEQ + l];
        xnp[c] = (t - u2) * r2 * mnw[c] + mnb[c];
    }
}

// ---------------------------------------------------------------------------
// GEMM NT: C[M,N] = (A1 (+A2))[M,K] @ W[N,K]^T.  all f32.
// ---------------------------------------------------------------------------
__global__ void gemm_nt(const float* __restrict__ A1, const float* __restrict__ A2,
                        const float* __restrict__ W, float* __restrict__ C,
                        int M, int N, int K) {
    __shared__ float As[32][65];
    __shared__ float Bs[32][65];
    int m0 = blockIdx.x * 64, n0 = blockIdx.y * 64;
    int t = threadIdx.x;
    int tx = t & 15, ty = t >> 4;
    int lrow = t >> 2;          // 0..63
    int lk = (t & 3) * 8;       // 0,8,16,24
    float acc[4][4] = {};
    for (int k0 = 0; k0 < K; k0 += 32) {
        {
            const float* ap = A1 + (size_t)(m0 + lrow) * K + k0 + lk;
            float v[8];
#pragma unroll
            for (int j = 0; j < 8; j++) v[j] = ap[j];
            if (A2) {
                const float* ap2 = A2 + (size_t)(m0 + lrow) * K + k0 + lk;
#pragma unroll
                for (int j = 0; j < 8; j++) v[j] += ap2[j];
            }
#pragma unroll
            for (int j = 0; j < 8; j++) As[lk + j][lrow] = v[j];
        }
        {
            int n = n0 + lrow;
            float v[8];
            if (n < N) {
                const float* wp = W + (size_t)n * K + k0 + lk;
#pragma unroll
                for (int j = 0; j < 8; j++) v[j] = wp[j];
            } else {
#pragma unroll
                for (int j = 0; j < 8; j++) v[j] = 0.f;
            }
#pragma unroll
            for (int j = 0; j < 8; j++) Bs[lk + j][lrow] = v[j];
        }
        __syncthreads();
#pragma unroll
        for (int k = 0; k < 32; k++) {
            float a[4], bb[4];
#pragma unroll
            for (int i = 0; i < 4; i++) a[i] = As[k][ty * 4 + i];
#pragma unroll
            for (int j = 0; j < 4; j++) bb[j] = Bs[k][tx * 4 + j];
#pragma unroll
            for (int i = 0; i < 4; i++)
#pragma unroll
                for (int j = 0; j < 4; j++) acc[i][j] += a[i] * bb[j];
        }
        __syncthreads();
    }
#pragma unroll
    for (int i = 0; i < 4; i++) {
        int m = m0 + ty * 4 + i;
#pragma unroll
        for (int j = 0; j < 4; j++) {
            int n = n0 + tx * 4 + j;
            if (n < N) C[(size_t)m * N + n] = acc[i][j];
        }
    }
}

// ---------------------------------------------------------------------------
// GEMM NN (batched): C[b][M,N] = W[M,K] @ Bmat[b][K,N].  all f32.
// ---------------------------------------------------------------------------
__global__ void gemm_nn(const float* __restrict__ W, const float* __restrict__ Bm,
                        float* __restrict__ C, int M, int N, int K,
                        size_t strideB, size_t strideC) {
    __shared__ float As[32][65];
    __shared__ float Bs[32][65];
    int m0 = blockIdx.x * 64, n0 = blockIdx.y * 64;
    const float* Bp = Bm + strideB * blockIdx.z;
    float* Cp = C + strideC * blockIdx.z;
    int t = threadIdx.x;
    int tx = t & 15, ty = t >> 4;
    int lrow = t >> 2, lk = (t & 3) * 8;     // W load
    int bk = t >> 3, bn = (t & 7) * 8;       // B load
    float acc[4][4] = {};
    for (int k0 = 0; k0 < K; k0 += 32) {
        {
            int m = m0 + lrow;
            float v[8];
            if (m < M) {
                const float* wp = W + (size_t)m * K + k0 + lk;
#pragma unroll
                for (int j = 0; j < 8; j++) v[j] = wp[j];
            } else {
#pragma unroll
                for (int j = 0; j < 8; j++) v[j] = 0.f;
            }
#pragma unroll
            for (int j = 0; j < 8; j++) As[lk + j][lrow] = v[j];
        }
        {
            const float* bp = Bp + (size_t)(k0 + bk) * N + n0 + bn;
#pragma unroll
            for (int j = 0; j < 8; j++) Bs[bk][bn + j] = bp[j];
        }
        __syncthreads();
#pragma unroll
        for (int k = 0; k < 32; k++) {
            float a[4], bb[4];
#pragma unroll
            for (int i = 0; i < 4; i++) a[i] = As[k][ty * 4 + i];
#pragma unroll
            for (int j = 0; j < 4; j++) bb[j] = Bs[k][tx * 4 + j];
#pragma unroll
            for (int i = 0; i < 4; i++)
#pragma unroll
                for (int j = 0; j < 4; j++) acc[i][j] += a[i] * bb[j];
        }
        __syncthreads();
    }
#pragma unroll
    for (int i = 0; i < 4; i++) {
        int m = m0 + ty * 4 + i;
        if (m < M) {
#pragma unroll
            for (int j = 0; j < 4; j++) Cp[(size_t)m * N + n0 + tx * 4 + j] = acc[i][j];
        }
    }
}

// ---------------------------------------------------------------------------
// K3: causal (dir=0) / anti-causal (dir=1) depthwise conv1d k=4 + bias + silu.
// ---------------------------------------------------------------------------
__global__ void k_conv(const float* __restrict__ XZ, const float* __restrict__ convw,
                       const float* __restrict__ convb, float* __restrict__ XS, int dirb) {
    int i = blockIdx.x * blockDim.x + threadIdx.x;   // NPOS*DI
    int d = i % DI;
    int p = i / DI;
    int b = p >> 12, l = p & (L_SEQ - 1);
    float acc = convb[d];
    if (!dirb) {
#pragma unroll
        for (int k = 0; k < 4; k++) {
            int ls = l - 3 + k;
            if (ls >= 0) acc += convw[d * 4 + k] * XZ[((size_t)(b * L_SEQ + ls)) * 384 + d];
        }
    } else {
#pragma unroll
        for (int k = 0; k < 4; k++) {
            int ls = l + 3 - k;
            if (ls < L_SEQ) acc += convw[d * 4 + k] * XZ[((size_t)(b * L_SEQ + ls)) * 384 + d];
        }
    }
    XS[(size_t)p * DI + d] = silu_f(acc);
}

// ---------------------------------------------------------------------------
// K5: delta = softplus(dt @ Wdt^T + bdt).  DBL (NPOS,38) -> DEL (NPOS,192)
// ---------------------------------------------------------------------------
__global__ void k_delta(const float* __restrict__ DBL, const float* __restrict__ Wdt,
                        const float* __restrict__ bdt, float* __restrict__ DEL) {
    int i = blockIdx.x * blockDim.x + threadIdx.x;   // NPOS*DI
    int d = i % DI;
    int p = i / DI;
    const float* dp = DBL + (size_t)p * 38;
    float acc = bdt[d];
#pragma unroll
    for (int r = 0; r < 6; r++) acc += dp[r] * Wdt[d * 6 + r];
    float sp = (acc > 0.f) ? (acc + log1pf(__expf(-acc))) : log1pf(__expf(acc));
    DEL[(size_t)p * DI + d] = sp;
}

// ---------------------------------------------------------------------------
// Chunked parallel scan. Thread map (p1/p3): t = ((rec*NCH + chunk)<<4) | s,
// rec = (dir*2+b)*DI + d. Chunk index counts along the scan direction.
// ---------------------------------------------------------------------------
__global__ void k_scan_p1(const float* __restrict__ DELF, const float* __restrict__ DELB,
                          const float* __restrict__ DBLF, const float* __restrict__ DBLB,
                          const float* __restrict__ XSF,  const float* __restrict__ XSB,
                          const float* __restrict__ fAlog, const float* __restrict__ bAlog,
                          float* __restrict__ P, float* __restrict__ Q) {
    int t = blockIdx.x * blockDim.x + threadIdx.x;   // 786432
    int s = t & 15;
    int gg = t >> 4;                                  // 0..49151
    int chunk = gg & (NCH - 1);
    int rec = gg >> 6;                                // 0..767
    int d = rec % DI;
    int b = (rec / DI) & 1;
    int dir = rec / (DI * 2);

    const float* DEL = dir ? DELB : DELF;
    const float* DBL = dir ? DBLB : DBLF;
    const float* XS  = dir ? XSB  : XSF;
    const float* Alog = dir ? bAlog : fAlog;

    float A = -__expf(Alog[d * DS + s]);
    int l = dir ? (L_SEQ - 1 - chunk * CHUNK) : chunk * CHUNK;
    int step = dir ? -1 : 1;

    float h = 0.f, Pv = 1.f;
    for (int i = 0; i < CHUNK; i++) {
        size_t p = (size_t)b * L_SEQ + l;
        float del = DEL[p * DI + d];
        float Bm  = DBL[p * 38 + 6 + s];
        float xs  = XS[p * DI + d];
        float dA = __expf(del * A);
        h = dA * h + del * Bm * xs;
        Pv *= dA;
        l += step;
    }
    P[t] = Pv;
    Q[t] = h;
}

// p2: per (rec,s), compose 64 chunk operators sequentially; Q[chunk] is
// overwritten with the chunk's INITIAL state.
__global__ void k_scan_p2(const float* __restrict__ P, float* __restrict__ Q) {
    int u = blockIdx.x * blockDim.x + threadIdx.x;   // 12288
    int s = u & 15;
    int rec = u >> 4;
    float run = 0.f;
    int base = rec * (NCH * 16) + s;
#pragma unroll 4
    for (int c = 0; c < NCH; c++) {
        int i = base + c * 16;
        float tmp = Q[i];
        Q[i] = run;
        run = P[i] * run + tmp;
    }
}

// p3: replay each chunk from its exact initial state; contract with C via
// 16-lane shuffle tree; fused (+xs*D)*silu(z) epilogue.
__global__ void k_scan_p3(const float* __restrict__ DELF, const float* __restrict__ DELB,
                          const float* __restrict__ DBLF, const float* __restrict__ DBLB,
                          const float* __restrict__ XSF,  const float* __restrict__ XSB,
                          const float* __restrict__ XZF,  const float* __restrict__ XZB,
                          const float* __restrict__ fAlog, const float* __restrict__ bAlog,
                          const float* __restrict__ fD,    const float* __restrict__ bD,
                          const float* __restrict__ Q,
                          float* __restrict__ YSF, float* __restrict__ YSB) {
    int t = blockIdx.x * blockDim.x + threadIdx.x;
    int s = t & 15;
    int gg = t >> 4;
    int chunk = gg & (NCH - 1);
    int rec = gg >> 6;
    int d = rec % DI;
    int b = (rec / DI) & 1;
    int dir = rec / (DI * 2);

    const float* DEL = dir ? DELB : DELF;
    const float* DBL = dir ? DBLB : DBLF;
    const float* XS  = dir ? XSB  : XSF;
    const float* XZ  = dir ? XZB  : XZF;
    const float* Alog = dir ? bAlog : fAlog;
    float Dp = dir ? bD[d] : fD[d];
    float* Y = dir ? YSB : YSF;

    float A = -__expf(Alog[d * DS + s]);
    int l = dir ? (L_SEQ - 1 - chunk * CHUNK) : chunk * CHUNK;
    int step = dir ? -1 : 1;

    float h = Q[t];
    for (int i = 0; i < CHUNK; i++) {
        size_t p = (size_t)b * L_SEQ + l;
        float del = DEL[p * DI + d];
        float Bm  = DBL[p * 38 + 6 + s];
        float Cm  = DBL[p * 38 + 22 + s];
        float xs  = XS[p * DI + d];
        float dA = __expf(del * A);
        h = dA * h + del * Bm * xs;
        float pr = h * Cm;
        pr += __shfl_xor(pr, 1, 64);
        pr += __shfl_xor(pr, 2, 64);
        pr += __shfl_xor(pr, 4, 64);
        pr += __shfl_xor(pr, 8, 64);
        if (s == 0) {
            float z = XZ[p * 384 + 192 + d];
            Y[p * DI + d] = (pr + xs * Dp) * silu_f(z);
        }
        l += step;
    }
}

// ---------------------------------------------------------------------------
// K9: x2 = x + gamma1*(yo + x1); store XMID (B,96,L); XM2 = ln_cf(x2) planar.
// ---------------------------------------------------------------------------
__global__ void k_mid(const float* __restrict__ x, const float* __restrict__ YO,
                      const float* __restrict__ X1,
                      const float* __restrict__ gamma1,
                      const float* __restrict__ ln1w, const float* __restrict__ ln1b,
                      float* __restrict__ XMID, float* __restrict__ XM2) {
    int p = blockIdx.x * blockDim.x + threadIdx.x;
    if (p >= NPOS) return;
    int b = p >> 12, l = p & (L_SEQ - 1);
    const float* yop = YO + (size_t)p * DIM;
    float s = 0.f, ss = 0.f;
    for (int c = 0; c < DIM; c++) {
        size_t idx = ((size_t)b * DIM + c) * L_SEQ + l;
        float v = x[idx] + gamma1[c] * (yop[c] + X1[idx]);
        XMID[idx] = v;
        s += v; ss += v * v;
    }
    float u = s / DIM;
    float r = rsqrtf(ss / DIM - u * u + 1e-6f);
    for (int c = 0; c < DIM; c++) {
        size_t idx = ((size_t)b * DIM + c) * L_SEQ + l;
        float v = XMID[idx];
        XM2[idx] = ln1w[c] * (v - u) * r + ln1b[c];
    }
}

// ---------------------------------------------------------------------------
// K11: fused 3x dilated depthwise 3x3 conv + GELU gate.
// ---------------------------------------------------------------------------
__global__ void k_msff(const float* __restrict__ H5,
                       const float* __restrict__ dw1, const float* __restrict__ dw2,
                       const float* __restrict__ dw3, float* __restrict__ G) {
    int i = blockIdx.x * blockDim.x + threadIdx.x;   // B*HID*4096
    int l = i & (L_SEQ - 1);
    int tmp = i >> 12;
    int c = tmp % HID;
    int b = tmp / HID;
    int y = l >> 6, xc = l & 63;
    const float* p1 = H5 + ((size_t)b * 576 + c) * L_SEQ;
    const float* p2 = H5 + ((size_t)b * 576 + HID + c) * L_SEQ;
    const float* p3 = H5 + ((size_t)b * 576 + 2 * HID + c) * L_SEQ;
    float a1 = 0.f, a2 = 0.f, a3 = 0.f;
#pragma unroll
    for (int ky = 0; ky < 3; ky++) {
#pragma unroll
        for (int kx = 0; kx < 3; kx++) {
            float w1 = dw1[(c * 3 + ky) * 3 + kx];
            float w2 = dw2[(c * 3 + ky) * 3 + kx];
            float w3 = dw3[(c * 3 + ky) * 3 + kx];
            int y1 = y + (ky - 1), x1 = xc + (kx - 1);
            if (y1 >= 0 && y1 < 64 && x1 >= 0 && x1 < 64) a1 += w1 * p1[y1 * 64 + x1];
            int y2 = y + (ky - 1) * 2, x2 = xc + (kx - 1) * 2;
            if (y2 >= 0 && y2 < 64 && x2 >= 0 && x2 < 64) a2 += w2 * p2[y2 * 64 + x2];
            int y3 = y + (ky - 1) * 3, x3 = xc + (kx - 1) * 3;
            if (y3 >= 0 && y3 < 64 && x3 >= 0 && x3 < 64) a3 += w3 * p3[y3 * 64 + x3];
        }
    }
    float ge = 0.5f * a1 * (1.f + erff(a1 * 0.70710678118f));
    G[((size_t)b * HID + c) * L_SEQ + l] = ge * a2 * a3;
}

// ---------------------------------------------------------------------------
// K13: out = XMID + gamma2[c] * OXM  (f32 output)
// ---------------------------------------------------------------------------
__global__ void k_out(const float* __restrict__ XMID, const float* __restrict__ OXM,
                      const float* __restrict__ gamma2, float* __restrict__ out) {
    int i = blockIdx.x * blockDim.x + threadIdx.x;   // B*96*4096
    int c = (i >> 12) % DIM;
    out[i] = XMID[i] + gamma2[c] * OXM[i];
}

// ---------------------------------------------------------------------------
extern "C" void kernel_launch(void* const* d_in, const int* in_sizes, int n_in,
                              void* d_out, int out_size, void* d_ws, size_t ws_size,
                              hipStream_t stream) {
    const float* x      = (const float*)d_in[0];
    const float* gamma1 = (const float*)d_in[1];
    const float* gamma2 = (const float*)d_in[2];
    const float* ln1w   = (const float*)d_in[3];
    const float* ln1b   = (const float*)d_in[4];
    const float* mnw    = (const float*)d_in[5];
    const float* mnb    = (const float*)d_in[6];
    const float* fWin   = (const float*)d_in[7];
    const float* fconvw = (const float*)d_in[8];
    const float* fconvb = (const float*)d_in[9];
    const float* fWx    = (const float*)d_in[10];
    const float* fWdt   = (const float*)d_in[11];
    const float* fbdt   = (const float*)d_in[12];
    const float* fAlog  = (const float*)d_in[13];
    const float* fD     = (const float*)d_in[14];
    const float* bWin   = (const float*)d_in[15];
    const float* bconvw = (const float*)d_in[16];
    const float* bconvb = (const float*)d_in[17];
    const float* bWx    = (const float*)d_in[18];
    const float* bWdt   = (const float*)d_in[19];
    const float* bbdt   = (const float*)d_in[20];
    const float* bAlog  = (const float*)d_in[21];
    const float* bD     = (const float*)d_in[22];
    const float* Wout   = (const float*)d_in[23];
    const float* mwin   = (const float*)d_in[24];
    const float* mdw1   = (const float*)d_in[25];
    const float* mdw2   = (const float*)d_in[26];
    const float* mdw3   = (const float*)d_in[27];
    const float* mwout  = (const float*)d_in[28];
    float* out = (float*)d_out;

    float* ws = (float*)d_ws;
    float* XN   = ws;                       // 786432
    float* X1   = XN   + 786432;            // 786432
    float* XZF  = X1   + 786432;            // 3145728
    float* XZB  = XZF  + 3145728;           // 3145728
    float* XSF  = XZB  + 3145728;           // 1572864
    float* XSB  = XSF  + 1572864;           // 1572864
    float* DBLF = XSB  + 1572864;           // 311296
    float* DBLB = DBLF + 311296;            // 311296
    float* DELF = DBLB + 311296;            // 1572864
    float* DELB = DELF + 1572864;           // 1572864
    float* YSF  = DELB + 1572864;           // 1572864
    float* YSB  = YSF  + 1572864;           // 1572864
    float* Qb   = YSB  + 1572864;           // 786432 (scan chunk states)
    // overlays:
    float* Pb   = XN;                       // 786432 (XN dead after in-proj)
    float* YO   = XN;                       // 786432 (P dead after p2)
    float* XMID = DELF;                     // 786432 (DEL dead after p3)
    float* XM2  = DELB;                     // 786432
    float* H576 = XZF;                      // 4718592 (XZ dead after p3)
    float* G    = YSF;                      // 1572864 (YS dead after out-proj)
    float* OXM  = XSF;                      // 786432  (XS dead after p3)

    // 1. double LN
    k_ln12<<<NPOS / 256, 256, 0, stream>>>(x, ln1w, ln1b, mnw, mnb, X1, XN);
    // 2-3. in-projections
    gemm_nt<<<dim3(128, 6), 256, 0, stream>>>(XN, nullptr, fWin, XZF, NPOS, 384, DIM);
    gemm_nt<<<dim3(128, 6), 256, 0, stream>>>(XN, nullptr, bWin, XZB, NPOS, 384, DIM);
    // 4-5. causal / anti-causal dwconv + silu
    k_conv<<<NPOS * DI / 256, 256, 0, stream>>>(XZF, fconvw, fconvb, XSF, 0);
    k_conv<<<NPOS * DI / 256, 256, 0, stream>>>(XZB, bconvw, bconvb, XSB, 1);
    // 6-7. x_dbl projections
    gemm_nt<<<dim3(128, 1), 256, 0, stream>>>(XSF, nullptr, fWx, DBLF, NPOS, 38, DI);
    gemm_nt<<<dim3(128, 1), 256, 0, stream>>>(XSB, nullptr, bWx, DBLB, NPOS, 38, DI);
    // 8-9. delta
    k_delta<<<NPOS * DI / 256, 256, 0, stream>>>(DBLF, fWdt, fbdt, DELF);
    k_delta<<<NPOS * DI / 256, 256, 0, stream>>>(DBLB, bWdt, bbdt, DELB);
    // 10. chunked parallel scan
    k_scan_p1<<<NREC * NCH * 16 / 256, 256, 0, stream>>>(DELF, DELB, DBLF, DBLB,
                                                         XSF, XSB, fAlog, bAlog, Pb, Qb);
    k_scan_p2<<<NREC * 16 / 256, 256, 0, stream>>>(Pb, Qb);
    k_scan_p3<<<NREC * NCH * 16 / 256, 256, 0, stream>>>(DELF, DELB, DBLF, DBLB,
                                                         XSF, XSB, XZF, XZB,
                                                         fAlog, bAlog, fD, bD, Qb,
                                                         YSF, YSB);
    // 11. out-projection with fused yf+yb add
    gemm_nt<<<dim3(128, 2), 256, 0, stream>>>(YSF, YSB, Wout, YO, NPOS, DIM, DI);
    // 12. residual + LN
    k_mid<<<NPOS / 256, 256, 0, stream>>>(x, YO, X1, gamma1, ln1w, ln1b, XMID, XM2);
    // 13. msff in-projection (planar)
    gemm_nn<<<dim3(9, 64, 2), 256, 0, stream>>>(mwin, XM2, H576, 576, L_SEQ, DIM,
                                                (size_t)DIM * L_SEQ, (size_t)576 * L_SEQ);
    // 14. fused dilated dwconvs + GELU gate
    k_msff<<<BATCH * HID * L_SEQ / 256, 256, 0, stream>>>(H576, mdw1, mdw2, mdw3, G);
    // 15. msff out-projection
    gemm_nn<<<dim3(2, 64, 2), 256, 0, stream>>>(mwout, G, OXM, DIM, L_SEQ, HID,
                                                (size_t)HID * L_SEQ, (size_t)DIM * L_SEQ);
    // 16. final residual -> f32 out
    k_out<<<BATCH * DIM * L_SEQ / 256, 256, 0, stream>>>(XMID, OXM, gamma2, out);
}

// Round 4
// 480.704 us; speedup vs baseline: 3.7421x; 1.0536x over previous
//
#include <hip/hip_runtime.h>
#include <hip/hip_bf16.h>
#include <math.h>

#define L_SEQ 4096
#define BATCH 2
#define DIM   96
#define DI    192
#define DS    16
#define HID   192
#define NPOS  (BATCH * L_SEQ)   // 8192
#define NCH   64                // chunks per sequence
#define CHUNK 64                // L_SEQ / NCH
#define NREC  (2 * BATCH * DI)  // 768 recurrences (dir,b,d)
#define LDBL  40                // padded x_dbl row stride: dt[0:6), B[8:24), C[24:40)

__device__ __forceinline__ float silu_f(float x) { return x / (1.f + __expf(-x)); }

// ---------------------------------------------------------------------------
// K1: double layernorm over channel dim.
// ---------------------------------------------------------------------------
__global__ void k_ln12(const float* __restrict__ x,
                       const float* __restrict__ ln1w, const float* __restrict__ ln1b,
                       const float* __restrict__ mnw,  const float* __restrict__ mnb,
                       float* __restrict__ X1, float* __restrict__ XN) {
    int p = blockIdx.x * blockDim.x + threadIdx.x;   // 0..NPOS-1
    if (p >= NPOS) return;
    int b = p >> 12, l = p & (L_SEQ - 1);
    const float* xb = x + (size_t)b * DIM * L_SEQ + l;
    float s = 0.f, ss = 0.f;
    for (int c = 0; c < DIM; c++) { float v = xb[(size_t)c * L_SEQ]; s += v; ss += v * v; }
    float u = s / DIM;
    float r = rsqrtf(ss / DIM - u * u + 1e-6f);
    float s2 = 0.f, ss2 = 0.f;
    for (int c = 0; c < DIM; c++) {
        float v = xb[(size_t)c * L_SEQ];
        float t = ln1w[c] * (v - u) * r + ln1b[c];
        X1[((size_t)b * DIM + c) * L_SEQ + l] = t;
        s2 += t; ss2 += t * t;
    }
    float u2 = s2 / DIM;
    float r2 = rsqrtf(ss2 / DIM - u2 * u2 + 1e-5f);
    float* xnp = XN + (size_t)p * DIM;
    for (int c = 0; c < DIM; c++) {
        float t = X1[((size_t)b * DIM + c) * L_SEQ + l];
        xnp[c] = (t - u2) * r2 * mnw[c] + mnb[c];
    }
}

// ---------------------------------------------------------------------------
// GEMM NT: C[M,N] = (A1 (+A2))[M,K] @ W[N,K]^T.  all f32.
// ldc = output row stride; pad6: output cols >=6 shifted +2 (for LDBL layout).
// ---------------------------------------------------------------------------
__global__ void gemm_nt(const float* __restrict__ A1, const float* __restrict__ A2,
                        const float* __restrict__ W, float* __restrict__ C,
                        int M, int N, int K, int ldc, int pad6) {
    __shared__ float As[32][65];
    __shared__ float Bs[32][65];
    int m0 = blockIdx.x * 64, n0 = blockIdx.y * 64;
    int t = threadIdx.x;
    int tx = t & 15, ty = t >> 4;
    int lrow = t >> 2;          // 0..63
    int lk = (t & 3) * 8;       // 0,8,16,24
    float acc[4][4] = {};
    for (int k0 = 0; k0 < K; k0 += 32) {
        {
            const float* ap = A1 + (size_t)(m0 + lrow) * K + k0 + lk;
            float v[8];
#pragma unroll
            for (int j = 0; j < 8; j++) v[j] = ap[j];
            if (A2) {
                const float* ap2 = A2 + (size_t)(m0 + lrow) * K + k0 + lk;
#pragma unroll
                for (int j = 0; j < 8; j++) v[j] += ap2[j];
            }
#pragma unroll
            for (int j = 0; j < 8; j++) As[lk + j][lrow] = v[j];
        }
        {
            int n = n0 + lrow;
            float v[8];
            if (n < N) {
                const float* wp = W + (size_t)n * K + k0 + lk;
#pragma unroll
                for (int j = 0; j < 8; j++) v[j] = wp[j];
            } else {
#pragma unroll
                for (int j = 0; j < 8; j++) v[j] = 0.f;
            }
#pragma unroll
            for (int j = 0; j < 8; j++) Bs[lk + j][lrow] = v[j];
        }
        __syncthreads();
#pragma unroll
        for (int k = 0; k < 32; k++) {
            float a[4], bb[4];
#pragma unroll
            for (int i = 0; i < 4; i++) a[i] = As[k][ty * 4 + i];
#pragma unroll
            for (int j = 0; j < 4; j++) bb[j] = Bs[k][tx * 4 + j];
#pragma unroll
            for (int i = 0; i < 4; i++)
#pragma unroll
                for (int j = 0; j < 4; j++) acc[i][j] += a[i] * bb[j];
        }
        __syncthreads();
    }
#pragma unroll
    for (int i = 0; i < 4; i++) {
        int m = m0 + ty * 4 + i;
#pragma unroll
        for (int j = 0; j < 4; j++) {
            int n = n0 + tx * 4 + j;
            if (n < N) {
                int nn = n + ((pad6 && n >= 6) ? 2 : 0);
                C[(size_t)m * ldc + nn] = acc[i][j];
            }
        }
    }
}

// ---------------------------------------------------------------------------
// GEMM NN (batched): C[b][M,N] = W[M,K] @ Bmat[b][K,N].  all f32.
// ---------------------------------------------------------------------------
__global__ void gemm_nn(const float* __restrict__ W, const float* __restrict__ Bm,
                        float* __restrict__ C, int M, int N, int K,
                        size_t strideB, size_t strideC) {
    __shared__ float As[32][65];
    __shared__ float Bs[32][65];
    int m0 = blockIdx.x * 64, n0 = blockIdx.y * 64;
    const float* Bp = Bm + strideB * blockIdx.z;
    float* Cp = C + strideC * blockIdx.z;
    int t = threadIdx.x;
    int tx = t & 15, ty = t >> 4;
    int lrow = t >> 2, lk = (t & 3) * 8;     // W load
    int bk = t >> 3, bn = (t & 7) * 8;       // B load
    float acc[4][4] = {};
    for (int k0 = 0; k0 < K; k0 += 32) {
        {
            int m = m0 + lrow;
            float v[8];
            if (m < M) {
                const float* wp = W + (size_t)m * K + k0 + lk;
#pragma unroll
                for (int j = 0; j < 8; j++) v[j] = wp[j];
            } else {
#pragma unroll
                for (int j = 0; j < 8; j++) v[j] = 0.f;
            }
#pragma unroll
            for (int j = 0; j < 8; j++) As[lk + j][lrow] = v[j];
        }
        {
            const float* bp = Bp + (size_t)(k0 + bk) * N + n0 + bn;
#pragma unroll
            for (int j = 0; j < 8; j++) Bs[bk][bn + j] = bp[j];
        }
        __syncthreads();
#pragma unroll
        for (int k = 0; k < 32; k++) {
            float a[4], bb[4];
#pragma unroll
            for (int i = 0; i < 4; i++) a[i] = As[k][ty * 4 + i];
#pragma unroll
            for (int j = 0; j < 4; j++) bb[j] = Bs[k][tx * 4 + j];
#pragma unroll
            for (int i = 0; i < 4; i++)
#pragma unroll
                for (int j = 0; j < 4; j++) acc[i][j] += a[i] * bb[j];
        }
        __syncthreads();
    }
#pragma unroll
    for (int i = 0; i < 4; i++) {
        int m = m0 + ty * 4 + i;
        if (m < M) {
#pragma unroll
            for (int j = 0; j < 4; j++) Cp[(size_t)m * N + n0 + tx * 4 + j] = acc[i][j];
        }
    }
}

// ---------------------------------------------------------------------------
// K3: causal (dir=0) / anti-causal (dir=1) depthwise conv1d k=4 + bias + silu.
// ---------------------------------------------------------------------------
__global__ void k_conv(const float* __restrict__ XZ, const float* __restrict__ convw,
                       const float* __restrict__ convb, float* __restrict__ XS, int dirb) {
    int i = blockIdx.x * blockDim.x + threadIdx.x;   // NPOS*DI
    int d = i % DI;
    int p = i / DI;
    int b = p >> 12, l = p & (L_SEQ - 1);
    float acc = convb[d];
    if (!dirb) {
#pragma unroll
        for (int k = 0; k < 4; k++) {
            int ls = l - 3 + k;
            if (ls >= 0) acc += convw[d * 4 + k] * XZ[((size_t)(b * L_SEQ + ls)) * 384 + d];
        }
    } else {
#pragma unroll
        for (int k = 0; k < 4; k++) {
            int ls = l + 3 - k;
            if (ls < L_SEQ) acc += convw[d * 4 + k] * XZ[((size_t)(b * L_SEQ + ls)) * 384 + d];
        }
    }
    XS[(size_t)p * DI + d] = silu_f(acc);
}

// ---------------------------------------------------------------------------
// K5: delta = softplus(dt @ Wdt^T + bdt).  DBL (NPOS,LDBL) -> DEL (NPOS,192)
// ---------------------------------------------------------------------------
__global__ void k_delta(const float* __restrict__ DBL, const float* __restrict__ Wdt,
                        const float* __restrict__ bdt, float* __restrict__ DEL) {
    int i = blockIdx.x * blockDim.x + threadIdx.x;   // NPOS*DI
    int d = i % DI;
    int p = i / DI;
    const float* dp = DBL + (size_t)p * LDBL;
    float acc = bdt[d];
#pragma unroll
    for (int r = 0; r < 6; r++) acc += dp[r] * Wdt[d * 6 + r];
    float sp = (acc > 0.f) ? (acc + log1pf(__expf(-acc))) : log1pf(__expf(acc));
    DEL[(size_t)p * DI + d] = sp;
}

// ---------------------------------------------------------------------------
// Chunked parallel scan, 16 states per THREAD (no shuffles).
// Thread map: t = gchunk*DI + d, gchunk = (dir*2+b)*NCH + chunk.
// P/Q layout: [gchunk][d][s] (16 contiguous floats per thread).
// ---------------------------------------------------------------------------
__global__ void k_scan_p1(const float* __restrict__ DELF, const float* __restrict__ DELB,
                          const float* __restrict__ DBLF, const float* __restrict__ DBLB,
                          const float* __restrict__ XSF,  const float* __restrict__ XSB,
                          const float* __restrict__ fAlog, const float* __restrict__ bAlog,
                          float* __restrict__ P, float* __restrict__ Q) {
    int t = blockIdx.x * blockDim.x + threadIdx.x;   // 49152
    int d = t % DI;
    int g = t / DI;                                   // 0..255
    int chunk = g & (NCH - 1);
    int dirb = g >> 6;
    int b = dirb & 1, dir = dirb >> 1;

    const float* DEL = dir ? DELB : DELF;
    const float* DBL = dir ? DBLB : DBLF;
    const float* XS  = dir ? XSB  : XSF;
    const float* al  = (dir ? bAlog : fAlog) + d * DS;

    float A[16], h[16], Pv[16];
#pragma unroll
    for (int s = 0; s < 16; s++) { A[s] = -__expf(al[s]); h[s] = 0.f; Pv[s] = 1.f; }

    int l = dir ? (L_SEQ - 1 - chunk * CHUNK) : chunk * CHUNK;
    int stp = dir ? -1 : 1;

    for (int i = 0; i < CHUNK; i++) {
        size_t p = (size_t)b * L_SEQ + l;
        float del = DEL[p * DI + d];
        float xs  = XS[p * DI + d];
        const float4* bm = (const float4*)(DBL + p * LDBL + 8);
        float4 B0 = bm[0], B1 = bm[1], B2 = bm[2], B3 = bm[3];
        float Bm[16] = {B0.x,B0.y,B0.z,B0.w, B1.x,B1.y,B1.z,B1.w,
                        B2.x,B2.y,B2.z,B2.w, B3.x,B3.y,B3.z,B3.w};
        float dx = del * xs;
#pragma unroll
        for (int s = 0; s < 16; s++) {
            float dA = __expf(del * A[s]);
            h[s] = dA * h[s] + dx * Bm[s];
            Pv[s] *= dA;
        }
        l += stp;
    }
    float4* pp = (float4*)(P + ((size_t)g * DI + d) * 16);
    float4* qq = (float4*)(Q + ((size_t)g * DI + d) * 16);
#pragma unroll
    for (int v = 0; v < 4; v++) {
        pp[v] = make_float4(Pv[4*v], Pv[4*v+1], Pv[4*v+2], Pv[4*v+3]);
        qq[v] = make_float4(h[4*v], h[4*v+1], h[4*v+2], h[4*v+3]);
    }
}

// p2: per (dirb,d,s), compose chunk operators; Q[chunk] overwritten with the
// chunk's INITIAL state.
__global__ void k_scan_p2(const float* __restrict__ P, float* __restrict__ Q) {
    int u = blockIdx.x * blockDim.x + threadIdx.x;   // 12288
    int s = u & 15;
    int dd = (u >> 4) % DI;
    int dirb = u / (DI * 16);
    float run = 0.f;
#pragma unroll 4
    for (int c = 0; c < NCH; c++) {
        size_t i = (((size_t)(dirb * NCH + c)) * DI + dd) * 16 + s;
        float tmp = Q[i];
        Q[i] = run;
        run = P[i] * run + tmp;
    }
}

// p3: replay each chunk from its exact initial state; in-thread C-contraction;
// fused (+xs*D)*silu(z) epilogue. One Y value stored per thread per step.
__global__ void k_scan_p3(const float* __restrict__ DELF, const float* __restrict__ DELB,
                          const float* __restrict__ DBLF, const float* __restrict__ DBLB,
                          const float* __restrict__ XSF,  const float* __restrict__ XSB,
                          const float* __restrict__ XZF,  const float* __restrict__ XZB,
                          const float* __restrict__ fAlog, const float* __restrict__ bAlog,
                          const float* __restrict__ fD,    const float* __restrict__ bD,
                          const float* __restrict__ Q,
                          float* __restrict__ YSF, float* __restrict__ YSB) {
    int t = blockIdx.x * blockDim.x + threadIdx.x;   // 49152
    int d = t % DI;
    int g = t / DI;
    int chunk = g & (NCH - 1);
    int dirb = g >> 6;
    int b = dirb & 1, dir = dirb >> 1;

    const float* DEL = dir ? DELB : DELF;
    const float* DBL = dir ? DBLB : DBLF;
    const float* XS  = dir ? XSB  : XSF;
    const float* XZ  = dir ? XZB  : XZF;
    const float* al  = (dir ? bAlog : fAlog) + d * DS;
    float Dp = dir ? bD[d] : fD[d];
    float* Y = dir ? YSB : YSF;

    float A[16], h[16];
#pragma unroll
    for (int s = 0; s < 16; s++) A[s] = -__expf(al[s]);
    const float4* qq = (const float4*)(Q + ((size_t)g * DI + d) * 16);
#pragma unroll
    for (int v = 0; v < 4; v++) {
        float4 q = qq[v];
        h[4*v] = q.x; h[4*v+1] = q.y; h[4*v+2] = q.z; h[4*v+3] = q.w;
    }

    int l = dir ? (L_SEQ - 1 - chunk * CHUNK) : chunk * CHUNK;
    int stp = dir ? -1 : 1;

    for (int i = 0; i < CHUNK; i++) {
        size_t p = (size_t)b * L_SEQ + l;
        float del = DEL[p * DI + d];
        float xs  = XS[p * DI + d];
        float z   = XZ[p * 384 + 192 + d];
        const float4* bm = (const float4*)(DBL + p * LDBL + 8);
        float4 B0 = bm[0], B1 = bm[1], B2 = bm[2], B3 = bm[3];
        float4 C0 = bm[4], C1 = bm[5], C2 = bm[6], C3 = bm[7];
        float Bm[16] = {B0.x,B0.y,B0.z,B0.w, B1.x,B1.y,B1.z,B1.w,
                        B2.x,B2.y,B2.z,B2.w, B3.x,B3.y,B3.z,B3.w};
        float Cm[16] = {C0.x,C0.y,C0.z,C0.w, C1.x,C1.y,C1.z,C1.w,
                        C2.x,C2.y,C2.z,C2.w, C3.x,C3.y,C3.z,C3.w};
        float dx = del * xs;
        float pr = 0.f;
#pragma unroll
        for (int s = 0; s < 16; s++) {
            float dA = __expf(del * A[s]);
            h[s] = dA * h[s] + dx * Bm[s];
            pr += h[s] * Cm[s];
        }
        Y[p * DI + d] = (pr + xs * Dp) * silu_f(z);
        l += stp;
    }
}

// ---------------------------------------------------------------------------
// K9: x2 = x + gamma1*(yo + x1); store XMID (B,96,L); XM2 = ln_cf(x2) planar.
// ---------------------------------------------------------------------------
__global__ void k_mid(const float* __restrict__ x, const float* __restrict__ YO,
                      const float* __restrict__ X1,
                      const float* __restrict__ gamma1,
                      const float* __restrict__ ln1w, const float* __restrict__ ln1b,
                      float* __restrict__ XMID, float* __restrict__ XM2) {
    int p = blockIdx.x * blockDim.x + threadIdx.x;
    if (p >= NPOS) return;
    int b = p >> 12, l = p & (L_SEQ - 1);
    const float* yop = YO + (size_t)p * DIM;
    float s = 0.f, ss = 0.f;
    for (int c = 0; c < DIM; c++) {
        size_t idx = ((size_t)b * DIM + c) * L_SEQ + l;
        float v = x[idx] + gamma1[c] * (yop[c] + X1[idx]);
        XMID[idx] = v;
        s += v; ss += v * v;
    }
    float u = s / DIM;
    float r = rsqrtf(ss / DIM - u * u + 1e-6f);
    for (int c = 0; c < DIM; c++) {
        size_t idx = ((size_t)b * DIM + c) * L_SEQ + l;
        float v = XMID[idx];
        XM2[idx] = ln1w[c] * (v - u) * r + ln1b[c];
    }
}

// ---------------------------------------------------------------------------
// K11: fused 3x dilated depthwise 3x3 conv + GELU gate.
// ---------------------------------------------------------------------------
__global__ void k_msff(const float* __restrict__ H5,
                       const float* __restrict__ dw1, const float* __restrict__ dw2,
                       const float* __restrict__ dw3, float* __restrict__ G) {
    int i = blockIdx.x * blockDim.x + threadIdx.x;   // B*HID*4096
    int l = i & (L_SEQ - 1);
    int tmp = i >> 12;
    int c = tmp % HID;
    int b = tmp / HID;
    int y = l >> 6, xc = l & 63;
    const float* p1 = H5 + ((size_t)b * 576 + c) * L_SEQ;
    const float* p2 = H5 + ((size_t)b * 576 + HID + c) * L_SEQ;
    const float* p3 = H5 + ((size_t)b * 576 + 2 * HID + c) * L_SEQ;
    float a1 = 0.f, a2 = 0.f, a3 = 0.f;
#pragma unroll
    for (int ky = 0; ky < 3; ky++) {
#pragma unroll
        for (int kx = 0; kx < 3; kx++) {
            float w1 = dw1[(c * 3 + ky) * 3 + kx];
            float w2 = dw2[(c * 3 + ky) * 3 + kx];
            float w3 = dw3[(c * 3 + ky) * 3 + kx];
            int y1 = y + (ky - 1), x1 = xc + (kx - 1);
            if (y1 >= 0 && y1 < 64 && x1 >= 0 && x1 < 64) a1 += w1 * p1[y1 * 64 + x1];
            int y2 = y + (ky - 1) * 2, x2 = xc + (kx - 1) * 2;
            if (y2 >= 0 && y2 < 64 && x2 >= 0 && x2 < 64) a2 += w2 * p2[y2 * 64 + x2];
            int y3 = y + (ky - 1) * 3, x3 = xc + (kx - 1) * 3;
            if (y3 >= 0 && y3 < 64 && x3 >= 0 && x3 < 64) a3 += w3 * p3[y3 * 64 + x3];
        }
    }
    float ge = 0.5f * a1 * (1.f + erff(a1 * 0.70710678118f));
    G[((size_t)b * HID + c) * L_SEQ + l] = ge * a2 * a3;
}

// ---------------------------------------------------------------------------
// K13: out = XMID + gamma2[c] * OXM  (f32 output)
// ---------------------------------------------------------------------------
__global__ void k_out(const float* __restrict__ XMID, const float* __restrict__ OXM,
                      const float* __restrict__ gamma2, float* __restrict__ out) {
    int i = blockIdx.x * blockDim.x + threadIdx.x;   // B*96*4096
    int c = (i >> 12) % DIM;
    out[i] = XMID[i] + gamma2[c] * OXM[i];
}

// ---------------------------------------------------------------------------
extern "C" void kernel_launch(void* const* d_in, const int* in_sizes, int n_in,
                              void* d_out, int out_size, void* d_ws, size_t ws_size,
                              hipStream_t stream) {
    const float* x      = (const float*)d_in[0];
    const float* gamma1 = (const float*)d_in[1];
    const float* gamma2 = (const float*)d_in[2];
    const float* ln1w   = (const float*)d_in[3];
    const float* ln1b   = (const float*)d_in[4];
    const float* mnw    = (const float*)d_in[5];
    const float* mnb    = (const float*)d_in[6];
    const float* fWin   = (const float*)d_in[7];
    const float* fconvw = (const float*)d_in[8];
    const float* fconvb = (const float*)d_in[9];
    const float* fWx    = (const float*)d_in[10];
    const float* fWdt   = (const float*)d_in[11];
    const float* fbdt   = (const float*)d_in[12];
    const float* fAlog  = (const float*)d_in[13];
    const float* fD     = (const float*)d_in[14];
    const float* bWin   = (const float*)d_in[15];
    const float* bconvw = (const float*)d_in[16];
    const float* bconvb = (const float*)d_in[17];
    const float* bWx    = (const float*)d_in[18];
    const float* bWdt   = (const float*)d_in[19];
    const float* bbdt   = (const float*)d_in[20];
    const float* bAlog  = (const float*)d_in[21];
    const float* bD     = (const float*)d_in[22];
    const float* Wout   = (const float*)d_in[23];
    const float* mwin   = (const float*)d_in[24];
    const float* mdw1   = (const float*)d_in[25];
    const float* mdw2   = (const float*)d_in[26];
    const float* mdw3   = (const float*)d_in[27];
    const float* mwout  = (const float*)d_in[28];
    float* out = (float*)d_out;

    float* ws = (float*)d_ws;
    float* XN   = ws;                       // 786432
    float* X1   = XN   + 786432;            // 786432
    float* XZF  = X1   + 786432;            // 3145728
    float* XZB  = XZF  + 3145728;           // 3145728
    float* XSF  = XZB  + 3145728;           // 1572864
    float* XSB  = XSF  + 1572864;           // 1572864
    float* DBLF = XSB  + 1572864;           // 327680 (NPOS*40)
    float* DBLB = DBLF + 327680;            // 327680
    float* DELF = DBLB + 327680;            // 1572864
    float* DELB = DELF + 1572864;           // 1572864
    float* YSF  = DELB + 1572864;           // 1572864
    float* YSB  = YSF  + 1572864;           // 1572864
    float* Qb   = YSB  + 1572864;           // 786432 (scan chunk states)
    // overlays:
    float* Pb   = XN;                       // 786432 (XN dead after in-proj)
    float* YO   = XN;                       // 786432 (P dead after p2)
    float* XMID = DELF;                     // 786432 (DEL dead after p3)
    float* XM2  = DELB;                     // 786432
    float* H576 = XZF;                      // 4718592 (XZ dead after p3)
    float* G    = YSF;                      // 1572864 (YS dead after out-proj)
    float* OXM  = XSF;                      // 786432  (XS dead after p3)

    // 1. double LN
    k_ln12<<<NPOS / 256, 256, 0, stream>>>(x, ln1w, ln1b, mnw, mnb, X1, XN);
    // 2-3. in-projections
    gemm_nt<<<dim3(128, 6), 256, 0, stream>>>(XN, nullptr, fWin, XZF, NPOS, 384, DIM, 384, 0);
    gemm_nt<<<dim3(128, 6), 256, 0, stream>>>(XN, nullptr, bWin, XZB, NPOS, 384, DIM, 384, 0);
    // 4-5. causal / anti-causal dwconv + silu
    k_conv<<<NPOS * DI / 256, 256, 0, stream>>>(XZF, fconvw, fconvb, XSF, 0);
    k_conv<<<NPOS * DI / 256, 256, 0, stream>>>(XZB, bconvw, bconvb, XSB, 1);
    // 6-7. x_dbl projections (padded LDBL=40 rows: dt[0:6), B[8:24), C[24:40))
    gemm_nt<<<dim3(128, 1), 256, 0, stream>>>(XSF, nullptr, fWx, DBLF, NPOS, 38, DI, LDBL, 1);
    gemm_nt<<<dim3(128, 1), 256, 0, stream>>>(XSB, nullptr, bWx, DBLB, NPOS, 38, DI, LDBL, 1);
    // 8-9. delta
    k_delta<<<NPOS * DI / 256, 256, 0, stream>>>(DBLF, fWdt, fbdt, DELF);
    k_delta<<<NPOS * DI / 256, 256, 0, stream>>>(DBLB, bWdt, bbdt, DELB);
    // 10. chunked parallel scan (16 states per thread)
    k_scan_p1<<<NREC * NCH / 256, 256, 0, stream>>>(DELF, DELB, DBLF, DBLB,
                                                    XSF, XSB, fAlog, bAlog, Pb, Qb);
    k_scan_p2<<<NREC * 16 / 256, 256, 0, stream>>>(Pb, Qb);
    k_scan_p3<<<NREC * NCH / 256, 256, 0, stream>>>(DELF, DELB, DBLF, DBLB,
                                                    XSF, XSB, XZF, XZB,
                                                    fAlog, bAlog, fD, bD, Qb,
                                                    YSF, YSB);
    // 11. out-projection with fused yf+yb add
    gemm_nt<<<dim3(128, 2), 256, 0, stream>>>(YSF, YSB, Wout, YO, NPOS, DIM, DI, DIM, 0);
    // 12. residual + LN
    k_mid<<<NPOS / 256, 256, 0, stream>>>(x, YO, X1, gamma1, ln1w, ln1b, XMID, XM2);
    // 13. msff in-projection (planar)
    gemm_nn<<<dim3(9, 64, 2), 256, 0, stream>>>(mwin, XM2, H576, 576, L_SEQ, DIM,
                                                (size_t)DIM * L_SEQ, (size_t)576 * L_SEQ);
    // 14. fused dilated dwconvs + GELU gate
    k_msff<<<BATCH * HID * L_SEQ / 256, 256, 0, stream>>>(H576, mdw1, mdw2, mdw3, G);
    // 15. msff out-projection
    gemm_nn<<<dim3(2, 64, 2), 256, 0, stream>>>(mwout, G, OXM, DIM, L_SEQ, HID,
                                                (size_t)HID * L_SEQ, (size_t)DIM * L_SEQ);
    // 16. final residual -> f32 out
    k_out<<<BATCH * DIM * L_SEQ / 256, 256, 0, stream>>>(XMID, OXM, gamma2, out);
}

// Round 5
// 435.865 us; speedup vs baseline: 4.1270x; 1.1029x over previous
//
#include <hip/hip_runtime.h>
#include <hip/hip_bf16.h>
#include <math.h>

#define L_SEQ 4096
#define BATCH 2
#define DIM   96
#define DI    192
#define DS    16
#define HID   192
#define NPOS  (BATCH * L_SEQ)   // 8192
#define NCH   256               // chunks per sequence
#define CHUNK 16                // L_SEQ / NCH
#define NREC  (2 * BATCH * DI)  // 768 recurrences (dir,b,d)
#define LDBL  40                // padded x_dbl row stride: dt[0:6), B[8:24), C[24:40)

__device__ __forceinline__ float silu_f(float x) { return x / (1.f + __expf(-x)); }
__device__ __forceinline__ float softplus_f(float x) {
    return (x > 0.f) ? (x + log1pf(__expf(-x))) : log1pf(__expf(x));
}

// ---------------------------------------------------------------------------
// K1: double layernorm over channel dim.
// ---------------------------------------------------------------------------
__global__ void k_ln12(const float* __restrict__ x,
                       const float* __restrict__ ln1w, const float* __restrict__ ln1b,
                       const float* __restrict__ mnw,  const float* __restrict__ mnb,
                       float* __restrict__ X1, float* __restrict__ XN) {
    int p = blockIdx.x * blockDim.x + threadIdx.x;   // 0..NPOS-1
    if (p >= NPOS) return;
    int b = p >> 12, l = p & (L_SEQ - 1);
    const float* xb = x + (size_t)b * DIM * L_SEQ + l;
    float s = 0.f, ss = 0.f;
    for (int c = 0; c < DIM; c++) { float v = xb[(size_t)c * L_SEQ]; s += v; ss += v * v; }
    float u = s / DIM;
    float r = rsqrtf(ss / DIM - u * u + 1e-6f);
    float s2 = 0.f, ss2 = 0.f;
    for (int c = 0; c < DIM; c++) {
        float v = xb[(size_t)c * L_SEQ];
        float t = ln1w[c] * (v - u) * r + ln1b[c];
        X1[((size_t)b * DIM + c) * L_SEQ + l] = t;
        s2 += t; ss2 += t * t;
    }
    float u2 = s2 / DIM;
    float r2 = rsqrtf(ss2 / DIM - u2 * u2 + 1e-5f);
    float* xnp = XN + (size_t)p * DIM;
    for (int c = 0; c < DIM; c++) {
        float t = X1[((size_t)b * DIM + c) * L_SEQ + l];
        xnp[c] = (t - u2) * r2 * mnw[c] + mnb[c];
    }
}

// ---------------------------------------------------------------------------
// GEMM NT: C[M,N] = (A1 (+A2))[M,K] @ W[N,K]^T.  all f32.
// ldc = output row stride; pad6: output cols >=6 shifted +2 (for LDBL layout).
// ---------------------------------------------------------------------------
__global__ void gemm_nt(const float* __restrict__ A1, const float* __restrict__ A2,
                        const float* __restrict__ W, float* __restrict__ C,
                        int M, int N, int K, int ldc, int pad6) {
    __shared__ float As[32][65];
    __shared__ float Bs[32][65];
    int m0 = blockIdx.x * 64, n0 = blockIdx.y * 64;
    int t = threadIdx.x;
    int tx = t & 15, ty = t >> 4;
    int lrow = t >> 2;          // 0..63
    int lk = (t & 3) * 8;       // 0,8,16,24
    float acc[4][4] = {};
    for (int k0 = 0; k0 < K; k0 += 32) {
        {
            const float* ap = A1 + (size_t)(m0 + lrow) * K + k0 + lk;
            float v[8];
#pragma unroll
            for (int j = 0; j < 8; j++) v[j] = ap[j];
            if (A2) {
                const float* ap2 = A2 + (size_t)(m0 + lrow) * K + k0 + lk;
#pragma unroll
                for (int j = 0; j < 8; j++) v[j] += ap2[j];
            }
#pragma unroll
            for (int j = 0; j < 8; j++) As[lk + j][lrow] = v[j];
        }
        {
            int n = n0 + lrow;
            float v[8];
            if (n < N) {
                const float* wp = W + (size_t)n * K + k0 + lk;
#pragma unroll
                for (int j = 0; j < 8; j++) v[j] = wp[j];
            } else {
#pragma unroll
                for (int j = 0; j < 8; j++) v[j] = 0.f;
            }
#pragma unroll
            for (int j = 0; j < 8; j++) Bs[lk + j][lrow] = v[j];
        }
        __syncthreads();
#pragma unroll
        for (int k = 0; k < 32; k++) {
            float a[4], bb[4];
#pragma unroll
            for (int i = 0; i < 4; i++) a[i] = As[k][ty * 4 + i];
#pragma unroll
            for (int j = 0; j < 4; j++) bb[j] = Bs[k][tx * 4 + j];
#pragma unroll
            for (int i = 0; i < 4; i++)
#pragma unroll
                for (int j = 0; j < 4; j++) acc[i][j] += a[i] * bb[j];
        }
        __syncthreads();
    }
#pragma unroll
    for (int i = 0; i < 4; i++) {
        int m = m0 + ty * 4 + i;
#pragma unroll
        for (int j = 0; j < 4; j++) {
            int n = n0 + tx * 4 + j;
            if (n < N) {
                int nn = n + ((pad6 && n >= 6) ? 2 : 0);
                C[(size_t)m * ldc + nn] = acc[i][j];
            }
        }
    }
}

// ---------------------------------------------------------------------------
// GEMM NN (batched): C[b][M,N] = W[M,K] @ Bmat[b][K,N].  all f32.
// ---------------------------------------------------------------------------
__global__ void gemm_nn(const float* __restrict__ W, const float* __restrict__ Bm,
                        float* __restrict__ C, int M, int N, int K,
                        size_t strideB, size_t strideC) {
    __shared__ float As[32][65];
    __shared__ float Bs[32][65];
    int m0 = blockIdx.x * 64, n0 = blockIdx.y * 64;
    const float* Bp = Bm + strideB * blockIdx.z;
    float* Cp = C + strideC * blockIdx.z;
    int t = threadIdx.x;
    int tx = t & 15, ty = t >> 4;
    int lrow = t >> 2, lk = (t & 3) * 8;     // W load
    int bk = t >> 3, bn = (t & 7) * 8;       // B load
    float acc[4][4] = {};
    for (int k0 = 0; k0 < K; k0 += 32) {
        {
            int m = m0 + lrow;
            float v[8];
            if (m < M) {
                const float* wp = W + (size_t)m * K + k0 + lk;
#pragma unroll
                for (int j = 0; j < 8; j++) v[j] = wp[j];
            } else {
#pragma unroll
                for (int j = 0; j < 8; j++) v[j] = 0.f;
            }
#pragma unroll
            for (int j = 0; j < 8; j++) As[lk + j][lrow] = v[j];
        }
        {
            const float* bp = Bp + (size_t)(k0 + bk) * N + n0 + bn;
#pragma unroll
            for (int j = 0; j < 8; j++) Bs[bk][bn + j] = bp[j];
        }
        __syncthreads();
#pragma unroll
        for (int k = 0; k < 32; k++) {
            float a[4], bb[4];
#pragma unroll
            for (int i = 0; i < 4; i++) a[i] = As[k][ty * 4 + i];
#pragma unroll
            for (int j = 0; j < 4; j++) bb[j] = Bs[k][tx * 4 + j];
#pragma unroll
            for (int i = 0; i < 4; i++)
#pragma unroll
                for (int j = 0; j < 4; j++) acc[i][j] += a[i] * bb[j];
        }
        __syncthreads();
    }
#pragma unroll
    for (int i = 0; i < 4; i++) {
        int m = m0 + ty * 4 + i;
        if (m < M) {
#pragma unroll
            for (int j = 0; j < 4; j++) Cp[(size_t)m * N + n0 + tx * 4 + j] = acc[i][j];
        }
    }
}

// ---------------------------------------------------------------------------
// K3: causal (dir=0) / anti-causal (dir=1) depthwise conv1d k=4 + bias + silu.
// ---------------------------------------------------------------------------
__global__ void k_conv(const float* __restrict__ XZ, const float* __restrict__ convw,
                       const float* __restrict__ convb, float* __restrict__ XS, int dirb) {
    int i = blockIdx.x * blockDim.x + threadIdx.x;   // NPOS*DI
    int d = i % DI;
    int p = i / DI;
    int b = p >> 12, l = p & (L_SEQ - 1);
    float acc = convb[d];
    if (!dirb) {
#pragma unroll
        for (int k = 0; k < 4; k++) {
            int ls = l - 3 + k;
            if (ls >= 0) acc += convw[d * 4 + k] * XZ[((size_t)(b * L_SEQ + ls)) * 384 + d];
        }
    } else {
#pragma unroll
        for (int k = 0; k < 4; k++) {
            int ls = l + 3 - k;
            if (ls < L_SEQ) acc += convw[d * 4 + k] * XZ[((size_t)(b * L_SEQ + ls)) * 384 + d];
        }
    }
    XS[(size_t)p * DI + d] = silu_f(acc);
}

// ---------------------------------------------------------------------------
// Chunked parallel scan, 16 states per THREAD, delta recomputed inline.
// Thread map: t = g*DI + d, g = dirb*NCH + chunk, dirb = dir*2+b.
// P/Q layout: [g][d][s] (16 contiguous floats per thread).
// ---------------------------------------------------------------------------
__global__ void k_scan_p1(const float* __restrict__ DBLF, const float* __restrict__ DBLB,
                          const float* __restrict__ XSF,  const float* __restrict__ XSB,
                          const float* __restrict__ fWdt, const float* __restrict__ fbdt,
                          const float* __restrict__ bWdt, const float* __restrict__ bbdt,
                          const float* __restrict__ fAlog, const float* __restrict__ bAlog,
                          float* __restrict__ P, float* __restrict__ Q) {
    int t = blockIdx.x * blockDim.x + threadIdx.x;   // 196608
    int d = t % DI;
    int g = t / DI;                                   // 0..1023
    int chunk = g & (NCH - 1);
    int dirb = g >> 8;
    int b = dirb & 1, dir = dirb >> 1;

    const float* DBL = dir ? DBLB : DBLF;
    const float* XS  = dir ? XSB  : XSF;
    const float* al  = (dir ? bAlog : fAlog) + d * DS;
    const float* wdt = (dir ? bWdt : fWdt) + d * 6;
    float bdtv = (dir ? bbdt : fbdt)[d];

    float wd[6];
#pragma unroll
    for (int r = 0; r < 6; r++) wd[r] = wdt[r];
    float A[16], h[16], Pv[16];
#pragma unroll
    for (int s = 0; s < 16; s++) { A[s] = -__expf(al[s]); h[s] = 0.f; Pv[s] = 1.f; }

    int l = dir ? (L_SEQ - 1 - chunk * CHUNK) : chunk * CHUNK;
    int stp = dir ? -1 : 1;

    for (int i = 0; i < CHUNK; i++) {
        size_t p = (size_t)b * L_SEQ + l;
        const float* row = DBL + p * LDBL;
        float dtv = bdtv;
#pragma unroll
        for (int r = 0; r < 6; r++) dtv += row[r] * wd[r];
        float del = softplus_f(dtv);
        float xs  = XS[p * DI + d];
        const float4* bm = (const float4*)(row + 8);
        float4 B0 = bm[0], B1 = bm[1], B2 = bm[2], B3 = bm[3];
        float Bm[16] = {B0.x,B0.y,B0.z,B0.w, B1.x,B1.y,B1.z,B1.w,
                        B2.x,B2.y,B2.z,B2.w, B3.x,B3.y,B3.z,B3.w};
        float dx = del * xs;
#pragma unroll
        for (int s = 0; s < 16; s++) {
            float dA = __expf(del * A[s]);
            h[s] = dA * h[s] + dx * Bm[s];
            Pv[s] *= dA;
        }
        l += stp;
    }
    float4* pp = (float4*)(P + ((size_t)g * DI + d) * 16);
    float4* qq = (float4*)(Q + ((size_t)g * DI + d) * 16);
#pragma unroll
    for (int v = 0; v < 4; v++) {
        pp[v] = make_float4(Pv[4*v], Pv[4*v+1], Pv[4*v+2], Pv[4*v+3]);
        qq[v] = make_float4(h[4*v], h[4*v+1], h[4*v+2], h[4*v+3]);
    }
}

// p2: per (dirb,d,s), compose chunk operators; Q[chunk] overwritten with the
// chunk's INITIAL state.
__global__ void k_scan_p2(const float* __restrict__ P, float* __restrict__ Q) {
    int u = blockIdx.x * blockDim.x + threadIdx.x;   // 12288
    int s = u & 15;
    int dd = (u >> 4) % DI;
    int dirb = u / (DI * 16);
    float run = 0.f;
#pragma unroll 8
    for (int c = 0; c < NCH; c++) {
        size_t i = (((size_t)(dirb * NCH + c)) * DI + dd) * 16 + s;
        float tmp = Q[i];
        Q[i] = run;
        run = P[i] * run + tmp;
    }
}

// p3: replay each chunk from its exact initial state; in-thread C-contraction;
// fused (+xs*D)*silu(z) epilogue.
__global__ void k_scan_p3(const float* __restrict__ DBLF, const float* __restrict__ DBLB,
                          const float* __restrict__ XSF,  const float* __restrict__ XSB,
                          const float* __restrict__ XZF,  const float* __restrict__ XZB,
                          const float* __restrict__ fWdt, const float* __restrict__ fbdt,
                          const float* __restrict__ bWdt, const float* __restrict__ bbdt,
                          const float* __restrict__ fAlog, const float* __restrict__ bAlog,
                          const float* __restrict__ fD,    const float* __restrict__ bD,
                          const float* __restrict__ Q,
                          float* __restrict__ YSF, float* __restrict__ YSB) {
    int t = blockIdx.x * blockDim.x + threadIdx.x;   // 196608
    int d = t % DI;
    int g = t / DI;
    int chunk = g & (NCH - 1);
    int dirb = g >> 8;
    int b = dirb & 1, dir = dirb >> 1;

    const float* DBL = dir ? DBLB : DBLF;
    const float* XS  = dir ? XSB  : XSF;
    const float* XZ  = dir ? XZB  : XZF;
    const float* al  = (dir ? bAlog : fAlog) + d * DS;
    const float* wdt = (dir ? bWdt : fWdt) + d * 6;
    float bdtv = (dir ? bbdt : fbdt)[d];
    float Dp = dir ? bD[d] : fD[d];
    float* Y = dir ? YSB : YSF;

    float wd[6];
#pragma unroll
    for (int r = 0; r < 6; r++) wd[r] = wdt[r];
    float A[16], h[16];
#pragma unroll
    for (int s = 0; s < 16; s++) A[s] = -__expf(al[s]);
    const float4* qq = (const float4*)(Q + ((size_t)g * DI + d) * 16);
#pragma unroll
    for (int v = 0; v < 4; v++) {
        float4 q = qq[v];
        h[4*v] = q.x; h[4*v+1] = q.y; h[4*v+2] = q.z; h[4*v+3] = q.w;
    }

    int l = dir ? (L_SEQ - 1 - chunk * CHUNK) : chunk * CHUNK;
    int stp = dir ? -1 : 1;

    for (int i = 0; i < CHUNK; i++) {
        size_t p = (size_t)b * L_SEQ + l;
        const float* row = DBL + p * LDBL;
        float dtv = bdtv;
#pragma unroll
        for (int r = 0; r < 6; r++) dtv += row[r] * wd[r];
        float del = softplus_f(dtv);
        float xs  = XS[p * DI + d];
        float z   = XZ[p * 384 + 192 + d];
        const float4* bm = (const float4*)(row + 8);
        float4 B0 = bm[0], B1 = bm[1], B2 = bm[2], B3 = bm[3];
        float4 C0 = bm[4], C1 = bm[5], C2 = bm[6], C3 = bm[7];
        float Bm[16] = {B0.x,B0.y,B0.z,B0.w, B1.x,B1.y,B1.z,B1.w,
                        B2.x,B2.y,B2.z,B2.w, B3.x,B3.y,B3.z,B3.w};
        float Cm[16] = {C0.x,C0.y,C0.z,C0.w, C1.x,C1.y,C1.z,C1.w,
                        C2.x,C2.y,C2.z,C2.w, C3.x,C3.y,C3.z,C3.w};
        float dx = del * xs;
        float pr = 0.f;
#pragma unroll
        for (int s = 0; s < 16; s++) {
            float dA = __expf(del * A[s]);
            h[s] = dA * h[s] + dx * Bm[s];
            pr += h[s] * Cm[s];
        }
        Y[p * DI + d] = (pr + xs * Dp) * silu_f(z);
        l += stp;
    }
}

// ---------------------------------------------------------------------------
// K9: x2 = x + gamma1*(yo + x1); store XMID (B,96,L); XM2 = ln_cf(x2) planar.
// ---------------------------------------------------------------------------
__global__ void k_mid(const float* __restrict__ x, const float* __restrict__ YO,
                      const float* __restrict__ X1,
                      const float* __restrict__ gamma1,
                      const float* __restrict__ ln1w, const float* __restrict__ ln1b,
                      float* __restrict__ XMID, float* __restrict__ XM2) {
    int p = blockIdx.x * blockDim.x + threadIdx.x;
    if (p >= NPOS) return;
    int b = p >> 12, l = p & (L_SEQ - 1);
    const float* yop = YO + (size_t)p * DIM;
    float s = 0.f, ss = 0.f;
    for (int c = 0; c < DIM; c++) {
        size_t idx = ((size_t)b * DIM + c) * L_SEQ + l;
        float v = x[idx] + gamma1[c] * (yop[c] + X1[idx]);
        XMID[idx] = v;
        s += v; ss += v * v;
    }
    float u = s / DIM;
    float r = rsqrtf(ss / DIM - u * u + 1e-6f);
    for (int c = 0; c < DIM; c++) {
        size_t idx = ((size_t)b * DIM + c) * L_SEQ + l;
        float v = XMID[idx];
        XM2[idx] = ln1w[c] * (v - u) * r + ln1b[c];
    }
}

// ---------------------------------------------------------------------------
// K11: fused 3x dilated depthwise 3x3 conv + GELU gate.
// ---------------------------------------------------------------------------
__global__ void k_msff(const float* __restrict__ H5,
                       const float* __restrict__ dw1, const float* __restrict__ dw2,
                       const float* __restrict__ dw3, float* __restrict__ G) {
    int i = blockIdx.x * blockDim.x + threadIdx.x;   // B*HID*4096
    int l = i & (L_SEQ - 1);
    int tmp = i >> 12;
    int c = tmp % HID;
    int b = tmp / HID;
    int y = l >> 6, xc = l & 63;
    const float* p1 = H5 + ((size_t)b * 576 + c) * L_SEQ;
    const float* p2 = H5 + ((size_t)b * 576 + HID + c) * L_SEQ;
    const float* p3 = H5 + ((size_t)b * 576 + 2 * HID + c) * L_SEQ;
    float a1 = 0.f, a2 = 0.f, a3 = 0.f;
#pragma unroll
    for (int ky = 0; ky < 3; ky++) {
#pragma unroll
        for (int kx = 0; kx < 3; kx++) {
            float w1 = dw1[(c * 3 + ky) * 3 + kx];
            float w2 = dw2[(c * 3 + ky) * 3 + kx];
            float w3 = dw3[(c * 3 + ky) * 3 + kx];
            int y1 = y + (ky - 1), x1 = xc + (kx - 1);
            if (y1 >= 0 && y1 < 64 && x1 >= 0 && x1 < 64) a1 += w1 * p1[y1 * 64 + x1];
            int y2 = y + (ky - 1) * 2, x2 = xc + (kx - 1) * 2;
            if (y2 >= 0 && y2 < 64 && x2 >= 0 && x2 < 64) a2 += w2 * p2[y2 * 64 + x2];
            int y3 = y + (ky - 1) * 3, x3 = xc + (kx - 1) * 3;
            if (y3 >= 0 && y3 < 64 && x3 >= 0 && x3 < 64) a3 += w3 * p3[y3 * 64 + x3];
        }
    }
    float ge = 0.5f * a1 * (1.f + erff(a1 * 0.70710678118f));
    G[((size_t)b * HID + c) * L_SEQ + l] = ge * a2 * a3;
}

// ---------------------------------------------------------------------------
// K13: out = XMID + gamma2[c] * OXM  (f32 output)
// ---------------------------------------------------------------------------
__global__ void k_out(const float* __restrict__ XMID, const float* __restrict__ OXM,
                      const float* __restrict__ gamma2, float* __restrict__ out) {
    int i = blockIdx.x * blockDim.x + threadIdx.x;   // B*96*4096
    int c = (i >> 12) % DIM;
    out[i] = XMID[i] + gamma2[c] * OXM[i];
}

// ---------------------------------------------------------------------------
extern "C" void kernel_launch(void* const* d_in, const int* in_sizes, int n_in,
                              void* d_out, int out_size, void* d_ws, size_t ws_size,
                              hipStream_t stream) {
    const float* x      = (const float*)d_in[0];
    const float* gamma1 = (const float*)d_in[1];
    const float* gamma2 = (const float*)d_in[2];
    const float* ln1w   = (const float*)d_in[3];
    const float* ln1b   = (const float*)d_in[4];
    const float* mnw    = (const float*)d_in[5];
    const float* mnb    = (const float*)d_in[6];
    const float* fWin   = (const float*)d_in[7];
    const float* fconvw = (const float*)d_in[8];
    const float* fconvb = (const float*)d_in[9];
    const float* fWx    = (const float*)d_in[10];
    const float* fWdt   = (const float*)d_in[11];
    const float* fbdt   = (const float*)d_in[12];
    const float* fAlog  = (const float*)d_in[13];
    const float* fD     = (const float*)d_in[14];
    const float* bWin   = (const float*)d_in[15];
    const float* bconvw = (const float*)d_in[16];
    const float* bconvb = (const float*)d_in[17];
    const float* bWx    = (const float*)d_in[18];
    const float* bWdt   = (const float*)d_in[19];
    const float* bbdt   = (const float*)d_in[20];
    const float* bAlog  = (const float*)d_in[21];
    const float* bD     = (const float*)d_in[22];
    const float* Wout   = (const float*)d_in[23];
    const float* mwin   = (const float*)d_in[24];
    const float* mdw1   = (const float*)d_in[25];
    const float* mdw2   = (const float*)d_in[26];
    const float* mdw3   = (const float*)d_in[27];
    const float* mwout  = (const float*)d_in[28];
    float* out = (float*)d_out;

    float* ws = (float*)d_ws;
    float* XN   = ws;                       // 786432
    float* X1   = XN   + 786432;            // 786432
    float* XZF  = X1   + 786432;            // 3145728
    float* XZB  = XZF  + 3145728;           // 3145728
    float* XSF  = XZB  + 3145728;           // 1572864
    float* XSB  = XSF  + 1572864;           // 1572864
    float* DBLF = XSB  + 1572864;           // 327680 (NPOS*40)
    float* DBLB = DBLF + 327680;            // 327680
    float* YSF  = DBLB + 327680;            // 1572864
    float* YSB  = YSF  + 1572864;           // 1572864
    float* Qb   = YSB  + 1572864;           // 3145728 (scan chunk states)
    // total: 17,956,864 floats ~= 72 MB
    // overlays:
    float* Pb   = YSF;                      // 3145728 (YS not written until p3; P dead after p2)
    float* YO   = XN;                       // 786432  (XN dead after in-proj)
    float* XMID = Qb;                       // 786432  (Q dead after p3)
    float* XM2  = Qb + 786432;              // 786432
    float* H576 = XZF;                      // 4718592 (XZ dead after p3)
    float* G    = YSF;                      // 1572864 (YS dead after out-proj)
    float* OXM  = XSF;                      // 786432  (XS dead after p3)

    // 1. double LN
    k_ln12<<<NPOS / 256, 256, 0, stream>>>(x, ln1w, ln1b, mnw, mnb, X1, XN);
    // 2-3. in-projections
    gemm_nt<<<dim3(128, 6), 256, 0, stream>>>(XN, nullptr, fWin, XZF, NPOS, 384, DIM, 384, 0);
    gemm_nt<<<dim3(128, 6), 256, 0, stream>>>(XN, nullptr, bWin, XZB, NPOS, 384, DIM, 384, 0);
    // 4-5. causal / anti-causal dwconv + silu
    k_conv<<<NPOS * DI / 256, 256, 0, stream>>>(XZF, fconvw, fconvb, XSF, 0);
    k_conv<<<NPOS * DI / 256, 256, 0, stream>>>(XZB, bconvw, bconvb, XSB, 1);
    // 6-7. x_dbl projections (padded LDBL=40 rows: dt[0:6), B[8:24), C[24:40))
    gemm_nt<<<dim3(128, 1), 256, 0, stream>>>(XSF, nullptr, fWx, DBLF, NPOS, 38, DI, LDBL, 1);
    gemm_nt<<<dim3(128, 1), 256, 0, stream>>>(XSB, nullptr, bWx, DBLB, NPOS, 38, DI, LDBL, 1);
    // 8-10. chunked parallel scan (16 states/thread, CHUNK=16, delta inline)
    k_scan_p1<<<NREC * NCH / 256, 256, 0, stream>>>(DBLF, DBLB, XSF, XSB,
                                                    fWdt, fbdt, bWdt, bbdt,
                                                    fAlog, bAlog, Pb, Qb);
    k_scan_p2<<<NREC * 16 / 256, 256, 0, stream>>>(Pb, Qb);
    k_scan_p3<<<NREC * NCH / 256, 256, 0, stream>>>(DBLF, DBLB, XSF, XSB, XZF, XZB,
                                                    fWdt, fbdt, bWdt, bbdt,
                                                    fAlog, bAlog, fD, bD, Qb,
                                                    YSF, YSB);
    // 11. out-projection with fused yf+yb add
    gemm_nt<<<dim3(128, 2), 256, 0, stream>>>(YSF, YSB, Wout, YO, NPOS, DIM, DI, DIM, 0);
    // 12. residual + LN
    k_mid<<<NPOS / 256, 256, 0, stream>>>(x, YO, X1, gamma1, ln1w, ln1b, XMID, XM2);
    // 13. msff in-projection (planar)
    gemm_nn<<<dim3(9, 64, 2), 256, 0, stream>>>(mwin, XM2, H576, 576, L_SEQ, DIM,
                                                (size_t)DIM * L_SEQ, (size_t)576 * L_SEQ);
    // 14. fused dilated dwconvs + GELU gate
    k_msff<<<BATCH * HID * L_SEQ / 256, 256, 0, stream>>>(H576, mdw1, mdw2, mdw3, G);
    // 15. msff out-projection
    gemm_nn<<<dim3(2, 64, 2), 256, 0, stream>>>(mwout, G, OXM, DIM, L_SEQ, HID,
                                                (size_t)HID * L_SEQ, (size_t)DIM * L_SEQ);
    // 16. final residual -> f32 out
    k_out<<<BATCH * DIM * L_SEQ / 256, 256, 0, stream>>>(XMID, OXM, gamma2, out);
}

// Round 6
// 364.535 us; speedup vs baseline: 4.9346x; 1.1957x over previous
//
#include <hip/hip_runtime.h>
#include <hip/hip_bf16.h>
#include <math.h>

typedef __hip_bfloat16 bf16;
typedef _Float16 f16;
typedef f16  f16x8  __attribute__((ext_vector_type(8)));
typedef short short8 __attribute__((ext_vector_type(8)));
typedef float floatx4 __attribute__((ext_vector_type(4)));

#define L_SEQ 4096
#define BATCH 2
#define DIM   96
#define DI    192
#define DS    16
#define HID   192
#define NPOS  (BATCH * L_SEQ)   // 8192
#define NCH   512               // chunks per sequence
#define CHUNK 8                 // L_SEQ / NCH
#define NREC  (2 * BATCH * DI)  // 768 recurrences (dir,b,d)
#define LDBL  40                // padded x_dbl row stride: dt[0:6), B[8:24), C[24:40)
#define LOG2E 1.44269504088896f

__device__ __forceinline__ float silu_f(float x) { return x / (1.f + __expf(-x)); }
__device__ __forceinline__ float softplus_f(float x) {
    // max(x,0) + log(1+exp(-|x|)) with fast transcendentals
    return fmaxf(x, 0.f) + __logf(1.f + __expf(-fabsf(x)));
}

// ---------------------------------------------------------------------------
// K0: cast all NT-GEMM weights fp32 -> bf16 arena.
// layout: fWin[0,36864) bWin[36864,73728) fWx[73728,81024) bWx[81024,88320)
//         Wout[88320,106752)
// ---------------------------------------------------------------------------
__global__ void k_cast_w(const float* __restrict__ fWin, const float* __restrict__ bWin,
                         const float* __restrict__ fWx,  const float* __restrict__ bWx,
                         const float* __restrict__ Wout, bf16* __restrict__ arena) {
    int i = blockIdx.x * blockDim.x + threadIdx.x;   // 106752
    float v;
    if (i < 36864)       v = fWin[i];
    else if (i < 73728)  v = bWin[i - 36864];
    else if (i < 81024)  v = fWx[i - 73728];
    else if (i < 88320)  v = bWx[i - 81024];
    else                 v = Wout[i - 88320];
    arena[i] = __float2bfloat16(v);
}

// ---------------------------------------------------------------------------
// K1: double layernorm. x (B,96,L) f32 -> X1 (B,96,L) f32, XNbf (B*L,96) bf16.
// ---------------------------------------------------------------------------
__global__ void k_ln12(const float* __restrict__ x,
                       const float* __restrict__ ln1w, const float* __restrict__ ln1b,
                       const float* __restrict__ mnw,  const float* __restrict__ mnb,
                       float* __restrict__ X1, bf16* __restrict__ XNbf) {
    int p = blockIdx.x * blockDim.x + threadIdx.x;   // 0..NPOS-1
    if (p >= NPOS) return;
    int b = p >> 12, l = p & (L_SEQ - 1);
    const float* xb = x + (size_t)b * DIM * L_SEQ + l;
    float s = 0.f, ss = 0.f;
    for (int c = 0; c < DIM; c++) { float v = xb[(size_t)c * L_SEQ]; s += v; ss += v * v; }
    float u = s / DIM;
    float r = rsqrtf(ss / DIM - u * u + 1e-6f);
    float s2 = 0.f, ss2 = 0.f;
    for (int c = 0; c < DIM; c++) {
        float v = xb[(size_t)c * L_SEQ];
        float t = ln1w[c] * (v - u) * r + ln1b[c];
        X1[((size_t)b * DIM + c) * L_SEQ + l] = t;
        s2 += t; ss2 += t * t;
    }
    float u2 = s2 / DIM;
    float r2 = rsqrtf(ss2 / DIM - u2 * u2 + 1e-5f);
    bf16* xnp = XNbf + (size_t)p * DIM;
    for (int c = 0; c < DIM; c++) {
        float t = X1[((size_t)b * DIM + c) * L_SEQ + l];
        xnp[c] = __float2bfloat16((t - u2) * r2 * mnw[c] + mnb[c]);
    }
}

// ---------------------------------------------------------------------------
// MFMA NT GEMM: C[M,N] = A[M,K](bf16) @ W[N,K](bf16)^T, fp32 out.
// Direct-from-global fragments (no LDS). M mult of 64, K mult of 32, N guarded.
// block 256 = 4 waves; block tile 64m x 64n; wave: 16m x 64n (4 MFMA tiles).
// ldc = out row stride; pad6: out cols >=6 shifted +2 (LDBL layout).
// ---------------------------------------------------------------------------
__global__ void mfma_nt(const bf16* __restrict__ A, const bf16* __restrict__ W,
                        float* __restrict__ C, int M, int N, int K, int ldc, int pad6) {
    int wave = threadIdx.x >> 6, lane = threadIdx.x & 63;
    int m0 = blockIdx.x * 64 + wave * 16;
    int n0 = blockIdx.y * 64;
    int lm = lane & 15, quad = lane >> 4;
    const short* Ap = (const short*)A + (size_t)(m0 + lm) * K + quad * 8;
    const short* Wp = (const short*)W;
    floatx4 acc[4];
#pragma unroll
    for (int t = 0; t < 4; t++) acc[t] = (floatx4){0.f, 0.f, 0.f, 0.f};
    for (int k0 = 0; k0 < K; k0 += 32) {
        short8 a = *(const short8*)(Ap + k0);
#pragma unroll
        for (int t = 0; t < 4; t++) {
            int n = n0 + t * 16 + lm;
            short8 b;
            if (n < N) b = *(const short8*)(Wp + (size_t)n * K + k0 + quad * 8);
            else       b = (short8){0,0,0,0,0,0,0,0};
            acc[t] = __builtin_amdgcn_mfma_f32_16x16x32_bf16(a, b, acc[t], 0, 0, 0);
        }
    }
#pragma unroll
    for (int t = 0; t < 4; t++) {
        int n = n0 + t * 16 + lm;
        if (n < N) {
            int nn = (pad6 && n >= 6) ? n + 2 : n;
#pragma unroll
            for (int r = 0; r < 4; r++) {
                int m = m0 + quad * 4 + r;
                C[(size_t)m * ldc + nn] = acc[t][r];
            }
        }
    }
}

// ---------------------------------------------------------------------------
// GEMM NN (batched, fp32): C[b][M,N] = W[M,K] @ Bmat[b][K,N].  (msff pair)
// ---------------------------------------------------------------------------
__global__ void gemm_nn(const float* __restrict__ W, const float* __restrict__ Bm,
                        float* __restrict__ C, int M, int N, int K,
                        size_t strideB, size_t strideC) {
    __shared__ float As[32][65];
    __shared__ float Bs[32][65];
    int m0 = blockIdx.x * 64, n0 = blockIdx.y * 64;
    const float* Bp = Bm + strideB * blockIdx.z;
    float* Cp = C + strideC * blockIdx.z;
    int t = threadIdx.x;
    int tx = t & 15, ty = t >> 4;
    int lrow = t >> 2, lk = (t & 3) * 8;     // W load
    int bk = t >> 3, bn = (t & 7) * 8;       // B load
    float acc[4][4] = {};
    for (int k0 = 0; k0 < K; k0 += 32) {
        {
            int m = m0 + lrow;
            float v[8];
            if (m < M) {
                const float* wp = W + (size_t)m * K + k0 + lk;
#pragma unroll
                for (int j = 0; j < 8; j++) v[j] = wp[j];
            } else {
#pragma unroll
                for (int j = 0; j < 8; j++) v[j] = 0.f;
            }
#pragma unroll
            for (int j = 0; j < 8; j++) As[lk + j][lrow] = v[j];
        }
        {
            const float* bp = Bp + (size_t)(k0 + bk) * N + n0 + bn;
#pragma unroll
            for (int j = 0; j < 8; j++) Bs[bk][bn + j] = bp[j];
        }
        __syncthreads();
#pragma unroll
        for (int k = 0; k < 32; k++) {
            float a[4], bb[4];
#pragma unroll
            for (int i = 0; i < 4; i++) a[i] = As[k][ty * 4 + i];
#pragma unroll
            for (int j = 0; j < 4; j++) bb[j] = Bs[k][tx * 4 + j];
#pragma unroll
            for (int i = 0; i < 4; i++)
#pragma unroll
                for (int j = 0; j < 4; j++) acc[i][j] += a[i] * bb[j];
        }
        __syncthreads();
    }
#pragma unroll
    for (int i = 0; i < 4; i++) {
        int m = m0 + ty * 4 + i;
        if (m < M) {
#pragma unroll
            for (int j = 0; j < 4; j++) Cp[(size_t)m * N + n0 + tx * 4 + j] = acc[i][j];
        }
    }
}

// ---------------------------------------------------------------------------
// K3: causal/anti-causal dwconv1d k=4 + bias + silu -> bf16 XS.
// ---------------------------------------------------------------------------
__global__ void k_conv(const float* __restrict__ XZ, const float* __restrict__ convw,
                       const float* __restrict__ convb, bf16* __restrict__ XS, int dirb) {
    int i = blockIdx.x * blockDim.x + threadIdx.x;   // NPOS*DI
    int d = i % DI;
    int p = i / DI;
    int b = p >> 12, l = p & (L_SEQ - 1);
    float acc = convb[d];
    if (!dirb) {
#pragma unroll
        for (int k = 0; k < 4; k++) {
            int ls = l - 3 + k;
            if (ls >= 0) acc += convw[d * 4 + k] * XZ[((size_t)(b * L_SEQ + ls)) * 384 + d];
        }
    } else {
#pragma unroll
        for (int k = 0; k < 4; k++) {
            int ls = l + 3 - k;
            if (ls < L_SEQ) acc += convw[d * 4 + k] * XZ[((size_t)(b * L_SEQ + ls)) * 384 + d];
        }
    }
    XS[(size_t)p * DI + d] = __float2bfloat16(silu_f(acc));
}

// ---------------------------------------------------------------------------
// Chunked parallel scan, 16 states per thread, delta inline, P/Q in fp16.
// Thread map: t = g*DI + d, g = dirb*NCH + chunk, dirb = dir*2+b.
// P/Q layout: [g][d][s] (16 contiguous f16 per thread).
// ---------------------------------------------------------------------------
__global__ void k_scan_p1(const float* __restrict__ DBLF, const float* __restrict__ DBLB,
                          const bf16* __restrict__ XSF,  const bf16* __restrict__ XSB,
                          const float* __restrict__ fWdt, const float* __restrict__ fbdt,
                          const float* __restrict__ bWdt, const float* __restrict__ bbdt,
                          const float* __restrict__ fAlog, const float* __restrict__ bAlog,
                          f16* __restrict__ P, f16* __restrict__ Q) {
    int t = blockIdx.x * blockDim.x + threadIdx.x;   // 393216
    int d = t % DI;
    int g = t / DI;                                   // 0..2047
    int chunk = g & (NCH - 1);
    int dirb = g >> 9;
    int b = dirb & 1, dir = dirb >> 1;

    const float* DBL = dir ? DBLB : DBLF;
    const bf16*  XS  = dir ? XSB  : XSF;
    const float* al  = (dir ? bAlog : fAlog) + d * DS;
    const float* wdt = (dir ? bWdt : fWdt) + d * 6;
    float bdtv = (dir ? bbdt : fbdt)[d];

    float wd[6];
#pragma unroll
    for (int r = 0; r < 6; r++) wd[r] = wdt[r];
    float A2[16], h[16];
#pragma unroll
    for (int s = 0; s < 16; s++) { A2[s] = -__expf(al[s]) * LOG2E; h[s] = 0.f; }

    int l = dir ? (L_SEQ - 1 - chunk * CHUNK) : chunk * CHUNK;
    int stp = dir ? -1 : 1;
    float sumdel = 0.f;

    for (int i = 0; i < CHUNK; i++) {
        size_t p = (size_t)b * L_SEQ + l;
        const float* row = DBL + p * LDBL;
        float dtv = bdtv;
#pragma unroll
        for (int r = 0; r < 6; r++) dtv += row[r] * wd[r];
        float del = softplus_f(dtv);
        float xs  = __bfloat162float(XS[p * DI + d]);
        const float4* bm = (const float4*)(row + 8);
        float4 B0 = bm[0], B1 = bm[1], B2 = bm[2], B3 = bm[3];
        float Bm[16] = {B0.x,B0.y,B0.z,B0.w, B1.x,B1.y,B1.z,B1.w,
                        B2.x,B2.y,B2.z,B2.w, B3.x,B3.y,B3.z,B3.w};
        float dx = del * xs;
        sumdel += del;
#pragma unroll
        for (int s = 0; s < 16; s++) {
            float dA = exp2f(del * A2[s]);
            h[s] = dA * h[s] + dx * Bm[s];
        }
        l += stp;
    }
    size_t idx = ((size_t)g * DI + d) * 16;
    f16x8 q0, q1, p0, p1;
#pragma unroll
    for (int j = 0; j < 8; j++) {
        q0[j] = (f16)h[j];
        q1[j] = (f16)h[8 + j];
        p0[j] = (f16)exp2f(A2[j] * sumdel);
        p1[j] = (f16)exp2f(A2[8 + j] * sumdel);
    }
    *(f16x8*)(Q + idx)     = q0;
    *(f16x8*)(Q + idx + 8) = q1;
    *(f16x8*)(P + idx)     = p0;
    *(f16x8*)(P + idx + 8) = p1;
}

// p2: per (dirb,d,s), compose chunk operators; Q[chunk] <- chunk's INITIAL state.
__global__ void k_scan_p2(const f16* __restrict__ P, f16* __restrict__ Q) {
    int u = blockIdx.x * blockDim.x + threadIdx.x;   // 12288
    int s = u & 15;
    int dd = (u >> 4) % DI;
    int dirb = u / (DI * 16);
    float run = 0.f;
#pragma unroll 8
    for (int c = 0; c < NCH; c++) {
        size_t i = (((size_t)(dirb * NCH + c)) * DI + dd) * 16 + s;
        float tmp = (float)Q[i];
        Q[i] = (f16)run;
        run = (float)P[i] * run + tmp;
    }
}

// p3: replay each chunk from its initial state; in-thread C-contraction;
// fused (+xs*D)*silu(z) epilogue.
__global__ void k_scan_p3(const float* __restrict__ DBLF, const float* __restrict__ DBLB,
                          const bf16* __restrict__ XSF,  const bf16* __restrict__ XSB,
                          const float* __restrict__ XZF,  const float* __restrict__ XZB,
                          const float* __restrict__ fWdt, const float* __restrict__ fbdt,
                          const float* __restrict__ bWdt, const float* __restrict__ bbdt,
                          const float* __restrict__ fAlog, const float* __restrict__ bAlog,
                          const float* __restrict__ fD,    const float* __restrict__ bD,
                          const f16* __restrict__ Q,
                          float* __restrict__ YSF, float* __restrict__ YSB) {
    int t = blockIdx.x * blockDim.x + threadIdx.x;   // 393216
    int d = t % DI;
    int g = t / DI;
    int chunk = g & (NCH - 1);
    int dirb = g >> 9;
    int b = dirb & 1, dir = dirb >> 1;

    const float* DBL = dir ? DBLB : DBLF;
    const bf16*  XS  = dir ? XSB  : XSF;
    const float* XZ  = dir ? XZB  : XZF;
    const float* al  = (dir ? bAlog : fAlog) + d * DS;
    const float* wdt = (dir ? bWdt : fWdt) + d * 6;
    float bdtv = (dir ? bbdt : fbdt)[d];
    float Dp = dir ? bD[d] : fD[d];
    float* Y = dir ? YSB : YSF;

    float wd[6];
#pragma unroll
    for (int r = 0; r < 6; r++) wd[r] = wdt[r];
    float A2[16], h[16];
#pragma unroll
    for (int s = 0; s < 16; s++) A2[s] = -__expf(al[s]) * LOG2E;
    size_t idx = ((size_t)g * DI + d) * 16;
    f16x8 q0 = *(const f16x8*)(Q + idx);
    f16x8 q1 = *(const f16x8*)(Q + idx + 8);
#pragma unroll
    for (int j = 0; j < 8; j++) { h[j] = (float)q0[j]; h[8 + j] = (float)q1[j]; }

    int l = dir ? (L_SEQ - 1 - chunk * CHUNK) : chunk * CHUNK;
    int stp = dir ? -1 : 1;

    for (int i = 0; i < CHUNK; i++) {
        size_t p = (size_t)b * L_SEQ + l;
        const float* row = DBL + p * LDBL;
        float dtv = bdtv;
#pragma unroll
        for (int r = 0; r < 6; r++) dtv += row[r] * wd[r];
        float del = softplus_f(dtv);
        float xs  = __bfloat162float(XS[p * DI + d]);
        float z   = XZ[p * 384 + 192 + d];
        const float4* bm = (const float4*)(row + 8);
        float4 B0 = bm[0], B1 = bm[1], B2 = bm[2], B3 = bm[3];
        float4 C0 = bm[4], C1 = bm[5], C2 = bm[6], C3 = bm[7];
        float Bm[16] = {B0.x,B0.y,B0.z,B0.w, B1.x,B1.y,B1.z,B1.w,
                        B2.x,B2.y,B2.z,B2.w, B3.x,B3.y,B3.z,B3.w};
        float Cm[16] = {C0.x,C0.y,C0.z,C0.w, C1.x,C1.y,C1.z,C1.w,
                        C2.x,C2.y,C2.z,C2.w, C3.x,C3.y,C3.z,C3.w};
        float dx = del * xs;
        float pr = 0.f;
#pragma unroll
        for (int s = 0; s < 16; s++) {
            float dA = exp2f(del * A2[s]);
            h[s] = dA * h[s] + dx * Bm[s];
            pr += h[s] * Cm[s];
        }
        Y[p * DI + d] = (pr + xs * Dp) * silu_f(z);
        l += stp;
    }
}

// ---------------------------------------------------------------------------
// K7: YSUMbf = bf16(YSF + YSB)
// ---------------------------------------------------------------------------
__global__ void k_cast_ysum(const float* __restrict__ YSF, const float* __restrict__ YSB,
                            bf16* __restrict__ YSUM) {
    int i = blockIdx.x * blockDim.x + threadIdx.x;   // NPOS*DI
    YSUM[i] = __float2bfloat16(YSF[i] + YSB[i]);
}

// ---------------------------------------------------------------------------
// K9: x2 = x + gamma1*(yo + x1); store XMID planar f32; XM2 = ln_cf(x2) planar f32.
// ---------------------------------------------------------------------------
__global__ void k_mid(const float* __restrict__ x, const float* __restrict__ YO,
                      const float* __restrict__ X1,
                      const float* __restrict__ gamma1,
                      const float* __restrict__ ln1w, const float* __restrict__ ln1b,
                      float* __restrict__ XMID, float* __restrict__ XM2) {
    int p = blockIdx.x * blockDim.x + threadIdx.x;
    if (p >= NPOS) return;
    int b = p >> 12, l = p & (L_SEQ - 1);
    const float* yop = YO + (size_t)p * DIM;
    float s = 0.f, ss = 0.f;
    for (int c = 0; c < DIM; c++) {
        size_t idx = ((size_t)b * DIM + c) * L_SEQ + l;
        float v = x[idx] + gamma1[c] * (yop[c] + X1[idx]);
        XMID[idx] = v;
        s += v; ss += v * v;
    }
    float u = s / DIM;
    float r = rsqrtf(ss / DIM - u * u + 1e-6f);
    for (int c = 0; c < DIM; c++) {
        size_t idx = ((size_t)b * DIM + c) * L_SEQ + l;
        float v = XMID[idx];
        XM2[idx] = ln1w[c] * (v - u) * r + ln1b[c];
    }
}

// ---------------------------------------------------------------------------
// K11: fused 3x dilated depthwise 3x3 conv + GELU gate (fp32 planar).
// ---------------------------------------------------------------------------
__global__ void k_msff(const float* __restrict__ H5,
                       const float* __restrict__ dw1, const float* __restrict__ dw2,
                       const float* __restrict__ dw3, float* __restrict__ G) {
    int i = blockIdx.x * blockDim.x + threadIdx.x;   // B*HID*4096
    int l = i & (L_SEQ - 1);
    int tmp = i >> 12;
    int c = tmp % HID;
    int b = tmp / HID;
    int y = l >> 6, xc = l & 63;
    const float* p1 = H5 + ((size_t)b * 576 + c) * L_SEQ;
    const float* p2 = H5 + ((size_t)b * 576 + HID + c) * L_SEQ;
    const float* p3 = H5 + ((size_t)b * 576 + 2 * HID + c) * L_SEQ;
    float a1 = 0.f, a2 = 0.f, a3 = 0.f;
#pragma unroll
    for (int ky = 0; ky < 3; ky++) {
#pragma unroll
        for (int kx = 0; kx < 3; kx++) {
            float w1 = dw1[(c * 3 + ky) * 3 + kx];
            float w2 = dw2[(c * 3 + ky) * 3 + kx];
            float w3 = dw3[(c * 3 + ky) * 3 + kx];
            int y1 = y + (ky - 1), x1 = xc + (kx - 1);
            if (y1 >= 0 && y1 < 64 && x1 >= 0 && x1 < 64) a1 += w1 * p1[y1 * 64 + x1];
            int y2 = y + (ky - 1) * 2, x2 = xc + (kx - 1) * 2;
            if (y2 >= 0 && y2 < 64 && x2 >= 0 && x2 < 64) a2 += w2 * p2[y2 * 64 + x2];
            int y3 = y + (ky - 1) * 3, x3 = xc + (kx - 1) * 3;
            if (y3 >= 0 && y3 < 64 && x3 >= 0 && x3 < 64) a3 += w3 * p3[y3 * 64 + x3];
        }
    }
    float ge = 0.5f * a1 * (1.f + erff(a1 * 0.70710678118f));
    G[((size_t)b * HID + c) * L_SEQ + l] = ge * a2 * a3;
}

// ---------------------------------------------------------------------------
// K13: out = XMID + gamma2[c] * OXM  (f32 output)
// ---------------------------------------------------------------------------
__global__ void k_out(const float* __restrict__ XMID, const float* __restrict__ OXM,
                      const float* __restrict__ gamma2, float* __restrict__ out) {
    int i = blockIdx.x * blockDim.x + threadIdx.x;   // B*96*4096
    int c = (i >> 12) % DIM;
    out[i] = XMID[i] + gamma2[c] * OXM[i];
}

// ---------------------------------------------------------------------------
extern "C" void kernel_launch(void* const* d_in, const int* in_sizes, int n_in,
                              void* d_out, int out_size, void* d_ws, size_t ws_size,
                              hipStream_t stream) {
    const float* x      = (const float*)d_in[0];
    const float* gamma1 = (const float*)d_in[1];
    const float* gamma2 = (const float*)d_in[2];
    const float* ln1w   = (const float*)d_in[3];
    const float* ln1b   = (const float*)d_in[4];
    const float* mnw    = (const float*)d_in[5];
    const float* mnb    = (const float*)d_in[6];
    const float* fWin   = (const float*)d_in[7];
    const float* fconvw = (const float*)d_in[8];
    const float* fconvb = (const float*)d_in[9];
    const float* fWx    = (const float*)d_in[10];
    const float* fWdt   = (const float*)d_in[11];
    const float* fbdt   = (const float*)d_in[12];
    const float* fAlog  = (const float*)d_in[13];
    const float* fD     = (const float*)d_in[14];
    const float* bWin   = (const float*)d_in[15];
    const float* bconvw = (const float*)d_in[16];
    const float* bconvb = (const float*)d_in[17];
    const float* bWx    = (const float*)d_in[18];
    const float* bWdt   = (const float*)d_in[19];
    const float* bbdt   = (const float*)d_in[20];
    const float* bAlog  = (const float*)d_in[21];
    const float* bD     = (const float*)d_in[22];
    const float* Wout   = (const float*)d_in[23];
    const float* mwin   = (const float*)d_in[24];
    const float* mdw1   = (const float*)d_in[25];
    const float* mdw2   = (const float*)d_in[26];
    const float* mdw3   = (const float*)d_in[27];
    const float* mwout  = (const float*)d_in[28];
    float* out = (float*)d_out;

    float* ws = (float*)d_ws;
    // layout (float offsets):
    float* R0    = ws;                      // 786432  (XNbf first half; YO later)
    float* X1    = ws + 786432;             // 786432
    float* XZF   = ws + 1572864;            // 3145728
    float* XZB   = ws + 4718592;            // 3145728
    bf16*  XSFbf = (bf16*)(ws + 7864320);   // 1572864 bf16 (786432 slots)
    bf16*  XSBbf = (bf16*)(ws + 8650752);   // 1572864 bf16
    float* DBLF  = ws + 9437184;            // 327680
    float* DBLB  = ws + 9764864;            // 327680
    float* YSF   = ws + 10092544;           // 1572864
    float* YSB   = ws + 11665408;           // 1572864
    f16*   Qh    = (f16*)(ws + 13238272);   // 6291456 f16 (3145728 slots)
    bf16*  WAR   = (bf16*)(ws + 16384000);  // 106752 bf16 (53376 slots) -> end 16437376
    // overlays:
    bf16*  XNbf  = (bf16*)R0;               // dead after in-proj
    float* YO    = R0;                      // written at out-proj
    f16*   Ph    = (f16*)YSF;               // 6291456 f16 over YSF+YSB (dead after p2)
    bf16*  YSUM  = (bf16*)(ws + 6291456);   // XZB tail (XZ dead after p3)
    float* XMID  = ws + 13238272;           // over Qh (dead after p3)
    float* XM2   = ws + 14024704;
    float* H576  = XZF;                     // 4718592 (XZ dead after p3)
    float* G     = YSF;                     // 1572864 (YS dead after out-proj)
    float* OXM   = ws + 7864320;            // over XSbf (dead after p3)

    const bf16* fWinB = WAR;
    const bf16* bWinB = WAR + 36864;
    const bf16* fWxB  = WAR + 73728;
    const bf16* bWxB  = WAR + 81024;
    const bf16* WoutB = WAR + 88320;

    // 0. weight casts
    k_cast_w<<<417, 256, 0, stream>>>(fWin, bWin, fWx, bWx, Wout, WAR);
    // 1. double LN
    k_ln12<<<NPOS / 256, 256, 0, stream>>>(x, ln1w, ln1b, mnw, mnb, X1, XNbf);
    // 2-3. in-projections (MFMA)
    mfma_nt<<<dim3(128, 6), 256, 0, stream>>>(XNbf, fWinB, XZF, NPOS, 384, DIM, 384, 0);
    mfma_nt<<<dim3(128, 6), 256, 0, stream>>>(XNbf, bWinB, XZB, NPOS, 384, DIM, 384, 0);
    // 4-5. causal / anti-causal dwconv + silu -> bf16
    k_conv<<<NPOS * DI / 256, 256, 0, stream>>>(XZF, fconvw, fconvb, XSFbf, 0);
    k_conv<<<NPOS * DI / 256, 256, 0, stream>>>(XZB, bconvw, bconvb, XSBbf, 1);
    // 6-7. x_dbl projections (MFMA, padded LDBL rows)
    mfma_nt<<<dim3(128, 1), 256, 0, stream>>>(XSFbf, fWxB, DBLF, NPOS, 38, DI, LDBL, 1);
    mfma_nt<<<dim3(128, 1), 256, 0, stream>>>(XSBbf, bWxB, DBLB, NPOS, 38, DI, LDBL, 1);
    // 8-10. chunked parallel scan (CHUNK=8, fp16 P/Q)
    k_scan_p1<<<NREC * NCH / 256, 256, 0, stream>>>(DBLF, DBLB, XSFbf, XSBbf,
                                                    fWdt, fbdt, bWdt, bbdt,
                                                    fAlog, bAlog, Ph, Qh);
    k_scan_p2<<<NREC * 16 / 256, 256, 0, stream>>>(Ph, Qh);
    k_scan_p3<<<NREC * NCH / 256, 256, 0, stream>>>(DBLF, DBLB, XSFbf, XSBbf, XZF, XZB,
                                                    fWdt, fbdt, bWdt, bbdt,
                                                    fAlog, bAlog, fD, bD, Qh,
                                                    YSF, YSB);
    // 11. yf+yb -> bf16, then out-projection (MFMA)
    k_cast_ysum<<<NPOS * DI / 256, 256, 0, stream>>>(YSF, YSB, YSUM);
    mfma_nt<<<dim3(128, 2), 256, 0, stream>>>(YSUM, WoutB, YO, NPOS, DIM, DI, DIM, 0);
    // 12. residual + LN
    k_mid<<<NPOS / 256, 256, 0, stream>>>(x, YO, X1, gamma1, ln1w, ln1b, XMID, XM2);
    // 13. msff in-projection (planar fp32)
    gemm_nn<<<dim3(9, 64, 2), 256, 0, stream>>>(mwin, XM2, H576, 576, L_SEQ, DIM,
                                                (size_t)DIM * L_SEQ, (size_t)576 * L_SEQ);
    // 14. fused dilated dwconvs + GELU gate
    k_msff<<<BATCH * HID * L_SEQ / 256, 256, 0, stream>>>(H576, mdw1, mdw2, mdw3, G);
    // 15. msff out-projection (planar fp32)
    gemm_nn<<<dim3(2, 64, 2), 256, 0, stream>>>(mwout, G, OXM, DIM, L_SEQ, HID,
                                                (size_t)HID * L_SEQ, (size_t)DIM * L_SEQ);
    // 16. final residual -> f32 out
    k_out<<<BATCH * DIM * L_SEQ / 256, 256, 0, stream>>>(XMID, OXM, gamma2, out);
}

// Round 9
// 334.011 us; speedup vs baseline: 5.3855x; 1.0914x over previous
//
#include <hip/hip_runtime.h>
#include <hip/hip_bf16.h>
#include <math.h>

typedef __hip_bfloat16 bf16;
typedef _Float16 f16;
typedef f16  f16x8  __attribute__((ext_vector_type(8)));
typedef short short8 __attribute__((ext_vector_type(8)));
typedef float floatx4 __attribute__((ext_vector_type(4)));

#define L_SEQ 4096
#define BATCH 2
#define DIM   96
#define DI    192
#define DS    16
#define HID   192
#define NPOS  (BATCH * L_SEQ)   // 8192
#define NCH   512               // chunks per sequence
#define CHUNK 8                 // L_SEQ / NCH
#define NREC  (2 * BATCH * DI)  // 768 recurrences (dir,b,d)
#define LDBL  40                // padded x_dbl row stride: dt[0:6), B[8:24), C[24:40)
#define LOG2E 1.44269504088896f
#define TP    32                // positions per LN block

__device__ __forceinline__ float silu_f(float x) { return x / (1.f + __expf(-x)); }
__device__ __forceinline__ float softplus_f(float x) {
    return fmaxf(x, 0.f) + __logf(1.f + __expf(-fabsf(x)));
}
__device__ __forceinline__ float b2f(bf16 v) { return __bfloat162float(v); }

// ---------------------------------------------------------------------------
// K0: cast all GEMM weights fp32 -> bf16 arena.
// offsets: fWin 0 | bWin 36864 | fWx 73728 | bWx 81024 | Wout 88320 |
//          mwin 106752 | mwout 162048 | total 180480
// ---------------------------------------------------------------------------
__global__ void k_cast_w(const float* __restrict__ fWin, const float* __restrict__ bWin,
                         const float* __restrict__ fWx,  const float* __restrict__ bWx,
                         const float* __restrict__ Wout, const float* __restrict__ mwin,
                         const float* __restrict__ mwout, bf16* __restrict__ arena) {
    int i = blockIdx.x * blockDim.x + threadIdx.x;
    if (i >= 180480) return;
    float v;
    if (i < 36864)        v = fWin[i];
    else if (i < 73728)   v = bWin[i - 36864];
    else if (i < 81024)   v = fWx[i - 73728];
    else if (i < 88320)   v = bWx[i - 81024];
    else if (i < 106752)  v = Wout[i - 88320];
    else if (i < 162048)  v = mwin[i - 106752];
    else                  v = mwout[i - 162048];
    arena[i] = __float2bfloat16(v);
}

// ---------------------------------------------------------------------------
// K1: LDS-tiled double layernorm. 256 blocks x 256 thr, TP=32 positions/block.
// x (B,96,L) f32 -> X1 planar f32, XNbf (B*L,96) bf16 channel-last.
// ---------------------------------------------------------------------------
__global__ void k_ln12_t(const float* __restrict__ x,
                         const float* __restrict__ ln1w, const float* __restrict__ ln1b,
                         const float* __restrict__ mnw,  const float* __restrict__ mnb,
                         float* __restrict__ X1, bf16* __restrict__ XNbf) {
    __shared__ float xt[DIM][TP + 1];
    __shared__ float rs[8][TP], rss[8][TP];
    __shared__ float uu[TP], rr[TP];
    int blk = blockIdx.x;
    int p0 = blk * TP;
    int b = p0 >> 12, l0 = p0 & (L_SEQ - 1);
    int t = threadIdx.x;
    int tg = t >> 5, li = t & 31;

    for (int idx = t; idx < DIM * TP; idx += 256) {
        int c = idx >> 5, q = idx & 31;
        xt[c][q] = x[((size_t)(b * DIM + c)) * L_SEQ + l0 + q];
    }
    __syncthreads();
    {
        float s = 0.f, ss = 0.f;
        for (int c = tg; c < DIM; c += 8) { float v = xt[c][li]; s += v; ss += v * v; }
        rs[tg][li] = s; rss[tg][li] = ss;
    }
    __syncthreads();
    if (t < TP) {
        float s = 0.f, ss = 0.f;
#pragma unroll
        for (int g = 0; g < 8; g++) { s += rs[g][t]; ss += rss[g][t]; }
        float u = s / DIM;
        uu[t] = u; rr[t] = rsqrtf(ss / DIM - u * u + 1e-6f);
    }
    __syncthreads();
    {
        float u = uu[li], r = rr[li];
        float s2 = 0.f, ss2 = 0.f;
        for (int c = tg; c < DIM; c += 8) {
            float tv = ln1w[c] * (xt[c][li] - u) * r + ln1b[c];
            X1[((size_t)(b * DIM + c)) * L_SEQ + l0 + li] = tv;
            xt[c][li] = tv;
            s2 += tv; ss2 += tv * tv;
        }
        rs[tg][li] = s2; rss[tg][li] = ss2;
    }
    __syncthreads();
    if (t < TP) {
        float s = 0.f, ss = 0.f;
#pragma unroll
        for (int g = 0; g < 8; g++) { s += rs[g][t]; ss += rss[g][t]; }
        float u = s / DIM;
        uu[t] = u; rr[t] = rsqrtf(ss / DIM - u * u + 1e-5f);
    }
    __syncthreads();
    for (int idx = t; idx < DIM * TP; idx += 256) {
        int q = idx / DIM, c = idx % DIM;
        XNbf[(size_t)(p0 + q) * DIM + c] =
            __float2bfloat16((xt[c][q] - uu[q]) * rr[q] * mnw[c] + mnb[c]);
    }
}

// ---------------------------------------------------------------------------
// MFMA NT GEMM: C[M,N] = A[M,K](bf16) @ W[N,K](bf16)^T.
// obf: bf16 output, else fp32. pad6: out cols >=6 shifted +2 (LDBL layout).
// ---------------------------------------------------------------------------
__global__ void mfma_nt(const bf16* __restrict__ A, const bf16* __restrict__ W,
                        void* __restrict__ C, int M, int N, int K,
                        int ldc, int pad6, int obf) {
    int wave = threadIdx.x >> 6, lane = threadIdx.x & 63;
    int m0 = blockIdx.x * 64 + wave * 16;
    int n0 = blockIdx.y * 64;
    int lm = lane & 15, quad = lane >> 4;
    int am = m0 + lm;
    bool aval = am < M;
    const short* Ap = (const short*)A + (size_t)am * K + quad * 8;
    const short* Wp = (const short*)W;
    floatx4 acc[4];
#pragma unroll
    for (int t = 0; t < 4; t++) acc[t] = (floatx4){0.f, 0.f, 0.f, 0.f};
    for (int k0 = 0; k0 < K; k0 += 32) {
        short8 a = aval ? *(const short8*)(Ap + k0) : (short8){0,0,0,0,0,0,0,0};
#pragma unroll
        for (int t = 0; t < 4; t++) {
            int n = n0 + t * 16 + lm;
            short8 b = (n < N) ? *(const short8*)(Wp + (size_t)n * K + k0 + quad * 8)
                               : (short8){0,0,0,0,0,0,0,0};
            acc[t] = __builtin_amdgcn_mfma_f32_16x16x32_bf16(a, b, acc[t], 0, 0, 0);
        }
    }
#pragma unroll
    for (int t = 0; t < 4; t++) {
        int n = n0 + t * 16 + lm;
        if (n < N) {
            int nn = (pad6 && n >= 6) ? n + 2 : n;
#pragma unroll
            for (int r = 0; r < 4; r++) {
                int m = m0 + quad * 4 + r;
                if (m < M) {
                    if (obf) ((bf16*)C)[(size_t)m * ldc + nn] = __float2bfloat16(acc[t][r]);
                    else     ((float*)C)[(size_t)m * ldc + nn] = acc[t][r];
                }
            }
        }
    }
}

// ---------------------------------------------------------------------------
// MFMA NT, planar store: C_planar[(b*M + m)*4096 + l] with n = b*4096+l.
// ---------------------------------------------------------------------------
__global__ void mfma_nt_pl(const bf16* __restrict__ A, const bf16* __restrict__ Bm,
                           float* __restrict__ C, int M, int K) {
    int wave = threadIdx.x >> 6, lane = threadIdx.x & 63;
    int m0 = blockIdx.x * 64 + wave * 16;
    int n0 = blockIdx.y * 64;
    int lm = lane & 15, quad = lane >> 4;
    int am = m0 + lm;
    bool aval = am < M;
    const short* Ap = (const short*)A + (size_t)am * K + quad * 8;
    const short* Bp = (const short*)Bm;
    floatx4 acc[4];
#pragma unroll
    for (int t = 0; t < 4; t++) acc[t] = (floatx4){0.f, 0.f, 0.f, 0.f};
    for (int k0 = 0; k0 < K; k0 += 32) {
        short8 a = aval ? *(const short8*)(Ap + k0) : (short8){0,0,0,0,0,0,0,0};
#pragma unroll
        for (int t = 0; t < 4; t++) {
            int n = n0 + t * 16 + lm;
            short8 b = *(const short8*)(Bp + (size_t)n * K + k0 + quad * 8);
            acc[t] = __builtin_amdgcn_mfma_f32_16x16x32_bf16(a, b, acc[t], 0, 0, 0);
        }
    }
#pragma unroll
    for (int t = 0; t < 4; t++) {
        int n = n0 + t * 16 + lm;
        int b = n >> 12, l = n & (L_SEQ - 1);
#pragma unroll
        for (int r = 0; r < 4; r++) {
            int m = m0 + quad * 4 + r;
            if (m < M) C[((size_t)(b * M + m)) * L_SEQ + l] = acc[t][r];
        }
    }
}

// ---------------------------------------------------------------------------
// K3: dwconv1d k=4 + bias + silu, both dirs (blockIdx.y). XZ bf16 -> XS bf16.
// ---------------------------------------------------------------------------
__global__ void k_conv(const bf16* __restrict__ XZF, const bf16* __restrict__ XZB,
                       const float* __restrict__ fw, const float* __restrict__ fb,
                       const float* __restrict__ bw, const float* __restrict__ bb,
                       bf16* __restrict__ XSF, bf16* __restrict__ XSB) {
    int dirb = blockIdx.y;
    int i = blockIdx.x * blockDim.x + threadIdx.x;   // NPOS*DI
    int d = i % DI;
    int p = i / DI;
    int b = p >> 12, l = p & (L_SEQ - 1);
    const bf16* XZ = dirb ? XZB : XZF;
    const float* cw = dirb ? bw : fw;
    float acc = (dirb ? bb : fb)[d];
    if (!dirb) {
#pragma unroll
        for (int k = 0; k < 4; k++) {
            int ls = l - 3 + k;
            if (ls >= 0) acc += cw[d * 4 + k] * b2f(XZ[((size_t)(b * L_SEQ + ls)) * 384 + d]);
        }
    } else {
#pragma unroll
        for (int k = 0; k < 4; k++) {
            int ls = l + 3 - k;
            if (ls < L_SEQ) acc += cw[d * 4 + k] * b2f(XZ[((size_t)(b * L_SEQ + ls)) * 384 + d]);
        }
    }
    (dirb ? XSB : XSF)[(size_t)p * DI + d] = __float2bfloat16(silu_f(acc));
}

// ---------------------------------------------------------------------------
// Chunked parallel scan, 16 states per thread, delta inline, P/Q fp16.
// ---------------------------------------------------------------------------
__global__ void k_scan_p1(const float* __restrict__ DBLF, const float* __restrict__ DBLB,
                          const bf16* __restrict__ XSF,  const bf16* __restrict__ XSB,
                          const float* __restrict__ fWdt, const float* __restrict__ fbdt,
                          const float* __restrict__ bWdt, const float* __restrict__ bbdt,
                          const float* __restrict__ fAlog, const float* __restrict__ bAlog,
                          f16* __restrict__ P, f16* __restrict__ Q) {
    int t = blockIdx.x * blockDim.x + threadIdx.x;   // 393216
    int d = t % DI;
    int g = t / DI;                                   // 0..2047
    int chunk = g & (NCH - 1);
    int dirb = g >> 9;
    int b = dirb & 1, dir = dirb >> 1;

    const float* DBL = dir ? DBLB : DBLF;
    const bf16*  XS  = dir ? XSB  : XSF;
    const float* al  = (dir ? bAlog : fAlog) + d * DS;
    const float* wdt = (dir ? bWdt : fWdt) + d * 6;
    float bdtv = (dir ? bbdt : fbdt)[d];

    float wd[6];
#pragma unroll
    for (int r = 0; r < 6; r++) wd[r] = wdt[r];
    float A2[16], h[16];
#pragma unroll
    for (int s = 0; s < 16; s++) { A2[s] = -__expf(al[s]) * LOG2E; h[s] = 0.f; }

    int l = dir ? (L_SEQ - 1 - chunk * CHUNK) : chunk * CHUNK;
    int stp = dir ? -1 : 1;
    float sumdel = 0.f;

    for (int i = 0; i < CHUNK; i++) {
        size_t p = (size_t)b * L_SEQ + l;
        const float* row = DBL + p * LDBL;
        float dtv = bdtv;
#pragma unroll
        for (int r = 0; r < 6; r++) dtv += row[r] * wd[r];
        float del = softplus_f(dtv);
        float xs  = b2f(XS[p * DI + d]);
        const float4* bm = (const float4*)(row + 8);
        float4 B0 = bm[0], B1 = bm[1], B2 = bm[2], B3 = bm[3];
        float Bm[16] = {B0.x,B0.y,B0.z,B0.w, B1.x,B1.y,B1.z,B1.w,
                        B2.x,B2.y,B2.z,B2.w, B3.x,B3.y,B3.z,B3.w};
        float dx = del * xs;
        sumdel += del;
#pragma unroll
        for (int s = 0; s < 16; s++) {
            float dA = exp2f(del * A2[s]);
            h[s] = dA * h[s] + dx * Bm[s];
        }
        l += stp;
    }
    size_t idx = ((size_t)g * DI + d) * 16;
    f16x8 q0, q1, p0, p1;
#pragma unroll
    for (int j = 0; j < 8; j++) {
        q0[j] = (f16)h[j];
        q1[j] = (f16)h[8 + j];
        p0[j] = (f16)exp2f(A2[j] * sumdel);
        p1[j] = (f16)exp2f(A2[8 + j] * sumdel);
    }
    *(f16x8*)(Q + idx)     = q0;
    *(f16x8*)(Q + idx + 8) = q1;
    *(f16x8*)(P + idx)     = p0;
    *(f16x8*)(P + idx + 8) = p1;
}

__global__ void k_scan_p2(const f16* __restrict__ P, f16* __restrict__ Q) {
    int u = blockIdx.x * blockDim.x + threadIdx.x;   // 12288
    int s = u & 15;
    int dd = (u >> 4) % DI;
    int dirb = u / (DI * 16);
    float run = 0.f;
#pragma unroll 8
    for (int c = 0; c < NCH; c++) {
        size_t i = (((size_t)(dirb * NCH + c)) * DI + dd) * 16 + s;
        float tmp = (float)Q[i];
        Q[i] = (f16)run;
        run = (float)P[i] * run + tmp;
    }
}

__global__ void k_scan_p3(const float* __restrict__ DBLF, const float* __restrict__ DBLB,
                          const bf16* __restrict__ XSF,  const bf16* __restrict__ XSB,
                          const bf16* __restrict__ XZF,  const bf16* __restrict__ XZB,
                          const float* __restrict__ fWdt, const float* __restrict__ fbdt,
                          const float* __restrict__ bWdt, const float* __restrict__ bbdt,
                          const float* __restrict__ fAlog, const float* __restrict__ bAlog,
                          const float* __restrict__ fD,    const float* __restrict__ bD,
                          const f16* __restrict__ Q,
                          float* __restrict__ YSF, float* __restrict__ YSB) {
    int t = blockIdx.x * blockDim.x + threadIdx.x;   // 393216
    int d = t % DI;
    int g = t / DI;
    int chunk = g & (NCH - 1);
    int dirb = g >> 9;
    int b = dirb & 1, dir = dirb >> 1;

    const float* DBL = dir ? DBLB : DBLF;
    const bf16*  XS  = dir ? XSB  : XSF;
    const bf16*  XZ  = dir ? XZB  : XZF;
    const float* al  = (dir ? bAlog : fAlog) + d * DS;
    const float* wdt = (dir ? bWdt : fWdt) + d * 6;
    float bdtv = (dir ? bbdt : fbdt)[d];
    float Dp = dir ? bD[d] : fD[d];
    float* Y = dir ? YSB : YSF;

    float wd[6];
#pragma unroll
    for (int r = 0; r < 6; r++) wd[r] = wdt[r];
    float A2[16], h[16];
#pragma unroll
    for (int s = 0; s < 16; s++) A2[s] = -__expf(al[s]) * LOG2E;
    size_t idx = ((size_t)g * DI + d) * 16;
    f16x8 q0 = *(const f16x8*)(Q + idx);
    f16x8 q1 = *(const f16x8*)(Q + idx + 8);
#pragma unroll
    for (int j = 0; j < 8; j++) { h[j] = (float)q0[j]; h[8 + j] = (float)q1[j]; }

    int l = dir ? (L_SEQ - 1 - chunk * CHUNK) : chunk * CHUNK;
    int stp = dir ? -1 : 1;

    for (int i = 0; i < CHUNK; i++) {
        size_t p = (size_t)b * L_SEQ + l;
        const float* row = DBL + p * LDBL;
        float dtv = bdtv;
#pragma unroll
        for (int r = 0; r < 6; r++) dtv += row[r] * wd[r];
        float del = softplus_f(dtv);
        float xs  = b2f(XS[p * DI + d]);
        float z   = b2f(XZ[p * 384 + 192 + d]);
        const float4* bm = (const float4*)(row + 8);
        float4 B0 = bm[0], B1 = bm[1], B2 = bm[2], B3 = bm[3];
        float4 C0 = bm[4], C1 = bm[5], C2 = bm[6], C3 = bm[7];
        float Bm[16] = {B0.x,B0.y,B0.z,B0.w, B1.x,B1.y,B1.z,B1.w,
                        B2.x,B2.y,B2.z,B2.w, B3.x,B3.y,B3.z,B3.w};
        float Cm[16] = {C0.x,C0.y,C0.z,C0.w, C1.x,C1.y,C1.z,C1.w,
                        C2.x,C2.y,C2.z,C2.w, C3.x,C3.y,C3.z,C3.w};
        float dx = del * xs;
        float pr = 0.f;
#pragma unroll
        for (int s = 0; s < 16; s++) {
            float dA = exp2f(del * A2[s]);
            h[s] = dA * h[s] + dx * Bm[s];
            pr += h[s] * Cm[s];
        }
        Y[p * DI + d] = (pr + xs * Dp) * silu_f(z);
        l += stp;
    }
}

// ---------------------------------------------------------------------------
// K7: YSUMbf = bf16(YSF + YSB)
// ---------------------------------------------------------------------------
__global__ void k_cast_ysum(const float* __restrict__ YSF, const float* __restrict__ YSB,
                            bf16* __restrict__ YSUM) {
    int i = blockIdx.x * blockDim.x + threadIdx.x;   // NPOS*DI
    YSUM[i] = __float2bfloat16(YSF[i] + YSB[i]);
}

// ---------------------------------------------------------------------------
// K9: LDS-tiled mid: x2 = x + gamma1*(yo + x1); XMID planar f32;
// XM2cl = ln_cf(x2) channel-last bf16.
// ---------------------------------------------------------------------------
__global__ void k_mid_t(const float* __restrict__ x, const float* __restrict__ YO,
                        const float* __restrict__ X1,
                        const float* __restrict__ gamma1,
                        const float* __restrict__ ln1w, const float* __restrict__ ln1b,
                        float* __restrict__ XMID, bf16* __restrict__ XM2cl) {
    __shared__ float vt[DIM][TP + 1];
    __shared__ float yt[DIM][TP + 1];
    __shared__ float rs[8][TP], rss[8][TP];
    __shared__ float uu[TP], rr[TP];
    int blk = blockIdx.x;
    int p0 = blk * TP;
    int b = p0 >> 12, l0 = p0 & (L_SEQ - 1);
    int t = threadIdx.x;
    int tg = t >> 5, li = t & 31;

    for (int idx = t; idx < DIM * TP; idx += 256) {
        int q = idx / DIM, c = idx % DIM;
        yt[c][q] = YO[(size_t)(p0 + q) * DIM + c];
    }
    __syncthreads();
    {
        float s = 0.f, ss = 0.f;
        for (int c = tg; c < DIM; c += 8) {
            size_t gi = ((size_t)(b * DIM + c)) * L_SEQ + l0 + li;
            float v = x[gi] + gamma1[c] * (yt[c][li] + X1[gi]);
            XMID[gi] = v;
            vt[c][li] = v;
            s += v; ss += v * v;
        }
        rs[tg][li] = s; rss[tg][li] = ss;
    }
    __syncthreads();
    if (t < TP) {
        float s = 0.f, ss = 0.f;
#pragma unroll
        for (int g = 0; g < 8; g++) { s += rs[g][t]; ss += rss[g][t]; }
        float u = s / DIM;
        uu[t] = u; rr[t] = rsqrtf(ss / DIM - u * u + 1e-6f);
    }
    __syncthreads();
    for (int idx = t; idx < DIM * TP; idx += 256) {
        int q = idx / DIM, c = idx % DIM;
        XM2cl[(size_t)(p0 + q) * DIM + c] =
            __float2bfloat16(ln1w[c] * (vt[c][q] - uu[q]) * rr[q] + ln1b[c]);
    }
}

// ---------------------------------------------------------------------------
// K11: fused dilated dwconvs + GELU gate, channel-last bf16 in/out.
// ---------------------------------------------------------------------------
__global__ void k_msff(const bf16* __restrict__ H,
                       const float* __restrict__ dw1, const float* __restrict__ dw2,
                       const float* __restrict__ dw3, bf16* __restrict__ G) {
    int i = blockIdx.x * blockDim.x + threadIdx.x;   // B*4096*192
    int c = i % HID;
    int p = i / HID;
    int b = p >> 12, l = p & (L_SEQ - 1);
    int y = l >> 6, xc = l & 63;
    float a1 = 0.f, a2 = 0.f, a3 = 0.f;
#pragma unroll
    for (int ky = 0; ky < 3; ky++) {
#pragma unroll
        for (int kx = 0; kx < 3; kx++) {
            float w1 = dw1[(c * 3 + ky) * 3 + kx];
            float w2 = dw2[(c * 3 + ky) * 3 + kx];
            float w3 = dw3[(c * 3 + ky) * 3 + kx];
            int y1 = y + (ky - 1), x1 = xc + (kx - 1);
            if (y1 >= 0 && y1 < 64 && x1 >= 0 && x1 < 64)
                a1 += w1 * b2f(H[((size_t)(b * L_SEQ + y1 * 64 + x1)) * 576 + c]);
            int y2 = y + (ky - 1) * 2, x2 = xc + (kx - 1) * 2;
            if (y2 >= 0 && y2 < 64 && x2 >= 0 && x2 < 64)
                a2 += w2 * b2f(H[((size_t)(b * L_SEQ + y2 * 64 + x2)) * 576 + 192 + c]);
            int y3 = y + (ky - 1) * 3, x3 = xc + (kx - 1) * 3;
            if (y3 >= 0 && y3 < 64 && x3 >= 0 && x3 < 64)
                a3 += w3 * b2f(H[((size_t)(b * L_SEQ + y3 * 64 + x3)) * 576 + 384 + c]);
        }
    }
    float ge = 0.5f * a1 * (1.f + erff(a1 * 0.70710678118f));
    G[(size_t)p * HID + c] = __float2bfloat16(ge * a2 * a3);
}

// ---------------------------------------------------------------------------
// K13: out = XMID + gamma2[c] * OXM  (planar f32)
// ---------------------------------------------------------------------------
__global__ void k_out(const float* __restrict__ XMID, const float* __restrict__ OXM,
                      const float* __restrict__ gamma2, float* __restrict__ out) {
    int i = blockIdx.x * blockDim.x + threadIdx.x;   // B*96*4096
    int c = (i >> 12) % DIM;
    out[i] = XMID[i] + gamma2[c] * OXM[i];
}

// ---------------------------------------------------------------------------
extern "C" void kernel_launch(void* const* d_in, const int* in_sizes, int n_in,
                              void* d_out, int out_size, void* d_ws, size_t ws_size,
                              hipStream_t stream) {
    const float* x      = (const float*)d_in[0];
    const float* gamma1 = (const float*)d_in[1];
    const float* gamma2 = (const float*)d_in[2];
    const float* ln1w   = (const float*)d_in[3];
    const float* ln1b   = (const float*)d_in[4];
    const float* mnw    = (const float*)d_in[5];
    const float* mnb    = (const float*)d_in[6];
    const float* fWin   = (const float*)d_in[7];
    const float* fconvw = (const float*)d_in[8];
    const float* fconvb = (const float*)d_in[9];
    const float* fWx    = (const float*)d_in[10];
    const float* fWdt   = (const float*)d_in[11];
    const float* fbdt   = (const float*)d_in[12];
    const float* fAlog  = (const float*)d_in[13];
    const float* fD     = (const float*)d_in[14];
    const float* bWin   = (const float*)d_in[15];
    const float* bconvw = (const float*)d_in[16];
    const float* bconvb = (const float*)d_in[17];
    const float* bWx    = (const float*)d_in[18];
    const float* bWdt   = (const float*)d_in[19];
    const float* bbdt   = (const float*)d_in[20];
    const float* bAlog  = (const float*)d_in[21];
    const float* bD     = (const float*)d_in[22];
    const float* Wout   = (const float*)d_in[23];
    const float* mwin   = (const float*)d_in[24];
    const float* mdw1   = (const float*)d_in[25];
    const float* mdw2   = (const float*)d_in[26];
    const float* mdw3   = (const float*)d_in[27];
    const float* mwout  = (const float*)d_in[28];
    float* out = (float*)d_out;

    float* ws = (float*)d_ws;
    // layout (float offsets) — NOTE: XS needs 2 x 1,572,864 bf16 = 1,572,864 floats
    float* R0    = ws;                      // [0,        786432)  XNbf bf16 / YO f32 cl
    float* X1    = ws + 786432;             // [786432,  1572864)
    float* XZFr  = ws + 1572864;            // [1572864, 3145728)  bf16 8192x384
    float* XZBr  = ws + 3145728;            // [3145728, 4718592)  bf16 8192x384
    float* XSr   = ws + 4718592;            // [4718592, 6291456)  XSF,XSB bf16 (full size!)
    float* DBLF  = ws + 6291456;            // [6291456, 6619136)
    float* DBLB  = ws + 6619136;            // [6619136, 6946816)
    float* YSF   = ws + 6946816;            // [6946816, 8519680)
    float* YSB   = ws + 8519680;            // [8519680, 10092544)
    float* Qr    = ws + 10092544;           // [10092544,13238272) = 6291456 f16 slots
    bf16*  WAR   = (bf16*)(ws + 13238272);  // 180480 bf16 -> end 13328512 (~53MB)

    bf16*  XNbf  = (bf16*)R0;
    float* YO    = R0;                      // f32 channel-last (8192,96); XNbf dead by then
    bf16*  XZF   = (bf16*)XZFr;
    bf16*  XZB   = (bf16*)XZBr;
    bf16*  XSF   = (bf16*)XSr;
    bf16*  XSB   = XSF + 1572864;           // FIXED: full 1,572,864-element offset
    f16*   Qh    = (f16*)Qr;                // 6291456 f16, exactly fits
    f16*   Ph    = (f16*)YSF;               // 6291456 f16 over YSF+YSB (dead after p2)
    bf16*  YSUM  = (bf16*)XZFr;             // over XZF (XZ dead after p3)
    float* XMID  = Qr;                      // [10092544,10878976) over dead Q
    bf16*  XM2cl = (bf16*)(Qr + 786432);    // [10878976,11272192) over dead Q
    bf16*  Hcl   = (bf16*)XZFr;             // 4718592 bf16 over XZF+XZB head (dead)
    bf16*  Gcl   = (bf16*)YSF;              // 1572864 bf16 over YSF (dead after ysum)
    float* OXM   = XSr;                     // 786432 f over XSF (dead after p3)

    const bf16* fWinB  = WAR;
    const bf16* bWinB  = WAR + 36864;
    const bf16* fWxB   = WAR + 73728;
    const bf16* bWxB   = WAR + 81024;
    const bf16* WoutB  = WAR + 88320;
    const bf16* mwinB  = WAR + 106752;
    const bf16* mwoutB = WAR + 162048;

    // 0. weight casts
    k_cast_w<<<705, 256, 0, stream>>>(fWin, bWin, fWx, bWx, Wout, mwin, mwout, WAR);
    // 1. double LN (LDS-tiled)
    k_ln12_t<<<NPOS / TP, 256, 0, stream>>>(x, ln1w, ln1b, mnw, mnb, X1, XNbf);
    // 2-3. in-projections (MFMA, bf16 out)
    mfma_nt<<<dim3(128, 6), 256, 0, stream>>>(XNbf, fWinB, XZF, NPOS, 384, DIM, 384, 0, 1);
    mfma_nt<<<dim3(128, 6), 256, 0, stream>>>(XNbf, bWinB, XZB, NPOS, 384, DIM, 384, 0, 1);
    // 4. dwconv + silu (both dirs)
    k_conv<<<dim3(NPOS * DI / 256, 2), 256, 0, stream>>>(XZF, XZB, fconvw, fconvb,
                                                         bconvw, bconvb, XSF, XSB);
    // 5-6. x_dbl projections (MFMA, padded LDBL rows, f32 out)
    mfma_nt<<<dim3(128, 1), 256, 0, stream>>>(XSF, fWxB, DBLF, NPOS, 38, DI, LDBL, 1, 0);
    mfma_nt<<<dim3(128, 1), 256, 0, stream>>>(XSB, bWxB, DBLB, NPOS, 38, DI, LDBL, 1, 0);
    // 7-9. chunked parallel scan
    k_scan_p1<<<NREC * NCH / 256, 256, 0, stream>>>(DBLF, DBLB, XSF, XSB,
                                                    fWdt, fbdt, bWdt, bbdt,
                                                    fAlog, bAlog, Ph, Qh);
    k_scan_p2<<<NREC * 16 / 256, 256, 0, stream>>>(Ph, Qh);
    k_scan_p3<<<NREC * NCH / 256, 256, 0, stream>>>(DBLF, DBLB, XSF, XSB, XZF, XZB,
                                                    fWdt, fbdt, bWdt, bbdt,
                                                    fAlog, bAlog, fD, bD, Qh,
                                                    YSF, YSB);
    // 10. yf+yb -> bf16; out-projection (MFMA, f32 channel-last YO)
    k_cast_ysum<<<NPOS * DI / 256, 256, 0, stream>>>(YSF, YSB, YSUM);
    mfma_nt<<<dim3(128, 2), 256, 0, stream>>>(YSUM, WoutB, YO, NPOS, DIM, DI, DIM, 0, 0);
    // 11. residual + LN (LDS-tiled) -> XMID planar, XM2cl bf16
    k_mid_t<<<NPOS / TP, 256, 0, stream>>>(x, YO, X1, gamma1, ln1w, ln1b, XMID, XM2cl);
    // 12. msff in-projection (MFMA, bf16 channel-last H)
    mfma_nt<<<dim3(128, 9), 256, 0, stream>>>(XM2cl, mwinB, Hcl, NPOS, 576, DIM, 576, 0, 1);
    // 13. fused dilated dwconvs + GELU gate (channel-last)
    k_msff<<<NPOS * HID / 256, 256, 0, stream>>>(Hcl, mdw1, mdw2, mdw3, Gcl);
    // 14. msff out-projection (MFMA, planar f32 OXM)
    mfma_nt_pl<<<dim3(2, 128), 256, 0, stream>>>(mwoutB, Gcl, OXM, DIM, HID);
    // 15. final residual -> f32 out
    k_out<<<BATCH * DIM * L_SEQ / 256, 256, 0, stream>>>(XMID, OXM, gamma2, out);
}

// Round 10
// 316.111 us; speedup vs baseline: 5.6905x; 1.0566x over previous
//
#include <hip/hip_runtime.h>
#include <hip/hip_bf16.h>
#include <math.h>

typedef __hip_bfloat16 bf16;
typedef _Float16 f16;
typedef f16  f16x8  __attribute__((ext_vector_type(8)));
typedef short short8 __attribute__((ext_vector_type(8)));
typedef float floatx4 __attribute__((ext_vector_type(4)));

#define L_SEQ 4096
#define BATCH 2
#define DIM   96
#define DI    192
#define DS    16
#define HID   192
#define NPOS  (BATCH * L_SEQ)   // 8192
#define NCH   512               // chunks per sequence
#define CHUNK 8                 // L_SEQ / NCH
#define NREC  (2 * BATCH * DI)  // 768 recurrences (dir,b,d)
#define LDBL  40                // padded x_dbl row stride: dt[0:6), B[8:24), C[24:40)
#define LOG2E 1.44269504088896f
#define TP    32                // positions per LN block

__device__ __forceinline__ float silu_f(float x) { return x / (1.f + __expf(-x)); }
__device__ __forceinline__ float softplus_f(float x) {
    return fmaxf(x, 0.f) + __logf(1.f + __expf(-fabsf(x)));
}
__device__ __forceinline__ float b2f(bf16 v) { return __bfloat162float(v); }

// ---------------------------------------------------------------------------
// K0: cast all GEMM weights fp32 -> bf16 arena.
// ---------------------------------------------------------------------------
__global__ void k_cast_w(const float* __restrict__ fWin, const float* __restrict__ bWin,
                         const float* __restrict__ fWx,  const float* __restrict__ bWx,
                         const float* __restrict__ Wout, const float* __restrict__ mwin,
                         const float* __restrict__ mwout, bf16* __restrict__ arena) {
    int i = blockIdx.x * blockDim.x + threadIdx.x;
    if (i >= 180480) return;
    float v;
    if (i < 36864)        v = fWin[i];
    else if (i < 73728)   v = bWin[i - 36864];
    else if (i < 81024)   v = fWx[i - 73728];
    else if (i < 88320)   v = bWx[i - 81024];
    else if (i < 106752)  v = Wout[i - 88320];
    else if (i < 162048)  v = mwin[i - 106752];
    else                  v = mwout[i - 162048];
    arena[i] = __float2bfloat16(v);
}

// ---------------------------------------------------------------------------
// K1: LDS-tiled double layernorm.
// ---------------------------------------------------------------------------
__global__ void k_ln12_t(const float* __restrict__ x,
                         const float* __restrict__ ln1w, const float* __restrict__ ln1b,
                         const float* __restrict__ mnw,  const float* __restrict__ mnb,
                         float* __restrict__ X1, bf16* __restrict__ XNbf) {
    __shared__ float xt[DIM][TP + 1];
    __shared__ float rs[8][TP], rss[8][TP];
    __shared__ float uu[TP], rr[TP];
    int p0 = blockIdx.x * TP;
    int b = p0 >> 12, l0 = p0 & (L_SEQ - 1);
    int t = threadIdx.x;
    int tg = t >> 5, li = t & 31;

    for (int idx = t; idx < DIM * TP; idx += 256) {
        int c = idx >> 5, q = idx & 31;
        xt[c][q] = x[((size_t)(b * DIM + c)) * L_SEQ + l0 + q];
    }
    __syncthreads();
    {
        float s = 0.f, ss = 0.f;
        for (int c = tg; c < DIM; c += 8) { float v = xt[c][li]; s += v; ss += v * v; }
        rs[tg][li] = s; rss[tg][li] = ss;
    }
    __syncthreads();
    if (t < TP) {
        float s = 0.f, ss = 0.f;
#pragma unroll
        for (int g = 0; g < 8; g++) { s += rs[g][t]; ss += rss[g][t]; }
        float u = s / DIM;
        uu[t] = u; rr[t] = rsqrtf(ss / DIM - u * u + 1e-6f);
    }
    __syncthreads();
    {
        float u = uu[li], r = rr[li];
        float s2 = 0.f, ss2 = 0.f;
        for (int c = tg; c < DIM; c += 8) {
            float tv = ln1w[c] * (xt[c][li] - u) * r + ln1b[c];
            X1[((size_t)(b * DIM + c)) * L_SEQ + l0 + li] = tv;
            xt[c][li] = tv;
            s2 += tv; ss2 += tv * tv;
        }
        rs[tg][li] = s2; rss[tg][li] = ss2;
    }
    __syncthreads();
    if (t < TP) {
        float s = 0.f, ss = 0.f;
#pragma unroll
        for (int g = 0; g < 8; g++) { s += rs[g][t]; ss += rss[g][t]; }
        float u = s / DIM;
        uu[t] = u; rr[t] = rsqrtf(ss / DIM - u * u + 1e-5f);
    }
    __syncthreads();
    for (int idx = t; idx < DIM * TP; idx += 256) {
        int q = idx / DIM, c = idx % DIM;
        XNbf[(size_t)(p0 + q) * DIM + c] =
            __float2bfloat16((xt[c][q] - uu[q]) * rr[q] * mnw[c] + mnb[c]);
    }
}

// ---------------------------------------------------------------------------
// MFMA NT GEMM, 2-dir batched via blockIdx.z.
// C[z][M,N] = A[z][M,K](bf16) @ W[z][N,K](bf16)^T.
// obf: bf16 out; pad6: out cols >=6 shifted +2.
// ---------------------------------------------------------------------------
__global__ void mfma_nt_dir(const bf16* __restrict__ A0, const bf16* __restrict__ A1,
                            const bf16* __restrict__ W0, const bf16* __restrict__ W1,
                            void* __restrict__ C0, void* __restrict__ C1,
                            int M, int N, int K, int ldc, int pad6, int obf) {
    int z = blockIdx.z;
    const bf16* A = z ? A1 : A0;
    const bf16* W = z ? W1 : W0;
    void* C = z ? C1 : C0;
    int wave = threadIdx.x >> 6, lane = threadIdx.x & 63;
    int m0 = blockIdx.x * 64 + wave * 16;
    int n0 = blockIdx.y * 64;
    int lm = lane & 15, quad = lane >> 4;
    const short* Ap = (const short*)A + (size_t)(m0 + lm) * K + quad * 8;
    const short* Wp = (const short*)W;
    floatx4 acc[4];
#pragma unroll
    for (int t = 0; t < 4; t++) acc[t] = (floatx4){0.f, 0.f, 0.f, 0.f};
    for (int k0 = 0; k0 < K; k0 += 32) {
        short8 a = *(const short8*)(Ap + k0);
#pragma unroll
        for (int t = 0; t < 4; t++) {
            int n = n0 + t * 16 + lm;
            short8 b = (n < N) ? *(const short8*)(Wp + (size_t)n * K + k0 + quad * 8)
                               : (short8){0,0,0,0,0,0,0,0};
            acc[t] = __builtin_amdgcn_mfma_f32_16x16x32_bf16(a, b, acc[t], 0, 0, 0);
        }
    }
#pragma unroll
    for (int t = 0; t < 4; t++) {
        int n = n0 + t * 16 + lm;
        if (n < N) {
            int nn = (pad6 && n >= 6) ? n + 2 : n;
#pragma unroll
            for (int r = 0; r < 4; r++) {
                int m = m0 + quad * 4 + r;
                if (obf) ((bf16*)C)[(size_t)m * ldc + nn] = __float2bfloat16(acc[t][r]);
                else     ((float*)C)[(size_t)m * ldc + nn] = acc[t][r];
            }
        }
    }
}

// ---------------------------------------------------------------------------
// MFMA NT single-matrix (msff in-projection): C = A @ W^T, bf16 out.
// ---------------------------------------------------------------------------
__global__ void mfma_nt(const bf16* __restrict__ A, const bf16* __restrict__ W,
                        bf16* __restrict__ C, int M, int N, int K, int ldc) {
    int wave = threadIdx.x >> 6, lane = threadIdx.x & 63;
    int m0 = blockIdx.x * 64 + wave * 16;
    int n0 = blockIdx.y * 64;
    int lm = lane & 15, quad = lane >> 4;
    const short* Ap = (const short*)A + (size_t)(m0 + lm) * K + quad * 8;
    const short* Wp = (const short*)W;
    floatx4 acc[4];
#pragma unroll
    for (int t = 0; t < 4; t++) acc[t] = (floatx4){0.f, 0.f, 0.f, 0.f};
    for (int k0 = 0; k0 < K; k0 += 32) {
        short8 a = *(const short8*)(Ap + k0);
#pragma unroll
        for (int t = 0; t < 4; t++) {
            int n = n0 + t * 16 + lm;
            short8 b = (n < N) ? *(const short8*)(Wp + (size_t)n * K + k0 + quad * 8)
                               : (short8){0,0,0,0,0,0,0,0};
            acc[t] = __builtin_amdgcn_mfma_f32_16x16x32_bf16(a, b, acc[t], 0, 0, 0);
        }
    }
#pragma unroll
    for (int t = 0; t < 4; t++) {
        int n = n0 + t * 16 + lm;
        if (n < N) {
#pragma unroll
            for (int r = 0; r < 4; r++) {
                int m = m0 + quad * 4 + r;
                C[(size_t)m * ldc + n] = __float2bfloat16(acc[t][r]);
            }
        }
    }
}

// ---------------------------------------------------------------------------
// Out-projection, dual-A: YO[M,N] = (Y1+Y2)[M,K] @ Wout[N,K]^T, f32 cl out.
// Exact: two accumulating MFMAs.
// ---------------------------------------------------------------------------
__global__ void mfma_out(const bf16* __restrict__ Y1, const bf16* __restrict__ Y2,
                         const bf16* __restrict__ W, float* __restrict__ C,
                         int M, int N, int K, int ldc) {
    int wave = threadIdx.x >> 6, lane = threadIdx.x & 63;
    int m0 = blockIdx.x * 64 + wave * 16;
    int n0 = blockIdx.y * 64;
    int lm = lane & 15, quad = lane >> 4;
    const short* A1p = (const short*)Y1 + (size_t)(m0 + lm) * K + quad * 8;
    const short* A2p = (const short*)Y2 + (size_t)(m0 + lm) * K + quad * 8;
    const short* Wp  = (const short*)W;
    floatx4 acc[4];
#pragma unroll
    for (int t = 0; t < 4; t++) acc[t] = (floatx4){0.f, 0.f, 0.f, 0.f};
    for (int k0 = 0; k0 < K; k0 += 32) {
        short8 a1 = *(const short8*)(A1p + k0);
        short8 a2 = *(const short8*)(A2p + k0);
#pragma unroll
        for (int t = 0; t < 4; t++) {
            int n = n0 + t * 16 + lm;
            short8 b = (n < N) ? *(const short8*)(Wp + (size_t)n * K + k0 + quad * 8)
                               : (short8){0,0,0,0,0,0,0,0};
            acc[t] = __builtin_amdgcn_mfma_f32_16x16x32_bf16(a1, b, acc[t], 0, 0, 0);
            acc[t] = __builtin_amdgcn_mfma_f32_16x16x32_bf16(a2, b, acc[t], 0, 0, 0);
        }
    }
#pragma unroll
    for (int t = 0; t < 4; t++) {
        int n = n0 + t * 16 + lm;
        if (n < N) {
#pragma unroll
            for (int r = 0; r < 4; r++) {
                int m = m0 + quad * 4 + r;
                C[(size_t)m * ldc + n] = acc[t][r];
            }
        }
    }
}

// ---------------------------------------------------------------------------
// msff out-projection with fused final residual:
// out[(b*DIM+m)*4096+l] = XMID[idx] + gamma2[m] * (mwout @ G^T)[m, n=b*4096+l]
// ---------------------------------------------------------------------------
__global__ void mfma_msffout(const bf16* __restrict__ A, const bf16* __restrict__ Bm,
                             const float* __restrict__ XMID, const float* __restrict__ gamma2,
                             float* __restrict__ out, int M, int K) {
    int wave = threadIdx.x >> 6, lane = threadIdx.x & 63;
    int m0 = blockIdx.x * 64 + wave * 16;
    int n0 = blockIdx.y * 64;
    int lm = lane & 15, quad = lane >> 4;
    int am = m0 + lm;
    bool aval = am < M;
    const short* Ap = (const short*)A + (size_t)am * K + quad * 8;
    const short* Bp = (const short*)Bm;
    floatx4 acc[4];
#pragma unroll
    for (int t = 0; t < 4; t++) acc[t] = (floatx4){0.f, 0.f, 0.f, 0.f};
    for (int k0 = 0; k0 < K; k0 += 32) {
        short8 a = aval ? *(const short8*)(Ap + k0) : (short8){0,0,0,0,0,0,0,0};
#pragma unroll
        for (int t = 0; t < 4; t++) {
            int n = n0 + t * 16 + lm;
            short8 b = *(const short8*)(Bp + (size_t)n * K + k0 + quad * 8);
            acc[t] = __builtin_amdgcn_mfma_f32_16x16x32_bf16(a, b, acc[t], 0, 0, 0);
        }
    }
#pragma unroll
    for (int t = 0; t < 4; t++) {
        int n = n0 + t * 16 + lm;
        int b = n >> 12, l = n & (L_SEQ - 1);
#pragma unroll
        for (int r = 0; r < 4; r++) {
            int m = m0 + quad * 4 + r;
            if (m < M) {
                size_t idx = ((size_t)(b * M + m)) * L_SEQ + l;
                out[idx] = XMID[idx] + gamma2[m] * acc[t][r];
            }
        }
    }
}

// ---------------------------------------------------------------------------
// K3: dwconv1d k=4 + bias + silu, both dirs (blockIdx.y). XZ bf16 -> XS bf16.
// ---------------------------------------------------------------------------
__global__ void k_conv(const bf16* __restrict__ XZF, const bf16* __restrict__ XZB,
                       const float* __restrict__ fw, const float* __restrict__ fb,
                       const float* __restrict__ bw, const float* __restrict__ bb,
                       bf16* __restrict__ XSF, bf16* __restrict__ XSB) {
    int dirb = blockIdx.y;
    int i = blockIdx.x * blockDim.x + threadIdx.x;   // NPOS*DI
    int d = i % DI;
    int p = i / DI;
    int b = p >> 12, l = p & (L_SEQ - 1);
    const bf16* XZ = dirb ? XZB : XZF;
    const float* cw = dirb ? bw : fw;
    float acc = (dirb ? bb : fb)[d];
    if (!dirb) {
#pragma unroll
        for (int k = 0; k < 4; k++) {
            int ls = l - 3 + k;
            if (ls >= 0) acc += cw[d * 4 + k] * b2f(XZ[((size_t)(b * L_SEQ + ls)) * 384 + d]);
        }
    } else {
#pragma unroll
        for (int k = 0; k < 4; k++) {
            int ls = l + 3 - k;
            if (ls < L_SEQ) acc += cw[d * 4 + k] * b2f(XZ[((size_t)(b * L_SEQ + ls)) * 384 + d]);
        }
    }
    (dirb ? XSB : XSF)[(size_t)p * DI + d] = __float2bfloat16(silu_f(acc));
}

// ---------------------------------------------------------------------------
// Chunked parallel scan, 16 states per thread, delta inline, P/Q fp16.
// ---------------------------------------------------------------------------
__global__ void k_scan_p1(const float* __restrict__ DBLF, const float* __restrict__ DBLB,
                          const bf16* __restrict__ XSF,  const bf16* __restrict__ XSB,
                          const float* __restrict__ fWdt, const float* __restrict__ fbdt,
                          const float* __restrict__ bWdt, const float* __restrict__ bbdt,
                          const float* __restrict__ fAlog, const float* __restrict__ bAlog,
                          f16* __restrict__ P, f16* __restrict__ Q) {
    int t = blockIdx.x * blockDim.x + threadIdx.x;   // 393216
    int d = t % DI;
    int g = t / DI;                                   // 0..2047
    int chunk = g & (NCH - 1);
    int dirb = g >> 9;
    int b = dirb & 1, dir = dirb >> 1;

    const float* DBL = dir ? DBLB : DBLF;
    const bf16*  XS  = dir ? XSB  : XSF;
    const float* al  = (dir ? bAlog : fAlog) + d * DS;
    const float* wdt = (dir ? bWdt : fWdt) + d * 6;
    float bdtv = (dir ? bbdt : fbdt)[d];

    float wd[6];
#pragma unroll
    for (int r = 0; r < 6; r++) wd[r] = wdt[r];
    float A2[16], h[16];
#pragma unroll
    for (int s = 0; s < 16; s++) { A2[s] = -__expf(al[s]) * LOG2E; h[s] = 0.f; }

    int l = dir ? (L_SEQ - 1 - chunk * CHUNK) : chunk * CHUNK;
    int stp = dir ? -1 : 1;
    float sumdel = 0.f;

    for (int i = 0; i < CHUNK; i++) {
        size_t p = (size_t)b * L_SEQ + l;
        const float* row = DBL + p * LDBL;
        float dtv = bdtv;
#pragma unroll
        for (int r = 0; r < 6; r++) dtv += row[r] * wd[r];
        float del = softplus_f(dtv);
        float xs  = b2f(XS[p * DI + d]);
        const float4* bm = (const float4*)(row + 8);
        float4 B0 = bm[0], B1 = bm[1], B2 = bm[2], B3 = bm[3];
        float Bm[16] = {B0.x,B0.y,B0.z,B0.w, B1.x,B1.y,B1.z,B1.w,
                        B2.x,B2.y,B2.z,B2.w, B3.x,B3.y,B3.z,B3.w};
        float dx = del * xs;
        sumdel += del;
#pragma unroll
        for (int s = 0; s < 16; s++) {
            float dA = exp2f(del * A2[s]);
            h[s] = dA * h[s] + dx * Bm[s];
        }
        l += stp;
    }
    size_t idx = ((size_t)g * DI + d) * 16;
    f16x8 q0, q1, p0, p1;
#pragma unroll
    for (int j = 0; j < 8; j++) {
        q0[j] = (f16)h[j];
        q1[j] = (f16)h[8 + j];
        p0[j] = (f16)exp2f(A2[j] * sumdel);
        p1[j] = (f16)exp2f(A2[8 + j] * sumdel);
    }
    *(f16x8*)(Q + idx)     = q0;
    *(f16x8*)(Q + idx + 8) = q1;
    *(f16x8*)(P + idx)     = p0;
    *(f16x8*)(P + idx + 8) = p1;
}

__global__ void k_scan_p2(const f16* __restrict__ P, f16* __restrict__ Q) {
    int u = blockIdx.x * blockDim.x + threadIdx.x;   // 12288
    int s = u & 15;
    int dd = (u >> 4) % DI;
    int dirb = u / (DI * 16);
    float run = 0.f;
#pragma unroll 8
    for (int c = 0; c < NCH; c++) {
        size_t i = (((size_t)(dirb * NCH + c)) * DI + dd) * 16 + s;
        float tmp = (float)Q[i];
        Q[i] = (f16)run;
        run = (float)P[i] * run + tmp;
    }
}

// p3: replay chunk from initial state; writes Y as bf16.
__global__ void k_scan_p3(const float* __restrict__ DBLF, const float* __restrict__ DBLB,
                          const bf16* __restrict__ XSF,  const bf16* __restrict__ XSB,
                          const bf16* __restrict__ XZF,  const bf16* __restrict__ XZB,
                          const float* __restrict__ fWdt, const float* __restrict__ fbdt,
                          const float* __restrict__ bWdt, const float* __restrict__ bbdt,
                          const float* __restrict__ fAlog, const float* __restrict__ bAlog,
                          const float* __restrict__ fD,    const float* __restrict__ bD,
                          const f16* __restrict__ Q,
                          bf16* __restrict__ YSF, bf16* __restrict__ YSB) {
    int t = blockIdx.x * blockDim.x + threadIdx.x;   // 393216
    int d = t % DI;
    int g = t / DI;
    int chunk = g & (NCH - 1);
    int dirb = g >> 9;
    int b = dirb & 1, dir = dirb >> 1;

    const float* DBL = dir ? DBLB : DBLF;
    const bf16*  XS  = dir ? XSB  : XSF;
    const bf16*  XZ  = dir ? XZB  : XZF;
    const float* al  = (dir ? bAlog : fAlog) + d * DS;
    const float* wdt = (dir ? bWdt : fWdt) + d * 6;
    float bdtv = (dir ? bbdt : fbdt)[d];
    float Dp = dir ? bD[d] : fD[d];
    bf16* Y = dir ? YSB : YSF;

    float wd[6];
#pragma unroll
    for (int r = 0; r < 6; r++) wd[r] = wdt[r];
    float A2[16], h[16];
#pragma unroll
    for (int s = 0; s < 16; s++) A2[s] = -__expf(al[s]) * LOG2E;
    size_t idx = ((size_t)g * DI + d) * 16;
    f16x8 q0 = *(const f16x8*)(Q + idx);
    f16x8 q1 = *(const f16x8*)(Q + idx + 8);
#pragma unroll
    for (int j = 0; j < 8; j++) { h[j] = (float)q0[j]; h[8 + j] = (float)q1[j]; }

    int l = dir ? (L_SEQ - 1 - chunk * CHUNK) : chunk * CHUNK;
    int stp = dir ? -1 : 1;

    for (int i = 0; i < CHUNK; i++) {
        size_t p = (size_t)b * L_SEQ + l;
        const float* row = DBL + p * LDBL;
        float dtv = bdtv;
#pragma unroll
        for (int r = 0; r < 6; r++) dtv += row[r] * wd[r];
        float del = softplus_f(dtv);
        float xs  = b2f(XS[p * DI + d]);
        float z   = b2f(XZ[p * 384 + 192 + d]);
        const float4* bm = (const float4*)(row + 8);
        float4 B0 = bm[0], B1 = bm[1], B2 = bm[2], B3 = bm[3];
        float4 C0 = bm[4], C1 = bm[5], C2 = bm[6], C3 = bm[7];
        float Bm[16] = {B0.x,B0.y,B0.z,B0.w, B1.x,B1.y,B1.z,B1.w,
                        B2.x,B2.y,B2.z,B2.w, B3.x,B3.y,B3.z,B3.w};
        float Cm[16] = {C0.x,C0.y,C0.z,C0.w, C1.x,C1.y,C1.z,C1.w,
                        C2.x,C2.y,C2.z,C2.w, C3.x,C3.y,C3.z,C3.w};
        float dx = del * xs;
        float pr = 0.f;
#pragma unroll
        for (int s = 0; s < 16; s++) {
            float dA = exp2f(del * A2[s]);
            h[s] = dA * h[s] + dx * Bm[s];
            pr += h[s] * Cm[s];
        }
        Y[p * DI + d] = __float2bfloat16((pr + xs * Dp) * silu_f(z));
        l += stp;
    }
}

// ---------------------------------------------------------------------------
// K9: LDS-tiled mid: x2 = x + gamma1*(yo + x1); XMID planar f32;
// XM2cl = ln_cf(x2) channel-last bf16.
// ---------------------------------------------------------------------------
__global__ void k_mid_t(const float* __restrict__ x, const float* __restrict__ YO,
                        const float* __restrict__ X1,
                        const float* __restrict__ gamma1,
                        const float* __restrict__ ln1w, const float* __restrict__ ln1b,
                        float* __restrict__ XMID, bf16* __restrict__ XM2cl) {
    __shared__ float vt[DIM][TP + 1];
    __shared__ float yt[DIM][TP + 1];
    __shared__ float rs[8][TP], rss[8][TP];
    __shared__ float uu[TP], rr[TP];
    int p0 = blockIdx.x * TP;
    int b = p0 >> 12, l0 = p0 & (L_SEQ - 1);
    int t = threadIdx.x;
    int tg = t >> 5, li = t & 31;

    for (int idx = t; idx < DIM * TP; idx += 256) {
        int q = idx / DIM, c = idx % DIM;
        yt[c][q] = YO[(size_t)(p0 + q) * DIM + c];
    }
    __syncthreads();
    {
        float s = 0.f, ss = 0.f;
        for (int c = tg; c < DIM; c += 8) {
            size_t gi = ((size_t)(b * DIM + c)) * L_SEQ + l0 + li;
            float v = x[gi] + gamma1[c] * (yt[c][li] + X1[gi]);
            XMID[gi] = v;
            vt[c][li] = v;
            s += v; ss += v * v;
        }
        rs[tg][li] = s; rss[tg][li] = ss;
    }
    __syncthreads();
    if (t < TP) {
        float s = 0.f, ss = 0.f;
#pragma unroll
        for (int g = 0; g < 8; g++) { s += rs[g][t]; ss += rss[g][t]; }
        float u = s / DIM;
        uu[t] = u; rr[t] = rsqrtf(ss / DIM - u * u + 1e-6f);
    }
    __syncthreads();
    for (int idx = t; idx < DIM * TP; idx += 256) {
        int q = idx / DIM, c = idx % DIM;
        XM2cl[(size_t)(p0 + q) * DIM + c] =
            __float2bfloat16(ln1w[c] * (vt[c][q] - uu[q]) * rr[q] + ln1b[c]);
    }
}

// ---------------------------------------------------------------------------
// K11: fused dilated dwconvs + GELU gate, channel-last bf16 in/out.
// ---------------------------------------------------------------------------
__global__ void k_msff(const bf16* __restrict__ H,
                       const float* __restrict__ dw1, const float* __restrict__ dw2,
                       const float* __restrict__ dw3, bf16* __restrict__ G) {
    int i = blockIdx.x * blockDim.x + threadIdx.x;   // B*4096*192
    int c = i % HID;
    int p = i / HID;
    int b = p >> 12, l = p & (L_SEQ - 1);
    int y = l >> 6, xc = l & 63;
    float a1 = 0.f, a2 = 0.f, a3 = 0.f;
#pragma unroll
    for (int ky = 0; ky < 3; ky++) {
#pragma unroll
        for (int kx = 0; kx < 3; kx++) {
            float w1 = dw1[(c * 3 + ky) * 3 + kx];
            float w2 = dw2[(c * 3 + ky) * 3 + kx];
            float w3 = dw3[(c * 3 + ky) * 3 + kx];
            int y1 = y + (ky - 1), x1 = xc + (kx - 1);
            if (y1 >= 0 && y1 < 64 && x1 >= 0 && x1 < 64)
                a1 += w1 * b2f(H[((size_t)(b * L_SEQ + y1 * 64 + x1)) * 576 + c]);
            int y2 = y + (ky - 1) * 2, x2 = xc + (kx - 1) * 2;
            if (y2 >= 0 && y2 < 64 && x2 >= 0 && x2 < 64)
                a2 += w2 * b2f(H[((size_t)(b * L_SEQ + y2 * 64 + x2)) * 576 + 192 + c]);
            int y3 = y + (ky - 1) * 3, x3 = xc + (kx - 1) * 3;
            if (y3 >= 0 && y3 < 64 && x3 >= 0 && x3 < 64)
                a3 += w3 * b2f(H[((size_t)(b * L_SEQ + y3 * 64 + x3)) * 576 + 384 + c]);
        }
    }
    float ge = 0.5f * a1 * (1.f + erff(a1 * 0.70710678118f));
    G[(size_t)p * HID + c] = __float2bfloat16(ge * a2 * a3);
}

// ---------------------------------------------------------------------------
extern "C" void kernel_launch(void* const* d_in, const int* in_sizes, int n_in,
                              void* d_out, int out_size, void* d_ws, size_t ws_size,
                              hipStream_t stream) {
    const float* x      = (const float*)d_in[0];
    const float* gamma1 = (const float*)d_in[1];
    const float* gamma2 = (const float*)d_in[2];
    const float* ln1w   = (const float*)d_in[3];
    const float* ln1b   = (const float*)d_in[4];
    const float* mnw    = (const float*)d_in[5];
    const float* mnb    = (const float*)d_in[6];
    const float* fWin   = (const float*)d_in[7];
    const float* fconvw = (const float*)d_in[8];
    const float* fconvb = (const float*)d_in[9];
    const float* fWx    = (const float*)d_in[10];
    const float* fWdt   = (const float*)d_in[11];
    const float* fbdt   = (const float*)d_in[12];
    const float* fAlog  = (const float*)d_in[13];
    const float* fD     = (const float*)d_in[14];
    const float* bWin   = (const float*)d_in[15];
    const float* bconvw = (const float*)d_in[16];
    const float* bconvb = (const float*)d_in[17];
    const float* bWx    = (const float*)d_in[18];
    const float* bWdt   = (const float*)d_in[19];
    const float* bbdt   = (const float*)d_in[20];
    const float* bAlog  = (const float*)d_in[21];
    const float* bD     = (const float*)d_in[22];
    const float* Wout   = (const float*)d_in[23];
    const float* mwin   = (const float*)d_in[24];
    const float* mdw1   = (const float*)d_in[25];
    const float* mdw2   = (const float*)d_in[26];
    const float* mdw3   = (const float*)d_in[27];
    const float* mwout  = (const float*)d_in[28];
    float* out = (float*)d_out;

    float* ws = (float*)d_ws;
    // layout (float offsets):
    float* R0    = ws;                      // [0,786432)       XNbf bf16 / YO f32 cl
    float* X1    = ws + 786432;             // [786432,1572864)
    float* XZFr  = ws + 1572864;            // [1572864,3145728)  bf16 8192x384
    float* XZBr  = ws + 3145728;            // [3145728,4718592)
    float* XSr   = ws + 4718592;            // [4718592,6291456)  XSF,XSB bf16
    float* DBLF  = ws + 6291456;            // [6291456,6619136)
    float* DBLB  = ws + 6619136;            // [6619136,6946816)
    float* YSr   = ws + 6946816;            // [6946816,10092544) Ph f16 / YSbf / Gcl
    float* Qr    = ws + 10092544;           // [10092544,13238272) Qh f16 / XMID,XM2cl
    bf16*  WAR   = (bf16*)(ws + 13238272);  // 180480 bf16 -> end 13328512 (~53MB)

    bf16*  XNbf  = (bf16*)R0;
    float* YO    = R0;                      // f32 cl (8192,96); XNbf dead by then
    bf16*  XZF   = (bf16*)XZFr;
    bf16*  XZB   = (bf16*)XZBr;
    bf16*  XSF   = (bf16*)XSr;
    bf16*  XSB   = XSF + 1572864;
    f16*   Qh    = (f16*)Qr;                // 6291456 f16
    f16*   Ph    = (f16*)YSr;               // 6291456 f16 (dead after p2)
    bf16*  YSFbf = (bf16*)YSr;              // 1572864 bf16 [6946816,7733248)
    bf16*  YSBbf = YSFbf + 1572864;         // [7733248,8519680)
    float* XMID  = Qr;                      // over dead Q
    bf16*  XM2cl = (bf16*)(Qr + 786432);
    bf16*  Hcl   = (bf16*)XZFr;             // 4718592 bf16 over XZ (dead after p3)
    bf16*  Gcl   = (bf16*)YSr;              // over YSbf (dead after out-proj)

    const bf16* fWinB  = WAR;
    const bf16* bWinB  = WAR + 36864;
    const bf16* fWxB   = WAR + 73728;
    const bf16* bWxB   = WAR + 81024;
    const bf16* WoutB  = WAR + 88320;
    const bf16* mwinB  = WAR + 106752;
    const bf16* mwoutB = WAR + 162048;

    // 0. weight casts
    k_cast_w<<<705, 256, 0, stream>>>(fWin, bWin, fWx, bWx, Wout, mwin, mwout, WAR);
    // 1. double LN (LDS-tiled)
    k_ln12_t<<<NPOS / TP, 256, 0, stream>>>(x, ln1w, ln1b, mnw, mnb, X1, XNbf);
    // 2. in-projections, both dirs in one launch
    mfma_nt_dir<<<dim3(128, 6, 2), 256, 0, stream>>>(XNbf, XNbf, fWinB, bWinB,
                                                     XZF, XZB, NPOS, 384, DIM, 384, 0, 1);
    // 3. dwconv + silu (both dirs)
    k_conv<<<dim3(NPOS * DI / 256, 2), 256, 0, stream>>>(XZF, XZB, fconvw, fconvb,
                                                         bconvw, bconvb, XSF, XSB);
    // 4. x_dbl projections, both dirs in one launch (padded LDBL rows)
    mfma_nt_dir<<<dim3(128, 1, 2), 256, 0, stream>>>(XSF, XSB, fWxB, bWxB,
                                                     DBLF, DBLB, NPOS, 38, DI, LDBL, 1, 0);
    // 5-7. chunked parallel scan (p3 writes bf16 Y)
    k_scan_p1<<<NREC * NCH / 256, 256, 0, stream>>>(DBLF, DBLB, XSF, XSB,
                                                    fWdt, fbdt, bWdt, bbdt,
                                                    fAlog, bAlog, Ph, Qh);
    k_scan_p2<<<NREC * 16 / 256, 256, 0, stream>>>(Ph, Qh);
    k_scan_p3<<<NREC * NCH / 256, 256, 0, stream>>>(DBLF, DBLB, XSF, XSB, XZF, XZB,
                                                    fWdt, fbdt, bWdt, bbdt,
                                                    fAlog, bAlog, fD, bD, Qh,
                                                    YSFbf, YSBbf);
    // 8. out-projection (dual-A MFMA, f32 channel-last YO)
    mfma_out<<<dim3(128, 2), 256, 0, stream>>>(YSFbf, YSBbf, WoutB, YO, NPOS, DIM, DI, DIM);
    // 9. residual + LN (LDS-tiled)
    k_mid_t<<<NPOS / TP, 256, 0, stream>>>(x, YO, X1, gamma1, ln1w, ln1b, XMID, XM2cl);
    // 10. msff in-projection (MFMA, bf16 channel-last H)
    mfma_nt<<<dim3(128, 9), 256, 0, stream>>>(XM2cl, mwinB, Hcl, NPOS, 576, DIM, 576);
    // 11. fused dilated dwconvs + GELU gate
    k_msff<<<NPOS * HID / 256, 256, 0, stream>>>(Hcl, mdw1, mdw2, mdw3, Gcl);
    // 12. msff out-projection + fused final residual -> out
    mfma_msffout<<<dim3(2, 128), 256, 0, stream>>>(mwoutB, Gcl, XMID, gamma2, out, DIM, HID);
}

// Round 11
// 315.809 us; speedup vs baseline: 5.6959x; 1.0010x over previous
//
#include <hip/hip_runtime.h>
#include <hip/hip_bf16.h>
#include <math.h>

typedef __hip_bfloat16 bf16;
typedef _Float16 f16;
typedef f16  f16x8  __attribute__((ext_vector_type(8)));
typedef short short8 __attribute__((ext_vector_type(8)));
typedef unsigned short ushort8 __attribute__((ext_vector_type(8)));
typedef float floatx4 __attribute__((ext_vector_type(4)));

#define L_SEQ 4096
#define BATCH 2
#define DIM   96
#define DI    192
#define DS    16
#define HID   192
#define NPOS  (BATCH * L_SEQ)   // 8192
#define NCH   1024              // chunks per sequence
#define CHUNK 4                 // L_SEQ / NCH
#define NREC  (2 * BATCH * DI)  // 768 recurrences (dir,b,d)
#define LDBL  40                // padded x_dbl row stride: dt[0:6), B[8:24), C[24:40)
#define LOG2E 1.44269504088896f
#define TP    32                // positions per LN block

__device__ __forceinline__ float silu_f(float x) { return x / (1.f + __expf(-x)); }
__device__ __forceinline__ float softplus_f(float x) {
    return fmaxf(x, 0.f) + __logf(1.f + __expf(-fabsf(x)));
}
__device__ __forceinline__ float b2f(bf16 v) { return __bfloat162float(v); }
__device__ __forceinline__ float us2f(unsigned short u) {
    union { unsigned int i; float f; } cv; cv.i = ((unsigned int)u) << 16; return cv.f;
}

// ---------------------------------------------------------------------------
// K0: prep — cast GEMM weights fp32->bf16, build A2 table, transpose msff dw.
// weights (bf16): fWin 0 | bWin 36864 | fWx 73728 | bWx 81024 | Wout 88320 |
//                 mwin 106752 | mwout 162048 | total 180480
// A2 (f32, 6144): [dir][d][s] = -exp(Alog[d,s])*LOG2E
// mdwt (f32, 5184): [conv][tap][c]
// ---------------------------------------------------------------------------
__global__ void k_prep(const float* __restrict__ fWin, const float* __restrict__ bWin,
                       const float* __restrict__ fWx,  const float* __restrict__ bWx,
                       const float* __restrict__ Wout, const float* __restrict__ mwin,
                       const float* __restrict__ mwout,
                       const float* __restrict__ fAlog, const float* __restrict__ bAlog,
                       const float* __restrict__ mdw1, const float* __restrict__ mdw2,
                       const float* __restrict__ mdw3,
                       bf16* __restrict__ war, float* __restrict__ a2tab,
                       float* __restrict__ mdwt) {
    int i = blockIdx.x * blockDim.x + threadIdx.x;
    if (i < 180480) {
        float v;
        if (i < 36864)        v = fWin[i];
        else if (i < 73728)   v = bWin[i - 36864];
        else if (i < 81024)   v = fWx[i - 73728];
        else if (i < 88320)   v = bWx[i - 81024];
        else if (i < 106752)  v = Wout[i - 88320];
        else if (i < 162048)  v = mwin[i - 106752];
        else                  v = mwout[i - 162048];
        war[i] = __float2bfloat16(v);
    } else if (i < 186624) {
        int j = i - 180480;                 // 0..6143
        int dir = j / 3072, rem = j % 3072; // [dir][d][s]
        const float* al = dir ? bAlog : fAlog;
        a2tab[j] = -__expf(al[rem]) * LOG2E;
    } else if (i < 191808) {
        int j = i - 186624;                 // 0..5183
        int cv = j / 1728, rem = j % 1728;
        int tap = rem / 192, c = rem % 192;
        const float* src = (cv == 0) ? mdw1 : (cv == 1) ? mdw2 : mdw3;
        mdwt[j] = src[c * 9 + tap];
    }
}

// ---------------------------------------------------------------------------
// K1: LDS-tiled double layernorm.
// ---------------------------------------------------------------------------
__global__ void k_ln12_t(const float* __restrict__ x,
                         const float* __restrict__ ln1w, const float* __restrict__ ln1b,
                         const float* __restrict__ mnw,  const float* __restrict__ mnb,
                         float* __restrict__ X1, bf16* __restrict__ XNbf) {
    __shared__ float xt[DIM][TP + 1];
    __shared__ float rs[8][TP], rss[8][TP];
    __shared__ float uu[TP], rr[TP];
    int p0 = blockIdx.x * TP;
    int b = p0 >> 12, l0 = p0 & (L_SEQ - 1);
    int t = threadIdx.x;
    int tg = t >> 5, li = t & 31;

    for (int idx = t; idx < DIM * TP; idx += 256) {
        int c = idx >> 5, q = idx & 31;
        xt[c][q] = x[((size_t)(b * DIM + c)) * L_SEQ + l0 + q];
    }
    __syncthreads();
    {
        float s = 0.f, ss = 0.f;
        for (int c = tg; c < DIM; c += 8) { float v = xt[c][li]; s += v; ss += v * v; }
        rs[tg][li] = s; rss[tg][li] = ss;
    }
    __syncthreads();
    if (t < TP) {
        float s = 0.f, ss = 0.f;
#pragma unroll
        for (int g = 0; g < 8; g++) { s += rs[g][t]; ss += rss[g][t]; }
        float u = s / DIM;
        uu[t] = u; rr[t] = rsqrtf(ss / DIM - u * u + 1e-6f);
    }
    __syncthreads();
    {
        float u = uu[li], r = rr[li];
        float s2 = 0.f, ss2 = 0.f;
        for (int c = tg; c < DIM; c += 8) {
            float tv = ln1w[c] * (xt[c][li] - u) * r + ln1b[c];
            X1[((size_t)(b * DIM + c)) * L_SEQ + l0 + li] = tv;
            xt[c][li] = tv;
            s2 += tv; ss2 += tv * tv;
        }
        rs[tg][li] = s2; rss[tg][li] = ss2;
    }
    __syncthreads();
    if (t < TP) {
        float s = 0.f, ss = 0.f;
#pragma unroll
        for (int g = 0; g < 8; g++) { s += rs[g][t]; ss += rss[g][t]; }
        float u = s / DIM;
        uu[t] = u; rr[t] = rsqrtf(ss / DIM - u * u + 1e-5f);
    }
    __syncthreads();
    for (int idx = t; idx < DIM * TP; idx += 256) {
        int q = idx / DIM, c = idx % DIM;
        XNbf[(size_t)(p0 + q) * DIM + c] =
            __float2bfloat16((xt[c][q] - uu[q]) * rr[q] * mnw[c] + mnb[c]);
    }
}

// ---------------------------------------------------------------------------
// MFMA NT GEMM, 2-dir batched via blockIdx.z.
// ---------------------------------------------------------------------------
__global__ void mfma_nt_dir(const bf16* __restrict__ A0, const bf16* __restrict__ A1,
                            const bf16* __restrict__ W0, const bf16* __restrict__ W1,
                            void* __restrict__ C0, void* __restrict__ C1,
                            int M, int N, int K, int ldc, int pad6, int obf) {
    int z = blockIdx.z;
    const bf16* A = z ? A1 : A0;
    const bf16* W = z ? W1 : W0;
    void* C = z ? C1 : C0;
    int wave = threadIdx.x >> 6, lane = threadIdx.x & 63;
    int m0 = blockIdx.x * 64 + wave * 16;
    int n0 = blockIdx.y * 64;
    int lm = lane & 15, quad = lane >> 4;
    const short* Ap = (const short*)A + (size_t)(m0 + lm) * K + quad * 8;
    const short* Wp = (const short*)W;
    floatx4 acc[4];
#pragma unroll
    for (int t = 0; t < 4; t++) acc[t] = (floatx4){0.f, 0.f, 0.f, 0.f};
    for (int k0 = 0; k0 < K; k0 += 32) {
        short8 a = *(const short8*)(Ap + k0);
#pragma unroll
        for (int t = 0; t < 4; t++) {
            int n = n0 + t * 16 + lm;
            short8 b = (n < N) ? *(const short8*)(Wp + (size_t)n * K + k0 + quad * 8)
                               : (short8){0,0,0,0,0,0,0,0};
            acc[t] = __builtin_amdgcn_mfma_f32_16x16x32_bf16(a, b, acc[t], 0, 0, 0);
        }
    }
#pragma unroll
    for (int t = 0; t < 4; t++) {
        int n = n0 + t * 16 + lm;
        if (n < N) {
            int nn = (pad6 && n >= 6) ? n + 2 : n;
#pragma unroll
            for (int r = 0; r < 4; r++) {
                int m = m0 + quad * 4 + r;
                if (obf) ((bf16*)C)[(size_t)m * ldc + nn] = __float2bfloat16(acc[t][r]);
                else     ((float*)C)[(size_t)m * ldc + nn] = acc[t][r];
            }
        }
    }
}

// ---------------------------------------------------------------------------
// MFMA NT single-matrix (msff in-projection): C = A @ W^T, bf16 out.
// ---------------------------------------------------------------------------
__global__ void mfma_nt(const bf16* __restrict__ A, const bf16* __restrict__ W,
                        bf16* __restrict__ C, int M, int N, int K, int ldc) {
    int wave = threadIdx.x >> 6, lane = threadIdx.x & 63;
    int m0 = blockIdx.x * 64 + wave * 16;
    int n0 = blockIdx.y * 64;
    int lm = lane & 15, quad = lane >> 4;
    const short* Ap = (const short*)A + (size_t)(m0 + lm) * K + quad * 8;
    const short* Wp = (const short*)W;
    floatx4 acc[4];
#pragma unroll
    for (int t = 0; t < 4; t++) acc[t] = (floatx4){0.f, 0.f, 0.f, 0.f};
    for (int k0 = 0; k0 < K; k0 += 32) {
        short8 a = *(const short8*)(Ap + k0);
#pragma unroll
        for (int t = 0; t < 4; t++) {
            int n = n0 + t * 16 + lm;
            short8 b = (n < N) ? *(const short8*)(Wp + (size_t)n * K + k0 + quad * 8)
                               : (short8){0,0,0,0,0,0,0,0};
            acc[t] = __builtin_amdgcn_mfma_f32_16x16x32_bf16(a, b, acc[t], 0, 0, 0);
        }
    }
#pragma unroll
    for (int t = 0; t < 4; t++) {
        int n = n0 + t * 16 + lm;
        if (n < N) {
#pragma unroll
            for (int r = 0; r < 4; r++) {
                int m = m0 + quad * 4 + r;
                C[(size_t)m * ldc + n] = __float2bfloat16(acc[t][r]);
            }
        }
    }
}

// ---------------------------------------------------------------------------
// Out-projection, dual-A: YO = (Y1+Y2) @ Wout^T, f32 channel-last out.
// ---------------------------------------------------------------------------
__global__ void mfma_out(const bf16* __restrict__ Y1, const bf16* __restrict__ Y2,
                         const bf16* __restrict__ W, float* __restrict__ C,
                         int M, int N, int K, int ldc) {
    int wave = threadIdx.x >> 6, lane = threadIdx.x & 63;
    int m0 = blockIdx.x * 64 + wave * 16;
    int n0 = blockIdx.y * 64;
    int lm = lane & 15, quad = lane >> 4;
    const short* A1p = (const short*)Y1 + (size_t)(m0 + lm) * K + quad * 8;
    const short* A2p = (const short*)Y2 + (size_t)(m0 + lm) * K + quad * 8;
    const short* Wp  = (const short*)W;
    floatx4 acc[4];
#pragma unroll
    for (int t = 0; t < 4; t++) acc[t] = (floatx4){0.f, 0.f, 0.f, 0.f};
    for (int k0 = 0; k0 < K; k0 += 32) {
        short8 a1 = *(const short8*)(A1p + k0);
        short8 a2 = *(const short8*)(A2p + k0);
#pragma unroll
        for (int t = 0; t < 4; t++) {
            int n = n0 + t * 16 + lm;
            short8 b = (n < N) ? *(const short8*)(Wp + (size_t)n * K + k0 + quad * 8)
                               : (short8){0,0,0,0,0,0,0,0};
            acc[t] = __builtin_amdgcn_mfma_f32_16x16x32_bf16(a1, b, acc[t], 0, 0, 0);
            acc[t] = __builtin_amdgcn_mfma_f32_16x16x32_bf16(a2, b, acc[t], 0, 0, 0);
        }
    }
#pragma unroll
    for (int t = 0; t < 4; t++) {
        int n = n0 + t * 16 + lm;
        if (n < N) {
#pragma unroll
            for (int r = 0; r < 4; r++) {
                int m = m0 + quad * 4 + r;
                C[(size_t)m * ldc + n] = acc[t][r];
            }
        }
    }
}

// ---------------------------------------------------------------------------
// msff out-projection + fused final residual (planar f32 out).
// ---------------------------------------------------------------------------
__global__ void mfma_msffout(const bf16* __restrict__ A, const bf16* __restrict__ Bm,
                             const float* __restrict__ XMID, const float* __restrict__ gamma2,
                             float* __restrict__ out, int M, int K) {
    int wave = threadIdx.x >> 6, lane = threadIdx.x & 63;
    int m0 = blockIdx.x * 64 + wave * 16;
    int n0 = blockIdx.y * 64;
    int lm = lane & 15, quad = lane >> 4;
    int am = m0 + lm;
    bool aval = am < M;
    const short* Ap = (const short*)A + (size_t)am * K + quad * 8;
    const short* Bp = (const short*)Bm;
    floatx4 acc[4];
#pragma unroll
    for (int t = 0; t < 4; t++) acc[t] = (floatx4){0.f, 0.f, 0.f, 0.f};
    for (int k0 = 0; k0 < K; k0 += 32) {
        short8 a = aval ? *(const short8*)(Ap + k0) : (short8){0,0,0,0,0,0,0,0};
#pragma unroll
        for (int t = 0; t < 4; t++) {
            int n = n0 + t * 16 + lm;
            short8 b = *(const short8*)(Bp + (size_t)n * K + k0 + quad * 8);
            acc[t] = __builtin_amdgcn_mfma_f32_16x16x32_bf16(a, b, acc[t], 0, 0, 0);
        }
    }
#pragma unroll
    for (int t = 0; t < 4; t++) {
        int n = n0 + t * 16 + lm;
        int b = n >> 12, l = n & (L_SEQ - 1);
#pragma unroll
        for (int r = 0; r < 4; r++) {
            int m = m0 + quad * 4 + r;
            if (m < M) {
                size_t idx = ((size_t)(b * M + m)) * L_SEQ + l;
                out[idx] = XMID[idx] + gamma2[m] * acc[t][r];
            }
        }
    }
}

// ---------------------------------------------------------------------------
// K3: dwconv1d k=4 + bias + silu, vectorized 8 channels/thread.
// grid (NPOS*24/256, 2). XZ bf16 -> XS bf16.
// ---------------------------------------------------------------------------
__global__ void k_conv_v(const bf16* __restrict__ XZF, const bf16* __restrict__ XZB,
                         const float* __restrict__ fw, const float* __restrict__ fb,
                         const float* __restrict__ bw, const float* __restrict__ bb,
                         bf16* __restrict__ XSF, bf16* __restrict__ XSB) {
    int dirb = blockIdx.y;
    int i = blockIdx.x * blockDim.x + threadIdx.x;   // NPOS*24
    int dg = i % 24;
    int p = i / 24;
    int b = p >> 12, l = p & (L_SEQ - 1);
    int d0 = dg * 8;
    const bf16* XZ = dirb ? XZB : XZF;
    const float* cw = dirb ? bw : fw;
    const float* cb = dirb ? bb : fb;

    float4 w[8];
#pragma unroll
    for (int j = 0; j < 8; j++) w[j] = *(const float4*)(cw + (d0 + j) * 4);
    float acc[8];
#pragma unroll
    for (int j = 0; j < 8; j++) acc[j] = cb[d0 + j];

#pragma unroll
    for (int k = 0; k < 4; k++) {
        int ls = dirb ? (l + 3 - k) : (l - 3 + k);
        if (ls >= 0 && ls < L_SEQ) {
            ushort8 xv = *(const ushort8*)((const unsigned short*)XZ +
                           ((size_t)(b * L_SEQ + ls)) * 384 + d0);
#pragma unroll
            for (int j = 0; j < 8; j++) {
                float wk = (k == 0) ? w[j].x : (k == 1) ? w[j].y : (k == 2) ? w[j].z : w[j].w;
                acc[j] += wk * us2f(xv[j]);
            }
        }
    }
    ushort8 ov;
#pragma unroll
    for (int j = 0; j < 8; j++) {
        bf16 t = __float2bfloat16(silu_f(acc[j]));
        ov[j] = *(unsigned short*)&t;
    }
    *(ushort8*)((unsigned short*)(dirb ? XSB : XSF) + (size_t)p * DI + d0) = ov;
}

// ---------------------------------------------------------------------------
// Chunked parallel scan, CHUNK=4, NCH=1024, A2 table-driven, P/Q fp16.
// Thread map: t = g*DI + d, g = dirb*NCH + chunk.
// ---------------------------------------------------------------------------
__global__ void k_scan_p1(const float* __restrict__ DBLF, const float* __restrict__ DBLB,
                          const bf16* __restrict__ XSF,  const bf16* __restrict__ XSB,
                          const float* __restrict__ fWdt, const float* __restrict__ fbdt,
                          const float* __restrict__ bWdt, const float* __restrict__ bbdt,
                          const float* __restrict__ a2tab,
                          f16* __restrict__ P, f16* __restrict__ Q) {
    int t = blockIdx.x * blockDim.x + threadIdx.x;   // 786432
    int d = t % DI;
    int g = t / DI;                                   // 0..4095
    int chunk = g & (NCH - 1);
    int dirb = g >> 10;
    int b = dirb & 1, dir = dirb >> 1;

    const float* DBL = dir ? DBLB : DBLF;
    const bf16*  XS  = dir ? XSB  : XSF;
    const float* wdt = (dir ? bWdt : fWdt) + d * 6;
    float bdtv = (dir ? bbdt : fbdt)[d];

    float wd[6];
#pragma unroll
    for (int r = 0; r < 6; r++) wd[r] = wdt[r];
    const float* a2p = a2tab + (dir * DI + d) * 16;
    float A2[16], h[16];
#pragma unroll
    for (int v = 0; v < 4; v++) {
        float4 a2v = *(const float4*)(a2p + 4 * v);
        A2[4*v] = a2v.x; A2[4*v+1] = a2v.y; A2[4*v+2] = a2v.z; A2[4*v+3] = a2v.w;
    }
#pragma unroll
    for (int s = 0; s < 16; s++) h[s] = 0.f;

    int l = dir ? (L_SEQ - 1 - chunk * CHUNK) : chunk * CHUNK;
    int stp = dir ? -1 : 1;
    float sumdel = 0.f;

#pragma unroll
    for (int i = 0; i < CHUNK; i++) {
        size_t p = (size_t)b * L_SEQ + l;
        const float* row = DBL + p * LDBL;
        float dtv = bdtv;
#pragma unroll
        for (int r = 0; r < 6; r++) dtv += row[r] * wd[r];
        float del = softplus_f(dtv);
        float xs  = b2f(XS[p * DI + d]);
        const float4* bm = (const float4*)(row + 8);
        float4 B0 = bm[0], B1 = bm[1], B2 = bm[2], B3 = bm[3];
        float Bm[16] = {B0.x,B0.y,B0.z,B0.w, B1.x,B1.y,B1.z,B1.w,
                        B2.x,B2.y,B2.z,B2.w, B3.x,B3.y,B3.z,B3.w};
        float dx = del * xs;
        sumdel += del;
#pragma unroll
        for (int s = 0; s < 16; s++) {
            float dA = exp2f(del * A2[s]);
            h[s] = dA * h[s] + dx * Bm[s];
        }
        l += stp;
    }
    size_t idx = ((size_t)g * DI + d) * 16;
    f16x8 q0, q1, p0, p1;
#pragma unroll
    for (int j = 0; j < 8; j++) {
        q0[j] = (f16)h[j];
        q1[j] = (f16)h[8 + j];
        p0[j] = (f16)exp2f(A2[j] * sumdel);
        p1[j] = (f16)exp2f(A2[8 + j] * sumdel);
    }
    *(f16x8*)(Q + idx)     = q0;
    *(f16x8*)(Q + idx + 8) = q1;
    *(f16x8*)(P + idx)     = p0;
    *(f16x8*)(P + idx + 8) = p1;
}

__global__ void k_scan_p2(const f16* __restrict__ P, f16* __restrict__ Q) {
    int u = blockIdx.x * blockDim.x + threadIdx.x;   // 12288
    int s = u & 15;
    int dd = (u >> 4) % DI;
    int dirb = u / (DI * 16);
    float run = 0.f;
#pragma unroll 8
    for (int c = 0; c < NCH; c++) {
        size_t i = (((size_t)(dirb * NCH + c)) * DI + dd) * 16 + s;
        float tmp = (float)Q[i];
        Q[i] = (f16)run;
        run = (float)P[i] * run + tmp;
    }
}

__global__ void k_scan_p3(const float* __restrict__ DBLF, const float* __restrict__ DBLB,
                          const bf16* __restrict__ XSF,  const bf16* __restrict__ XSB,
                          const bf16* __restrict__ XZF,  const bf16* __restrict__ XZB,
                          const float* __restrict__ fWdt, const float* __restrict__ fbdt,
                          const float* __restrict__ bWdt, const float* __restrict__ bbdt,
                          const float* __restrict__ a2tab,
                          const float* __restrict__ fD,    const float* __restrict__ bD,
                          const f16* __restrict__ Q,
                          bf16* __restrict__ YSF, bf16* __restrict__ YSB) {
    int t = blockIdx.x * blockDim.x + threadIdx.x;   // 786432
    int d = t % DI;
    int g = t / DI;
    int chunk = g & (NCH - 1);
    int dirb = g >> 10;
    int b = dirb & 1, dir = dirb >> 1;

    const float* DBL = dir ? DBLB : DBLF;
    const bf16*  XS  = dir ? XSB  : XSF;
    const bf16*  XZ  = dir ? XZB  : XZF;
    const float* wdt = (dir ? bWdt : fWdt) + d * 6;
    float bdtv = (dir ? bbdt : fbdt)[d];
    float Dp = dir ? bD[d] : fD[d];
    bf16* Y = dir ? YSB : YSF;

    float wd[6];
#pragma unroll
    for (int r = 0; r < 6; r++) wd[r] = wdt[r];
    const float* a2p = a2tab + (dir * DI + d) * 16;
    float A2[16], h[16];
#pragma unroll
    for (int v = 0; v < 4; v++) {
        float4 a2v = *(const float4*)(a2p + 4 * v);
        A2[4*v] = a2v.x; A2[4*v+1] = a2v.y; A2[4*v+2] = a2v.z; A2[4*v+3] = a2v.w;
    }
    size_t idx = ((size_t)g * DI + d) * 16;
    f16x8 q0 = *(const f16x8*)(Q + idx);
    f16x8 q1 = *(const f16x8*)(Q + idx + 8);
#pragma unroll
    for (int j = 0; j < 8; j++) { h[j] = (float)q0[j]; h[8 + j] = (float)q1[j]; }

    int l = dir ? (L_SEQ - 1 - chunk * CHUNK) : chunk * CHUNK;
    int stp = dir ? -1 : 1;

#pragma unroll
    for (int i = 0; i < CHUNK; i++) {
        size_t p = (size_t)b * L_SEQ + l;
        const float* row = DBL + p * LDBL;
        float dtv = bdtv;
#pragma unroll
        for (int r = 0; r < 6; r++) dtv += row[r] * wd[r];
        float del = softplus_f(dtv);
        float xs  = b2f(XS[p * DI + d]);
        float z   = b2f(XZ[p * 384 + 192 + d]);
        const float4* bm = (const float4*)(row + 8);
        float4 B0 = bm[0], B1 = bm[1], B2 = bm[2], B3 = bm[3];
        float4 C0 = bm[4], C1 = bm[5], C2 = bm[6], C3 = bm[7];
        float Bm[16] = {B0.x,B0.y,B0.z,B0.w, B1.x,B1.y,B1.z,B1.w,
                        B2.x,B2.y,B2.z,B2.w, B3.x,B3.y,B3.z,B3.w};
        float Cm[16] = {C0.x,C0.y,C0.z,C0.w, C1.x,C1.y,C1.z,C1.w,
                        C2.x,C2.y,C2.z,C2.w, C3.x,C3.y,C3.z,C3.w};
        float dx = del * xs;
        float pr = 0.f;
#pragma unroll
        for (int s = 0; s < 16; s++) {
            float dA = exp2f(del * A2[s]);
            h[s] = dA * h[s] + dx * Bm[s];
            pr += h[s] * Cm[s];
        }
        Y[p * DI + d] = __float2bfloat16((pr + xs * Dp) * silu_f(z));
        l += stp;
    }
}

// ---------------------------------------------------------------------------
// K9: LDS-tiled mid: x2 = x + gamma1*(yo + x1); XMID planar f32;
// XM2cl = ln_cf(x2) channel-last bf16.
// ---------------------------------------------------------------------------
__global__ void k_mid_t(const float* __restrict__ x, const float* __restrict__ YO,
                        const float* __restrict__ X1,
                        const float* __restrict__ gamma1,
                        const float* __restrict__ ln1w, const float* __restrict__ ln1b,
                        float* __restrict__ XMID, bf16* __restrict__ XM2cl) {
    __shared__ float vt[DIM][TP + 1];
    __shared__ float yt[DIM][TP + 1];
    __shared__ float rs[8][TP], rss[8][TP];
    __shared__ float uu[TP], rr[TP];
    int p0 = blockIdx.x * TP;
    int b = p0 >> 12, l0 = p0 & (L_SEQ - 1);
    int t = threadIdx.x;
    int tg = t >> 5, li = t & 31;

    for (int idx = t; idx < DIM * TP; idx += 256) {
        int q = idx / DIM, c = idx % DIM;
        yt[c][q] = YO[(size_t)(p0 + q) * DIM + c];
    }
    __syncthreads();
    {
        float s = 0.f, ss = 0.f;
        for (int c = tg; c < DIM; c += 8) {
            size_t gi = ((size_t)(b * DIM + c)) * L_SEQ + l0 + li;
            float v = x[gi] + gamma1[c] * (yt[c][li] + X1[gi]);
            XMID[gi] = v;
            vt[c][li] = v;
            s += v; ss += v * v;
        }
        rs[tg][li] = s; rss[tg][li] = ss;
    }
    __syncthreads();
    if (t < TP) {
        float s = 0.f, ss = 0.f;
#pragma unroll
        for (int g = 0; g < 8; g++) { s += rs[g][t]; ss += rss[g][t]; }
        float u = s / DIM;
        uu[t] = u; rr[t] = rsqrtf(ss / DIM - u * u + 1e-6f);
    }
    __syncthreads();
    for (int idx = t; idx < DIM * TP; idx += 256) {
        int q = idx / DIM, c = idx % DIM;
        XM2cl[(size_t)(p0 + q) * DIM + c] =
            __float2bfloat16(ln1w[c] * (vt[c][q] - uu[q]) * rr[q] + ln1b[c]);
    }
}

// ---------------------------------------------------------------------------
// K11: fused dilated dwconvs + GELU gate, vectorized 8 channels/thread.
// mdwt layout [conv][tap][c]. H/G channel-last bf16.
// ---------------------------------------------------------------------------
__global__ void k_msff_v(const bf16* __restrict__ H, const float* __restrict__ mdwt,
                         bf16* __restrict__ G) {
    int i = blockIdx.x * blockDim.x + threadIdx.x;   // NPOS*24
    int cg = i % 24;
    int p = i / 24;
    int c0 = cg * 8;
    int b = p >> 12, l = p & (L_SEQ - 1);
    int y = l >> 6, xc = l & 63;
    float a1[8] = {}, a2[8] = {}, a3[8] = {};
    const unsigned short* Hu = (const unsigned short*)H;

#pragma unroll
    for (int ky = 0; ky < 3; ky++) {
#pragma unroll
        for (int kx = 0; kx < 3; kx++) {
            int tap = ky * 3 + kx;
            // conv1, dil 1
            {
                int y1 = y + (ky - 1), x1 = xc + (kx - 1);
                if (y1 >= 0 && y1 < 64 && x1 >= 0 && x1 < 64) {
                    float4 w0 = *(const float4*)(mdwt + tap * 192 + c0);
                    float4 w1 = *(const float4*)(mdwt + tap * 192 + c0 + 4);
                    ushort8 hv = *(const ushort8*)(Hu +
                        ((size_t)(b * L_SEQ + y1 * 64 + x1)) * 576 + c0);
                    float wv[8] = {w0.x,w0.y,w0.z,w0.w, w1.x,w1.y,w1.z,w1.w};
#pragma unroll
                    for (int j = 0; j < 8; j++) a1[j] += wv[j] * us2f(hv[j]);
                }
            }
            // conv2, dil 2
            {
                int y2 = y + (ky - 1) * 2, x2 = xc + (kx - 1) * 2;
                if (y2 >= 0 && y2 < 64 && x2 >= 0 && x2 < 64) {
                    float4 w0 = *(const float4*)(mdwt + (9 + tap) * 192 + c0);
                    float4 w1 = *(const float4*)(mdwt + (9 + tap) * 192 + c0 + 4);
                    ushort8 hv = *(const ushort8*)(Hu +
                        ((size_t)(b * L_SEQ + y2 * 64 + x2)) * 576 + 192 + c0);
                    float wv[8] = {w0.x,w0.y,w0.z,w0.w, w1.x,w1.y,w1.z,w1.w};
#pragma unroll
                    for (int j = 0; j < 8; j++) a2[j] += wv[j] * us2f(hv[j]);
                }
            }
            // conv3, dil 3
            {
                int y3 = y + (ky - 1) * 3, x3 = xc + (kx - 1) * 3;
                if (y3 >= 0 && y3 < 64 && x3 >= 0 && x3 < 64) {
                    float4 w0 = *(const float4*)(mdwt + (18 + tap) * 192 + c0);
                    float4 w1 = *(const float4*)(mdwt + (18 + tap) * 192 + c0 + 4);
                    ushort8 hv = *(const ushort8*)(Hu +
                        ((size_t)(b * L_SEQ + y3 * 64 + x3)) * 576 + 384 + c0);
                    float wv[8] = {w0.x,w0.y,w0.z,w0.w, w1.x,w1.y,w1.z,w1.w};
#pragma unroll
                    for (int j = 0; j < 8; j++) a3[j] += wv[j] * us2f(hv[j]);
                }
            }
        }
    }
    ushort8 ov;
#pragma unroll
    for (int j = 0; j < 8; j++) {
        float ge = 0.5f * a1[j] * (1.f + erff(a1[j] * 0.70710678118f));
        bf16 t = __float2bfloat16(ge * a2[j] * a3[j]);
        ov[j] = *(unsigned short*)&t;
    }
    *(ushort8*)((unsigned short*)G + (size_t)p * HID + c0) = ov;
}

// ---------------------------------------------------------------------------
extern "C" void kernel_launch(void* const* d_in, const int* in_sizes, int n_in,
                              void* d_out, int out_size, void* d_ws, size_t ws_size,
                              hipStream_t stream) {
    const float* x      = (const float*)d_in[0];
    const float* gamma1 = (const float*)d_in[1];
    const float* gamma2 = (const float*)d_in[2];
    const float* ln1w   = (const float*)d_in[3];
    const float* ln1b   = (const float*)d_in[4];
    const float* mnw    = (const float*)d_in[5];
    const float* mnb    = (const float*)d_in[6];
    const float* fWin   = (const float*)d_in[7];
    const float* fconvw = (const float*)d_in[8];
    const float* fconvb = (const float*)d_in[9];
    const float* fWx    = (const float*)d_in[10];
    const float* fWdt   = (const float*)d_in[11];
    const float* fbdt   = (const float*)d_in[12];
    const float* fAlog  = (const float*)d_in[13];
    const float* fD     = (const float*)d_in[14];
    const float* bWin   = (const float*)d_in[15];
    const float* bconvw = (const float*)d_in[16];
    const float* bconvb = (const float*)d_in[17];
    const float* bWx    = (const float*)d_in[18];
    const float* bWdt   = (const float*)d_in[19];
    const float* bbdt   = (const float*)d_in[20];
    const float* bAlog  = (const float*)d_in[21];
    const float* bD     = (const float*)d_in[22];
    const float* Wout   = (const float*)d_in[23];
    const float* mwin   = (const float*)d_in[24];
    const float* mdw1   = (const float*)d_in[25];
    const float* mdw2   = (const float*)d_in[26];
    const float* mdw3   = (const float*)d_in[27];
    const float* mwout  = (const float*)d_in[28];
    float* out = (float*)d_out;

    float* ws = (float*)d_ws;
    // Fully dedicated regions (no overlays). float offsets; total ~104 MB.
    float* X1    = ws;                       // 786432
    bf16*  XNbf  = (bf16*)(ws + 786432);     // 786432 bf16 (393216 f)
    bf16*  XZF   = (bf16*)(ws + 1179648);    // 3145728 bf16 (1572864 f)
    bf16*  XZB   = (bf16*)(ws + 2752512);    // 3145728 bf16
    bf16*  XSF   = (bf16*)(ws + 4325376);    // 1572864 bf16 (786432 f)
    bf16*  XSB   = (bf16*)(ws + 5111808);    // 1572864 bf16
    float* DBLF  = ws + 5898240;             // 327680
    float* DBLB  = ws + 6225920;             // 327680
    f16*   Ph    = (f16*)(ws + 6553600);     // 12582912 f16 (6291456 f)
    f16*   Qh    = (f16*)(ws + 12845056);    // 12582912 f16
    bf16*  YSFbf = (bf16*)(ws + 19136512);   // 1572864 bf16
    bf16*  YSBbf = (bf16*)(ws + 19922944);   // 1572864 bf16
    float* YO    = ws + 20709376;            // 786432
    float* XMID  = ws + 21495808;            // 786432
    bf16*  XM2cl = (bf16*)(ws + 22282240);   // 786432 bf16
    bf16*  Hcl   = (bf16*)(ws + 22675456);   // 4718592 bf16 (2359296 f)
    bf16*  Gcl   = (bf16*)(ws + 25034752);   // 1572864 bf16
    bf16*  WAR   = (bf16*)(ws + 25821184);   // 180480 bf16 (90240 f)
    float* A2tab = ws + 25911424;            // 6144
    float* MDWT  = ws + 25917568;            // 5184 -> end 25922752 (~104 MB)

    const bf16* fWinB  = WAR;
    const bf16* bWinB  = WAR + 36864;
    const bf16* fWxB   = WAR + 73728;
    const bf16* bWxB   = WAR + 81024;
    const bf16* WoutB  = WAR + 88320;
    const bf16* mwinB  = WAR + 106752;
    const bf16* mwoutB = WAR + 162048;

    // 0. prep: weight casts + A2 table + transposed msff weights
    k_prep<<<750, 256, 0, stream>>>(fWin, bWin, fWx, bWx, Wout, mwin, mwout,
                                    fAlog, bAlog, mdw1, mdw2, mdw3,
                                    WAR, A2tab, MDWT);
    // 1. double LN (LDS-tiled)
    k_ln12_t<<<NPOS / TP, 256, 0, stream>>>(x, ln1w, ln1b, mnw, mnb, X1, XNbf);
    // 2. in-projections, both dirs
    mfma_nt_dir<<<dim3(128, 6, 2), 256, 0, stream>>>(XNbf, XNbf, fWinB, bWinB,
                                                     XZF, XZB, NPOS, 384, DIM, 384, 0, 1);
    // 3. dwconv + silu (vectorized, both dirs)
    k_conv_v<<<dim3(NPOS * 24 / 256, 2), 256, 0, stream>>>(XZF, XZB, fconvw, fconvb,
                                                           bconvw, bconvb, XSF, XSB);
    // 4. x_dbl projections, both dirs (padded LDBL rows)
    mfma_nt_dir<<<dim3(128, 1, 2), 256, 0, stream>>>(XSF, XSB, fWxB, bWxB,
                                                     DBLF, DBLB, NPOS, 38, DI, LDBL, 1, 0);
    // 5-7. chunked parallel scan (CHUNK=4)
    k_scan_p1<<<NREC * NCH / 256, 256, 0, stream>>>(DBLF, DBLB, XSF, XSB,
                                                    fWdt, fbdt, bWdt, bbdt,
                                                    A2tab, Ph, Qh);
    k_scan_p2<<<NREC * 16 / 256, 256, 0, stream>>>(Ph, Qh);
    k_scan_p3<<<NREC * NCH / 256, 256, 0, stream>>>(DBLF, DBLB, XSF, XSB, XZF, XZB,
                                                    fWdt, fbdt, bWdt, bbdt,
                                                    A2tab, fD, bD, Qh,
                                                    YSFbf, YSBbf);
    // 8. out-projection (dual-A MFMA, f32 channel-last YO)
    mfma_out<<<dim3(128, 2), 256, 0, stream>>>(YSFbf, YSBbf, WoutB, YO, NPOS, DIM, DI, DIM);
    // 9. residual + LN (LDS-tiled)
    k_mid_t<<<NPOS / TP, 256, 0, stream>>>(x, YO, X1, gamma1, ln1w, ln1b, XMID, XM2cl);
    // 10. msff in-projection (MFMA, bf16 channel-last H)
    mfma_nt<<<dim3(128, 9), 256, 0, stream>>>(XM2cl, mwinB, Hcl, NPOS, 576, DIM, 576);
    // 11. fused dilated dwconvs + GELU gate (vectorized)
    k_msff_v<<<NPOS * 24 / 256, 256, 0, stream>>>(Hcl, MDWT, Gcl);
    // 12. msff out-projection + fused final residual -> out
    mfma_msffout<<<dim3(2, 128), 256, 0, stream>>>(mwoutB, Gcl, XMID, gamma2, out, DIM, HID);
}

// Round 12
// 289.982 us; speedup vs baseline: 6.2032x; 1.0891x over previous
//
#include <hip/hip_runtime.h>
#include <hip/hip_bf16.h>
#include <math.h>

typedef __hip_bfloat16 bf16;
typedef _Float16 f16;
typedef f16  f16x8  __attribute__((ext_vector_type(8)));
typedef short short8 __attribute__((ext_vector_type(8)));
typedef unsigned short ushort8 __attribute__((ext_vector_type(8)));
typedef float floatx4 __attribute__((ext_vector_type(4)));

#define L_SEQ 4096
#define BATCH 2
#define DIM   96
#define DI    192
#define DS    16
#define HID   192
#define NPOS  (BATCH * L_SEQ)   // 8192
#define NCH   1024              // chunks per sequence
#define CHUNK 4                 // L_SEQ / NCH
#define GRP   32                // chunks per p2 group
#define NGRP  (NCH / GRP)       // 32 groups
#define NREC  (2 * BATCH * DI)  // 768 recurrences (dir,b,d)
#define LDBL  40                // padded x_dbl row stride: dt[0:6), B[8:24), C[24:40)
#define LOG2E 1.44269504088896f
#define TP    32                // positions per LN block

__device__ __forceinline__ float silu_f(float x) { return x / (1.f + __expf(-x)); }
__device__ __forceinline__ float softplus_f(float x) {
    return fmaxf(x, 0.f) + __logf(1.f + __expf(-fabsf(x)));
}
__device__ __forceinline__ float b2f(bf16 v) { return __bfloat162float(v); }
__device__ __forceinline__ float us2f(unsigned short u) {
    union { unsigned int i; float f; } cv; cv.i = ((unsigned int)u) << 16; return cv.f;
}

// ---------------------------------------------------------------------------
// K0: prep — cast GEMM weights fp32->bf16, build A2 table, transpose msff dw.
// ---------------------------------------------------------------------------
__global__ void k_prep(const float* __restrict__ fWin, const float* __restrict__ bWin,
                       const float* __restrict__ fWx,  const float* __restrict__ bWx,
                       const float* __restrict__ Wout, const float* __restrict__ mwin,
                       const float* __restrict__ mwout,
                       const float* __restrict__ fAlog, const float* __restrict__ bAlog,
                       const float* __restrict__ mdw1, const float* __restrict__ mdw2,
                       const float* __restrict__ mdw3,
                       bf16* __restrict__ war, float* __restrict__ a2tab,
                       float* __restrict__ mdwt) {
    int i = blockIdx.x * blockDim.x + threadIdx.x;
    if (i < 180480) {
        float v;
        if (i < 36864)        v = fWin[i];
        else if (i < 73728)   v = bWin[i - 36864];
        else if (i < 81024)   v = fWx[i - 73728];
        else if (i < 88320)   v = bWx[i - 81024];
        else if (i < 106752)  v = Wout[i - 88320];
        else if (i < 162048)  v = mwin[i - 106752];
        else                  v = mwout[i - 162048];
        war[i] = __float2bfloat16(v);
    } else if (i < 186624) {
        int j = i - 180480;                 // 0..6143
        int dir = j / 3072, rem = j % 3072; // [dir][d][s]
        const float* al = dir ? bAlog : fAlog;
        a2tab[j] = -__expf(al[rem]) * LOG2E;
    } else if (i < 191808) {
        int j = i - 186624;                 // 0..5183
        int cv = j / 1728, rem = j % 1728;
        int tap = rem / 192, c = rem % 192;
        const float* src = (cv == 0) ? mdw1 : (cv == 1) ? mdw2 : mdw3;
        mdwt[j] = src[c * 9 + tap];
    }
}

// ---------------------------------------------------------------------------
// K1: LDS-tiled double layernorm.
// ---------------------------------------------------------------------------
__global__ void k_ln12_t(const float* __restrict__ x,
                         const float* __restrict__ ln1w, const float* __restrict__ ln1b,
                         const float* __restrict__ mnw,  const float* __restrict__ mnb,
                         float* __restrict__ X1, bf16* __restrict__ XNbf) {
    __shared__ float xt[DIM][TP + 1];
    __shared__ float rs[8][TP], rss[8][TP];
    __shared__ float uu[TP], rr[TP];
    int p0 = blockIdx.x * TP;
    int b = p0 >> 12, l0 = p0 & (L_SEQ - 1);
    int t = threadIdx.x;
    int tg = t >> 5, li = t & 31;

    for (int idx = t; idx < DIM * TP; idx += 256) {
        int c = idx >> 5, q = idx & 31;
        xt[c][q] = x[((size_t)(b * DIM + c)) * L_SEQ + l0 + q];
    }
    __syncthreads();
    {
        float s = 0.f, ss = 0.f;
        for (int c = tg; c < DIM; c += 8) { float v = xt[c][li]; s += v; ss += v * v; }
        rs[tg][li] = s; rss[tg][li] = ss;
    }
    __syncthreads();
    if (t < TP) {
        float s = 0.f, ss = 0.f;
#pragma unroll
        for (int g = 0; g < 8; g++) { s += rs[g][t]; ss += rss[g][t]; }
        float u = s / DIM;
        uu[t] = u; rr[t] = rsqrtf(ss / DIM - u * u + 1e-6f);
    }
    __syncthreads();
    {
        float u = uu[li], r = rr[li];
        float s2 = 0.f, ss2 = 0.f;
        for (int c = tg; c < DIM; c += 8) {
            float tv = ln1w[c] * (xt[c][li] - u) * r + ln1b[c];
            X1[((size_t)(b * DIM + c)) * L_SEQ + l0 + li] = tv;
            xt[c][li] = tv;
            s2 += tv; ss2 += tv * tv;
        }
        rs[tg][li] = s2; rss[tg][li] = ss2;
    }
    __syncthreads();
    if (t < TP) {
        float s = 0.f, ss = 0.f;
#pragma unroll
        for (int g = 0; g < 8; g++) { s += rs[g][t]; ss += rss[g][t]; }
        float u = s / DIM;
        uu[t] = u; rr[t] = rsqrtf(ss / DIM - u * u + 1e-5f);
    }
    __syncthreads();
    for (int idx = t; idx < DIM * TP; idx += 256) {
        int q = idx / DIM, c = idx % DIM;
        XNbf[(size_t)(p0 + q) * DIM + c] =
            __float2bfloat16((xt[c][q] - uu[q]) * rr[q] * mnw[c] + mnb[c]);
    }
}

// ---------------------------------------------------------------------------
// MFMA NT GEMM, 2-dir batched via blockIdx.z.
// ---------------------------------------------------------------------------
__global__ void mfma_nt_dir(const bf16* __restrict__ A0, const bf16* __restrict__ A1,
                            const bf16* __restrict__ W0, const bf16* __restrict__ W1,
                            void* __restrict__ C0, void* __restrict__ C1,
                            int M, int N, int K, int ldc, int pad6, int obf) {
    int z = blockIdx.z;
    const bf16* A = z ? A1 : A0;
    const bf16* W = z ? W1 : W0;
    void* C = z ? C1 : C0;
    int wave = threadIdx.x >> 6, lane = threadIdx.x & 63;
    int m0 = blockIdx.x * 64 + wave * 16;
    int n0 = blockIdx.y * 64;
    int lm = lane & 15, quad = lane >> 4;
    const short* Ap = (const short*)A + (size_t)(m0 + lm) * K + quad * 8;
    const short* Wp = (const short*)W;
    floatx4 acc[4];
#pragma unroll
    for (int t = 0; t < 4; t++) acc[t] = (floatx4){0.f, 0.f, 0.f, 0.f};
    for (int k0 = 0; k0 < K; k0 += 32) {
        short8 a = *(const short8*)(Ap + k0);
#pragma unroll
        for (int t = 0; t < 4; t++) {
            int n = n0 + t * 16 + lm;
            short8 b = (n < N) ? *(const short8*)(Wp + (size_t)n * K + k0 + quad * 8)
                               : (short8){0,0,0,0,0,0,0,0};
            acc[t] = __builtin_amdgcn_mfma_f32_16x16x32_bf16(a, b, acc[t], 0, 0, 0);
        }
    }
#pragma unroll
    for (int t = 0; t < 4; t++) {
        int n = n0 + t * 16 + lm;
        if (n < N) {
            int nn = (pad6 && n >= 6) ? n + 2 : n;
#pragma unroll
            for (int r = 0; r < 4; r++) {
                int m = m0 + quad * 4 + r;
                if (obf) ((bf16*)C)[(size_t)m * ldc + nn] = __float2bfloat16(acc[t][r]);
                else     ((float*)C)[(size_t)m * ldc + nn] = acc[t][r];
            }
        }
    }
}

// ---------------------------------------------------------------------------
// MFMA NT single-matrix (msff in-projection): C = A @ W^T, bf16 out.
// ---------------------------------------------------------------------------
__global__ void mfma_nt(const bf16* __restrict__ A, const bf16* __restrict__ W,
                        bf16* __restrict__ C, int M, int N, int K, int ldc) {
    int wave = threadIdx.x >> 6, lane = threadIdx.x & 63;
    int m0 = blockIdx.x * 64 + wave * 16;
    int n0 = blockIdx.y * 64;
    int lm = lane & 15, quad = lane >> 4;
    const short* Ap = (const short*)A + (size_t)(m0 + lm) * K + quad * 8;
    const short* Wp = (const short*)W;
    floatx4 acc[4];
#pragma unroll
    for (int t = 0; t < 4; t++) acc[t] = (floatx4){0.f, 0.f, 0.f, 0.f};
    for (int k0 = 0; k0 < K; k0 += 32) {
        short8 a = *(const short8*)(Ap + k0);
#pragma unroll
        for (int t = 0; t < 4; t++) {
            int n = n0 + t * 16 + lm;
            short8 b = (n < N) ? *(const short8*)(Wp + (size_t)n * K + k0 + quad * 8)
                               : (short8){0,0,0,0,0,0,0,0};
            acc[t] = __builtin_amdgcn_mfma_f32_16x16x32_bf16(a, b, acc[t], 0, 0, 0);
        }
    }
#pragma unroll
    for (int t = 0; t < 4; t++) {
        int n = n0 + t * 16 + lm;
        if (n < N) {
#pragma unroll
            for (int r = 0; r < 4; r++) {
                int m = m0 + quad * 4 + r;
                C[(size_t)m * ldc + n] = __float2bfloat16(acc[t][r]);
            }
        }
    }
}

// ---------------------------------------------------------------------------
// Out-projection, dual-A: YO = (Y1+Y2) @ Wout^T, f32 channel-last out.
// ---------------------------------------------------------------------------
__global__ void mfma_out(const bf16* __restrict__ Y1, const bf16* __restrict__ Y2,
                         const bf16* __restrict__ W, float* __restrict__ C,
                         int M, int N, int K, int ldc) {
    int wave = threadIdx.x >> 6, lane = threadIdx.x & 63;
    int m0 = blockIdx.x * 64 + wave * 16;
    int n0 = blockIdx.y * 64;
    int lm = lane & 15, quad = lane >> 4;
    const short* A1p = (const short*)Y1 + (size_t)(m0 + lm) * K + quad * 8;
    const short* A2p = (const short*)Y2 + (size_t)(m0 + lm) * K + quad * 8;
    const short* Wp  = (const short*)W;
    floatx4 acc[4];
#pragma unroll
    for (int t = 0; t < 4; t++) acc[t] = (floatx4){0.f, 0.f, 0.f, 0.f};
    for (int k0 = 0; k0 < K; k0 += 32) {
        short8 a1 = *(const short8*)(A1p + k0);
        short8 a2 = *(const short8*)(A2p + k0);
#pragma unroll
        for (int t = 0; t < 4; t++) {
            int n = n0 + t * 16 + lm;
            short8 b = (n < N) ? *(const short8*)(Wp + (size_t)n * K + k0 + quad * 8)
                               : (short8){0,0,0,0,0,0,0,0};
            acc[t] = __builtin_amdgcn_mfma_f32_16x16x32_bf16(a1, b, acc[t], 0, 0, 0);
            acc[t] = __builtin_amdgcn_mfma_f32_16x16x32_bf16(a2, b, acc[t], 0, 0, 0);
        }
    }
#pragma unroll
    for (int t = 0; t < 4; t++) {
        int n = n0 + t * 16 + lm;
        if (n < N) {
#pragma unroll
            for (int r = 0; r < 4; r++) {
                int m = m0 + quad * 4 + r;
                C[(size_t)m * ldc + n] = acc[t][r];
            }
        }
    }
}

// ---------------------------------------------------------------------------
// msff out-projection + fused final residual (planar f32 out).
// ---------------------------------------------------------------------------
__global__ void mfma_msffout(const bf16* __restrict__ A, const bf16* __restrict__ Bm,
                             const float* __restrict__ XMID, const float* __restrict__ gamma2,
                             float* __restrict__ out, int M, int K) {
    int wave = threadIdx.x >> 6, lane = threadIdx.x & 63;
    int m0 = blockIdx.x * 64 + wave * 16;
    int n0 = blockIdx.y * 64;
    int lm = lane & 15, quad = lane >> 4;
    int am = m0 + lm;
    bool aval = am < M;
    const short* Ap = (const short*)A + (size_t)am * K + quad * 8;
    const short* Bp = (const short*)Bm;
    floatx4 acc[4];
#pragma unroll
    for (int t = 0; t < 4; t++) acc[t] = (floatx4){0.f, 0.f, 0.f, 0.f};
    for (int k0 = 0; k0 < K; k0 += 32) {
        short8 a = aval ? *(const short8*)(Ap + k0) : (short8){0,0,0,0,0,0,0,0};
#pragma unroll
        for (int t = 0; t < 4; t++) {
            int n = n0 + t * 16 + lm;
            short8 b = *(const short8*)(Bp + (size_t)n * K + k0 + quad * 8);
            acc[t] = __builtin_amdgcn_mfma_f32_16x16x32_bf16(a, b, acc[t], 0, 0, 0);
        }
    }
#pragma unroll
    for (int t = 0; t < 4; t++) {
        int n = n0 + t * 16 + lm;
        int b = n >> 12, l = n & (L_SEQ - 1);
#pragma unroll
        for (int r = 0; r < 4; r++) {
            int m = m0 + quad * 4 + r;
            if (m < M) {
                size_t idx = ((size_t)(b * M + m)) * L_SEQ + l;
                out[idx] = XMID[idx] + gamma2[m] * acc[t][r];
            }
        }
    }
}

// ---------------------------------------------------------------------------
// K3: dwconv1d k=4 + bias + silu, vectorized 8 channels/thread.
// ---------------------------------------------------------------------------
__global__ void k_conv_v(const bf16* __restrict__ XZF, const bf16* __restrict__ XZB,
                         const float* __restrict__ fw, const float* __restrict__ fb,
                         const float* __restrict__ bw, const float* __restrict__ bb,
                         bf16* __restrict__ XSF, bf16* __restrict__ XSB) {
    int dirb = blockIdx.y;
    int i = blockIdx.x * blockDim.x + threadIdx.x;   // NPOS*24
    int dg = i % 24;
    int p = i / 24;
    int b = p >> 12, l = p & (L_SEQ - 1);
    int d0 = dg * 8;
    const bf16* XZ = dirb ? XZB : XZF;
    const float* cw = dirb ? bw : fw;
    const float* cb = dirb ? bb : fb;

    float4 w[8];
#pragma unroll
    for (int j = 0; j < 8; j++) w[j] = *(const float4*)(cw + (d0 + j) * 4);
    float acc[8];
#pragma unroll
    for (int j = 0; j < 8; j++) acc[j] = cb[d0 + j];

#pragma unroll
    for (int k = 0; k < 4; k++) {
        int ls = dirb ? (l + 3 - k) : (l - 3 + k);
        if (ls >= 0 && ls < L_SEQ) {
            ushort8 xv = *(const ushort8*)((const unsigned short*)XZ +
                           ((size_t)(b * L_SEQ + ls)) * 384 + d0);
#pragma unroll
            for (int j = 0; j < 8; j++) {
                float wk = (k == 0) ? w[j].x : (k == 1) ? w[j].y : (k == 2) ? w[j].z : w[j].w;
                acc[j] += wk * us2f(xv[j]);
            }
        }
    }
    ushort8 ov;
#pragma unroll
    for (int j = 0; j < 8; j++) {
        bf16 t = __float2bfloat16(silu_f(acc[j]));
        ov[j] = *(unsigned short*)&t;
    }
    *(ushort8*)((unsigned short*)(dirb ? XSB : XSF) + (size_t)p * DI + d0) = ov;
}

// ---------------------------------------------------------------------------
// Chunked parallel scan, CHUNK=4, NCH=1024, A2 table-driven, P/Q fp16.
// Thread map p1/p3: t = g*DI + d, g = dirb*NCH + chunk.
// ---------------------------------------------------------------------------
__global__ void k_scan_p1(const float* __restrict__ DBLF, const float* __restrict__ DBLB,
                          const bf16* __restrict__ XSF,  const bf16* __restrict__ XSB,
                          const float* __restrict__ fWdt, const float* __restrict__ fbdt,
                          const float* __restrict__ bWdt, const float* __restrict__ bbdt,
                          const float* __restrict__ a2tab,
                          f16* __restrict__ P, f16* __restrict__ Q) {
    int t = blockIdx.x * blockDim.x + threadIdx.x;   // 786432
    int d = t % DI;
    int g = t / DI;                                   // 0..4095
    int chunk = g & (NCH - 1);
    int dirb = g >> 10;
    int b = dirb & 1, dir = dirb >> 1;

    const float* DBL = dir ? DBLB : DBLF;
    const bf16*  XS  = dir ? XSB  : XSF;
    const float* wdt = (dir ? bWdt : fWdt) + d * 6;
    float bdtv = (dir ? bbdt : fbdt)[d];

    float wd[6];
#pragma unroll
    for (int r = 0; r < 6; r++) wd[r] = wdt[r];
    const float* a2p = a2tab + (dir * DI + d) * 16;
    float A2[16], h[16];
#pragma unroll
    for (int v = 0; v < 4; v++) {
        float4 a2v = *(const float4*)(a2p + 4 * v);
        A2[4*v] = a2v.x; A2[4*v+1] = a2v.y; A2[4*v+2] = a2v.z; A2[4*v+3] = a2v.w;
    }
#pragma unroll
    for (int s = 0; s < 16; s++) h[s] = 0.f;

    int l = dir ? (L_SEQ - 1 - chunk * CHUNK) : chunk * CHUNK;
    int stp = dir ? -1 : 1;
    float sumdel = 0.f;

#pragma unroll
    for (int i = 0; i < CHUNK; i++) {
        size_t p = (size_t)b * L_SEQ + l;
        const float* row = DBL + p * LDBL;
        float dtv = bdtv;
#pragma unroll
        for (int r = 0; r < 6; r++) dtv += row[r] * wd[r];
        float del = softplus_f(dtv);
        float xs  = b2f(XS[p * DI + d]);
        const float4* bm = (const float4*)(row + 8);
        float4 B0 = bm[0], B1 = bm[1], B2 = bm[2], B3 = bm[3];
        float Bm[16] = {B0.x,B0.y,B0.z,B0.w, B1.x,B1.y,B1.z,B1.w,
                        B2.x,B2.y,B2.z,B2.w, B3.x,B3.y,B3.z,B3.w};
        float dx = del * xs;
        sumdel += del;
#pragma unroll
        for (int s = 0; s < 16; s++) {
            float dA = exp2f(del * A2[s]);
            h[s] = dA * h[s] + dx * Bm[s];
        }
        l += stp;
    }
    size_t idx = ((size_t)g * DI + d) * 16;
    f16x8 q0, q1, p0, p1;
#pragma unroll
    for (int j = 0; j < 8; j++) {
        q0[j] = (f16)h[j];
        q1[j] = (f16)h[8 + j];
        p0[j] = (f16)exp2f(A2[j] * sumdel);
        p1[j] = (f16)exp2f(A2[8 + j] * sumdel);
    }
    *(f16x8*)(Q + idx)     = q0;
    *(f16x8*)(Q + idx + 8) = q1;
    *(f16x8*)(P + idx)     = p0;
    *(f16x8*)(P + idx + 8) = p1;
}

// p2a: compose GRP consecutive chunk ops into one group op (f32).
// thread: t = ((dirb*NGRP + grp)*DI + d)*2 + s8   (49152 threads)
__global__ void k_scan_p2a(const f16* __restrict__ P, const f16* __restrict__ Q,
                           float* __restrict__ Pg, float* __restrict__ Qg) {
    int t = blockIdx.x * blockDim.x + threadIdx.x;
    int s8 = t & 1;
    int d = (t >> 1) % DI;
    int rest = t / (DI * 2);
    int grp = rest % NGRP;
    int dirb = rest / NGRP;

    float Pr[8], Qr[8];
#pragma unroll
    for (int j = 0; j < 8; j++) { Pr[j] = 1.f; Qr[j] = 0.f; }

    size_t base = (((size_t)(dirb * NCH + grp * GRP)) * DI + d) * 16 + s8 * 8;
    for (int i = 0; i < GRP; i++) {
        size_t idx = base + (size_t)i * (DI * 16);
        f16x8 p8 = *(const f16x8*)(P + idx);
        f16x8 q8 = *(const f16x8*)(Q + idx);
#pragma unroll
        for (int j = 0; j < 8; j++) {
            float pv = (float)p8[j], qv = (float)q8[j];
            Qr[j] = pv * Qr[j] + qv;
            Pr[j] *= pv;
        }
    }
    size_t gidx = (((size_t)(dirb * NGRP + grp)) * DI + d) * 16 + s8 * 8;
#pragma unroll
    for (int v = 0; v < 2; v++) {
        *(float4*)(Pg + gidx + 4 * v) = make_float4(Pr[4*v], Pr[4*v+1], Pr[4*v+2], Pr[4*v+3]);
        *(float4*)(Qg + gidx + 4 * v) = make_float4(Qr[4*v], Qr[4*v+1], Qr[4*v+2], Qr[4*v+3]);
    }
}

// p2b: exclusive scan over NGRP group ops per (dirb,d,s); Qg <- exclusive Q.
__global__ void k_scan_p2b(const float* __restrict__ Pg, float* __restrict__ Qg) {
    int u = blockIdx.x * blockDim.x + threadIdx.x;   // 12288
    int s = u & 15;
    int dd = (u >> 4) % DI;
    int dirb = u / (DI * 16);
    float runP = 1.f, runQ = 0.f;
#pragma unroll
    for (int g = 0; g < NGRP; g++) {
        size_t i = (((size_t)(dirb * NGRP + g)) * DI + dd) * 16 + s;
        float pg = Pg[i], qg = Qg[i];
        Qg[i] = runQ;
        runQ = pg * runQ + qg;
        runP *= pg;   // kept for exactness of composition semantics (dead value)
    }
}

// p2c: replay GRP chunks from the group's exclusive prefix; Q[chunk] <- state
// at chunk start (f16).
__global__ void k_scan_p2c(const f16* __restrict__ P, f16* __restrict__ Q,
                           const float* __restrict__ Qg) {
    int t = blockIdx.x * blockDim.x + threadIdx.x;
    int s8 = t & 1;
    int d = (t >> 1) % DI;
    int rest = t / (DI * 2);
    int grp = rest % NGRP;
    int dirb = rest / NGRP;

    size_t gidx = (((size_t)(dirb * NGRP + grp)) * DI + d) * 16 + s8 * 8;
    float runQ[8];
#pragma unroll
    for (int v = 0; v < 2; v++) {
        float4 qv = *(const float4*)(Qg + gidx + 4 * v);
        runQ[4*v] = qv.x; runQ[4*v+1] = qv.y; runQ[4*v+2] = qv.z; runQ[4*v+3] = qv.w;
    }

    size_t base = (((size_t)(dirb * NCH + grp * GRP)) * DI + d) * 16 + s8 * 8;
    for (int i = 0; i < GRP; i++) {
        size_t idx = base + (size_t)i * (DI * 16);
        f16x8 p8 = *(const f16x8*)(P + idx);
        f16x8 q8 = *(const f16x8*)(Q + idx);
        f16x8 o8;
#pragma unroll
        for (int j = 0; j < 8; j++) {
            o8[j] = (f16)runQ[j];
            runQ[j] = (float)p8[j] * runQ[j] + (float)q8[j];
        }
        *(f16x8*)(Q + idx) = o8;
    }
}

__global__ void k_scan_p3(const float* __restrict__ DBLF, const float* __restrict__ DBLB,
                          const bf16* __restrict__ XSF,  const bf16* __restrict__ XSB,
                          const bf16* __restrict__ XZF,  const bf16* __restrict__ XZB,
                          const float* __restrict__ fWdt, const float* __restrict__ fbdt,
                          const float* __restrict__ bWdt, const float* __restrict__ bbdt,
                          const float* __restrict__ a2tab,
                          const float* __restrict__ fD,    const float* __restrict__ bD,
                          const f16* __restrict__ Q,
                          bf16* __restrict__ YSF, bf16* __restrict__ YSB) {
    int t = blockIdx.x * blockDim.x + threadIdx.x;   // 786432
    int d = t % DI;
    int g = t / DI;
    int chunk = g & (NCH - 1);
    int dirb = g >> 10;
    int b = dirb & 1, dir = dirb >> 1;

    const float* DBL = dir ? DBLB : DBLF;
    const bf16*  XS  = dir ? XSB  : XSF;
    const bf16*  XZ  = dir ? XZB  : XZF;
    const float* wdt = (dir ? bWdt : fWdt) + d * 6;
    float bdtv = (dir ? bbdt : fbdt)[d];
    float Dp = dir ? bD[d] : fD[d];
    bf16* Y = dir ? YSB : YSF;

    float wd[6];
#pragma unroll
    for (int r = 0; r < 6; r++) wd[r] = wdt[r];
    const float* a2p = a2tab + (dir * DI + d) * 16;
    float A2[16], h[16];
#pragma unroll
    for (int v = 0; v < 4; v++) {
        float4 a2v = *(const float4*)(a2p + 4 * v);
        A2[4*v] = a2v.x; A2[4*v+1] = a2v.y; A2[4*v+2] = a2v.z; A2[4*v+3] = a2v.w;
    }
    size_t idx = ((size_t)g * DI + d) * 16;
    f16x8 q0 = *(const f16x8*)(Q + idx);
    f16x8 q1 = *(const f16x8*)(Q + idx + 8);
#pragma unroll
    for (int j = 0; j < 8; j++) { h[j] = (float)q0[j]; h[8 + j] = (float)q1[j]; }

    int l = dir ? (L_SEQ - 1 - chunk * CHUNK) : chunk * CHUNK;
    int stp = dir ? -1 : 1;

#pragma unroll
    for (int i = 0; i < CHUNK; i++) {
        size_t p = (size_t)b * L_SEQ + l;
        const float* row = DBL + p * LDBL;
        float dtv = bdtv;
#pragma unroll
        for (int r = 0; r < 6; r++) dtv += row[r] * wd[r];
        float del = softplus_f(dtv);
        float xs  = b2f(XS[p * DI + d]);
        float z   = b2f(XZ[p * 384 + 192 + d]);
        const float4* bm = (const float4*)(row + 8);
        float4 B0 = bm[0], B1 = bm[1], B2 = bm[2], B3 = bm[3];
        float4 C0 = bm[4], C1 = bm[5], C2 = bm[6], C3 = bm[7];
        float Bm[16] = {B0.x,B0.y,B0.z,B0.w, B1.x,B1.y,B1.z,B1.w,
                        B2.x,B2.y,B2.z,B2.w, B3.x,B3.y,B3.z,B3.w};
        float Cm[16] = {C0.x,C0.y,C0.z,C0.w, C1.x,C1.y,C1.z,C1.w,
                        C2.x,C2.y,C2.z,C2.w, C3.x,C3.y,C3.z,C3.w};
        float dx = del * xs;
        float pr = 0.f;
#pragma unroll
        for (int s = 0; s < 16; s++) {
            float dA = exp2f(del * A2[s]);
            h[s] = dA * h[s] + dx * Bm[s];
            pr += h[s] * Cm[s];
        }
        Y[p * DI + d] = __float2bfloat16((pr + xs * Dp) * silu_f(z));
        l += stp;
    }
}

// ---------------------------------------------------------------------------
// K9: LDS-tiled mid.
// ---------------------------------------------------------------------------
__global__ void k_mid_t(const float* __restrict__ x, const float* __restrict__ YO,
                        const float* __restrict__ X1,
                        const float* __restrict__ gamma1,
                        const float* __restrict__ ln1w, const float* __restrict__ ln1b,
                        float* __restrict__ XMID, bf16* __restrict__ XM2cl) {
    __shared__ float vt[DIM][TP + 1];
    __shared__ float yt[DIM][TP + 1];
    __shared__ float rs[8][TP], rss[8][TP];
    __shared__ float uu[TP], rr[TP];
    int p0 = blockIdx.x * TP;
    int b = p0 >> 12, l0 = p0 & (L_SEQ - 1);
    int t = threadIdx.x;
    int tg = t >> 5, li = t & 31;

    for (int idx = t; idx < DIM * TP; idx += 256) {
        int q = idx / DIM, c = idx % DIM;
        yt[c][q] = YO[(size_t)(p0 + q) * DIM + c];
    }
    __syncthreads();
    {
        float s = 0.f, ss = 0.f;
        for (int c = tg; c < DIM; c += 8) {
            size_t gi = ((size_t)(b * DIM + c)) * L_SEQ + l0 + li;
            float v = x[gi] + gamma1[c] * (yt[c][li] + X1[gi]);
            XMID[gi] = v;
            vt[c][li] = v;
            s += v; ss += v * v;
        }
        rs[tg][li] = s; rss[tg][li] = ss;
    }
    __syncthreads();
    if (t < TP) {
        float s = 0.f, ss = 0.f;
#pragma unroll
        for (int g = 0; g < 8; g++) { s += rs[g][t]; ss += rss[g][t]; }
        float u = s / DIM;
        uu[t] = u; rr[t] = rsqrtf(ss / DIM - u * u + 1e-6f);
    }
    __syncthreads();
    for (int idx = t; idx < DIM * TP; idx += 256) {
        int q = idx / DIM, c = idx % DIM;
        XM2cl[(size_t)(p0 + q) * DIM + c] =
            __float2bfloat16(ln1w[c] * (vt[c][q] - uu[q]) * rr[q] + ln1b[c]);
    }
}

// ---------------------------------------------------------------------------
// K11: fused dilated dwconvs + GELU gate, vectorized 8 channels/thread.
// ---------------------------------------------------------------------------
__global__ void k_msff_v(const bf16* __restrict__ H, const float* __restrict__ mdwt,
                         bf16* __restrict__ G) {
    int i = blockIdx.x * blockDim.x + threadIdx.x;   // NPOS*24
    int cg = i % 24;
    int p = i / 24;
    int c0 = cg * 8;
    int b = p >> 12, l = p & (L_SEQ - 1);
    int y = l >> 6, xc = l & 63;
    float a1[8] = {}, a2[8] = {}, a3[8] = {};
    const unsigned short* Hu = (const unsigned short*)H;

#pragma unroll
    for (int ky = 0; ky < 3; ky++) {
#pragma unroll
        for (int kx = 0; kx < 3; kx++) {
            int tap = ky * 3 + kx;
            {
                int y1 = y + (ky - 1), x1 = xc + (kx - 1);
                if (y1 >= 0 && y1 < 64 && x1 >= 0 && x1 < 64) {
                    float4 w0 = *(const float4*)(mdwt + tap * 192 + c0);
                    float4 w1 = *(const float4*)(mdwt + tap * 192 + c0 + 4);
                    ushort8 hv = *(const ushort8*)(Hu +
                        ((size_t)(b * L_SEQ + y1 * 64 + x1)) * 576 + c0);
                    float wv[8] = {w0.x,w0.y,w0.z,w0.w, w1.x,w1.y,w1.z,w1.w};
#pragma unroll
                    for (int j = 0; j < 8; j++) a1[j] += wv[j] * us2f(hv[j]);
                }
            }
            {
                int y2 = y + (ky - 1) * 2, x2 = xc + (kx - 1) * 2;
                if (y2 >= 0 && y2 < 64 && x2 >= 0 && x2 < 64) {
                    float4 w0 = *(const float4*)(mdwt + (9 + tap) * 192 + c0);
                    float4 w1 = *(const float4*)(mdwt + (9 + tap) * 192 + c0 + 4);
                    ushort8 hv = *(const ushort8*)(Hu +
                        ((size_t)(b * L_SEQ + y2 * 64 + x2)) * 576 + 192 + c0);
                    float wv[8] = {w0.x,w0.y,w0.z,w0.w, w1.x,w1.y,w1.z,w1.w};
#pragma unroll
                    for (int j = 0; j < 8; j++) a2[j] += wv[j] * us2f(hv[j]);
                }
            }
            {
                int y3 = y + (ky - 1) * 3, x3 = xc + (kx - 1) * 3;
                if (y3 >= 0 && y3 < 64 && x3 >= 0 && x3 < 64) {
                    float4 w0 = *(const float4*)(mdwt + (18 + tap) * 192 + c0);
                    float4 w1 = *(const float4*)(mdwt + (18 + tap) * 192 + c0 + 4);
                    ushort8 hv = *(const ushort8*)(Hu +
                        ((size_t)(b * L_SEQ + y3 * 64 + x3)) * 576 + 384 + c0);
                    float wv[8] = {w0.x,w0.y,w0.z,w0.w, w1.x,w1.y,w1.z,w1.w};
#pragma unroll
                    for (int j = 0; j < 8; j++) a3[j] += wv[j] * us2f(hv[j]);
                }
            }
        }
    }
    ushort8 ov;
#pragma unroll
    for (int j = 0; j < 8; j++) {
        float ge = 0.5f * a1[j] * (1.f + erff(a1[j] * 0.70710678118f));
        bf16 t = __float2bfloat16(ge * a2[j] * a3[j]);
        ov[j] = *(unsigned short*)&t;
    }
    *(ushort8*)((unsigned short*)G + (size_t)p * HID + c0) = ov;
}

// ---------------------------------------------------------------------------
extern "C" void kernel_launch(void* const* d_in, const int* in_sizes, int n_in,
                              void* d_out, int out_size, void* d_ws, size_t ws_size,
                              hipStream_t stream) {
    const float* x      = (const float*)d_in[0];
    const float* gamma1 = (const float*)d_in[1];
    const float* gamma2 = (const float*)d_in[2];
    const float* ln1w   = (const float*)d_in[3];
    const float* ln1b   = (const float*)d_in[4];
    const float* mnw    = (const float*)d_in[5];
    const float* mnb    = (const float*)d_in[6];
    const float* fWin   = (const float*)d_in[7];
    const float* fconvw = (const float*)d_in[8];
    const float* fconvb = (const float*)d_in[9];
    const float* fWx    = (const float*)d_in[10];
    const float* fWdt   = (const float*)d_in[11];
    const float* fbdt   = (const float*)d_in[12];
    const float* fAlog  = (const float*)d_in[13];
    const float* fD     = (const float*)d_in[14];
    const float* bWin   = (const float*)d_in[15];
    const float* bconvw = (const float*)d_in[16];
    const float* bconvb = (const float*)d_in[17];
    const float* bWx    = (const float*)d_in[18];
    const float* bWdt   = (const float*)d_in[19];
    const float* bbdt   = (const float*)d_in[20];
    const float* bAlog  = (const float*)d_in[21];
    const float* bD     = (const float*)d_in[22];
    const float* Wout   = (const float*)d_in[23];
    const float* mwin   = (const float*)d_in[24];
    const float* mdw1   = (const float*)d_in[25];
    const float* mdw2   = (const float*)d_in[26];
    const float* mdw3   = (const float*)d_in[27];
    const float* mwout  = (const float*)d_in[28];
    float* out = (float*)d_out;

    float* ws = (float*)d_ws;
    // Fully dedicated regions (no overlays). float offsets; total ~110 MB.
    float* X1    = ws;                       // 786432
    bf16*  XNbf  = (bf16*)(ws + 786432);     // 786432 bf16 (393216 f)
    bf16*  XZF   = (bf16*)(ws + 1179648);    // 3145728 bf16 (1572864 f)
    bf16*  XZB   = (bf16*)(ws + 2752512);    // 3145728 bf16
    bf16*  XSF   = (bf16*)(ws + 4325376);    // 1572864 bf16 (786432 f)
    bf16*  XSB   = (bf16*)(ws + 5111808);    // 1572864 bf16
    float* DBLF  = ws + 5898240;             // 327680
    float* DBLB  = ws + 6225920;             // 327680
    f16*   Ph    = (f16*)(ws + 6553600);     // 12582912 f16 (6291456 f)
    f16*   Qh    = (f16*)(ws + 12845056);    // 12582912 f16
    bf16*  YSFbf = (bf16*)(ws + 19136512);   // 1572864 bf16
    bf16*  YSBbf = (bf16*)(ws + 19922944);   // 1572864 bf16
    float* YO    = ws + 20709376;            // 786432
    float* XMID  = ws + 21495808;            // 786432
    bf16*  XM2cl = (bf16*)(ws + 22282240);   // 786432 bf16
    bf16*  Hcl   = (bf16*)(ws + 22675456);   // 4718592 bf16 (2359296 f)
    bf16*  Gcl   = (bf16*)(ws + 25034752);   // 1572864 bf16
    bf16*  WAR   = (bf16*)(ws + 25821184);   // 180480 bf16 (90240 f)
    float* A2tab = ws + 25911424;            // 6144
    float* MDWT  = ws + 25917568;            // 5184
    float* Pgb   = ws + 25922752;            // 393216 (4*NGRP*DI*16)
    float* Qgb   = ws + 26315968;            // 393216 -> end 26709184 (~107 MB)

    const bf16* fWinB  = WAR;
    const bf16* bWinB  = WAR + 36864;
    const bf16* fWxB   = WAR + 73728;
    const bf16* bWxB   = WAR + 81024;
    const bf16* WoutB  = WAR + 88320;
    const bf16* mwinB  = WAR + 106752;
    const bf16* mwoutB = WAR + 162048;

    // 0. prep
    k_prep<<<750, 256, 0, stream>>>(fWin, bWin, fWx, bWx, Wout, mwin, mwout,
                                    fAlog, bAlog, mdw1, mdw2, mdw3,
                                    WAR, A2tab, MDWT);
    // 1. double LN (LDS-tiled)
    k_ln12_t<<<NPOS / TP, 256, 0, stream>>>(x, ln1w, ln1b, mnw, mnb, X1, XNbf);
    // 2. in-projections, both dirs
    mfma_nt_dir<<<dim3(128, 6, 2), 256, 0, stream>>>(XNbf, XNbf, fWinB, bWinB,
                                                     XZF, XZB, NPOS, 384, DIM, 384, 0, 1);
    // 3. dwconv + silu (vectorized, both dirs)
    k_conv_v<<<dim3(NPOS * 24 / 256, 2), 256, 0, stream>>>(XZF, XZB, fconvw, fconvb,
                                                           bconvw, bconvb, XSF, XSB);
    // 4. x_dbl projections, both dirs (padded LDBL rows)
    mfma_nt_dir<<<dim3(128, 1, 2), 256, 0, stream>>>(XSF, XSB, fWxB, bWxB,
                                                     DBLF, DBLB, NPOS, 38, DI, LDBL, 1, 0);
    // 5-9. chunked parallel scan with hierarchical p2
    k_scan_p1<<<NREC * NCH / 256, 256, 0, stream>>>(DBLF, DBLB, XSF, XSB,
                                                    fWdt, fbdt, bWdt, bbdt,
                                                    A2tab, Ph, Qh);
    k_scan_p2a<<<4 * NGRP * DI * 2 / 256, 256, 0, stream>>>(Ph, Qh, Pgb, Qgb);
    k_scan_p2b<<<NREC * 16 / 256, 256, 0, stream>>>(Pgb, Qgb);
    k_scan_p2c<<<4 * NGRP * DI * 2 / 256, 256, 0, stream>>>(Ph, Qh, Qgb);
    k_scan_p3<<<NREC * NCH / 256, 256, 0, stream>>>(DBLF, DBLB, XSF, XSB, XZF, XZB,
                                                    fWdt, fbdt, bWdt, bbdt,
                                                    A2tab, fD, bD, Qh,
                                                    YSFbf, YSBbf);
    // 10. out-projection (dual-A MFMA, f32 channel-last YO)
    mfma_out<<<dim3(128, 2), 256, 0, stream>>>(YSFbf, YSBbf, WoutB, YO, NPOS, DIM, DI, DIM);
    // 11. residual + LN (LDS-tiled)
    k_mid_t<<<NPOS / TP, 256, 0, stream>>>(x, YO, X1, gamma1, ln1w, ln1b, XMID, XM2cl);
    // 12. msff in-projection (MFMA, bf16 channel-last H)
    mfma_nt<<<dim3(128, 9), 256, 0, stream>>>(XM2cl, mwinB, Hcl, NPOS, 576, DIM, 576);
    // 13. fused dilated dwconvs + GELU gate (vectorized)
    k_msff_v<<<NPOS * 24 / 256, 256, 0, stream>>>(Hcl, MDWT, Gcl);
    // 14. msff out-projection + fused final residual -> out
    mfma_msffout<<<dim3(2, 128), 256, 0, stream>>>(mwoutB, Gcl, XMID, gamma2, out, DIM, HID);
}

// Round 13
// 285.963 us; speedup vs baseline: 6.2904x; 1.0141x over previous
//
#include <hip/hip_runtime.h>
#include <hip/hip_bf16.h>
#include <math.h>

typedef __hip_bfloat16 bf16;
typedef _Float16 f16;
typedef f16  f16x8  __attribute__((ext_vector_type(8)));
typedef short short8 __attribute__((ext_vector_type(8)));
typedef unsigned short ushort8 __attribute__((ext_vector_type(8)));
typedef float floatx4 __attribute__((ext_vector_type(4)));

#define L_SEQ 4096
#define BATCH 2
#define DIM   96
#define DI    192
#define DS    16
#define HID   192
#define NPOS  (BATCH * L_SEQ)   // 8192
#define NCH   512               // chunks per sequence
#define CHUNK 8                 // L_SEQ / NCH
#define GRP   32                // chunks per p2 group
#define NGRP  (NCH / GRP)       // 16 groups
#define NREC  (2 * BATCH * DI)  // 768 recurrences (dir,b,d)
#define LDBL  40                // padded x_dbl row stride: dt[0:6), B[8:24), C[24:40)
#define LOG2E 1.44269504088896f
#define TP    32                // positions per LN block

__device__ __forceinline__ float silu_f(float x) { return x / (1.f + __expf(-x)); }
__device__ __forceinline__ float softplus_f(float x) {
    return fmaxf(x, 0.f) + __logf(1.f + __expf(-fabsf(x)));
}
__device__ __forceinline__ float b2f(bf16 v) { return __bfloat162float(v); }
__device__ __forceinline__ float us2f(unsigned short u) {
    union { unsigned int i; float f; } cv; cv.i = ((unsigned int)u) << 16; return cv.f;
}

// ---------------------------------------------------------------------------
// K0: prep — cast GEMM weights fp32->bf16, build A2 table, transpose msff dw.
// ---------------------------------------------------------------------------
__global__ void k_prep(const float* __restrict__ fWin, const float* __restrict__ bWin,
                       const float* __restrict__ fWx,  const float* __restrict__ bWx,
                       const float* __restrict__ Wout, const float* __restrict__ mwin,
                       const float* __restrict__ mwout,
                       const float* __restrict__ fAlog, const float* __restrict__ bAlog,
                       const float* __restrict__ mdw1, const float* __restrict__ mdw2,
                       const float* __restrict__ mdw3,
                       bf16* __restrict__ war, float* __restrict__ a2tab,
                       float* __restrict__ mdwt) {
    int i = blockIdx.x * blockDim.x + threadIdx.x;
    if (i < 180480) {
        float v;
        if (i < 36864)        v = fWin[i];
        else if (i < 73728)   v = bWin[i - 36864];
        else if (i < 81024)   v = fWx[i - 73728];
        else if (i < 88320)   v = bWx[i - 81024];
        else if (i < 106752)  v = Wout[i - 88320];
        else if (i < 162048)  v = mwin[i - 106752];
        else                  v = mwout[i - 162048];
        war[i] = __float2bfloat16(v);
    } else if (i < 186624) {
        int j = i - 180480;                 // 0..6143
        int dir = j / 3072, rem = j % 3072; // [dir][d][s]
        const float* al = dir ? bAlog : fAlog;
        a2tab[j] = -__expf(al[rem]) * LOG2E;
    } else if (i < 191808) {
        int j = i - 186624;                 // 0..5183
        int cv = j / 1728, rem = j % 1728;
        int tap = rem / 192, c = rem % 192;
        const float* src = (cv == 0) ? mdw1 : (cv == 1) ? mdw2 : mdw3;
        mdwt[j] = src[c * 9 + tap];
    }
}

// ---------------------------------------------------------------------------
// K1: LDS-tiled double layernorm. No X1 store (k_mid recomputes LN1 inline).
// ---------------------------------------------------------------------------
__global__ void k_ln12_t(const float* __restrict__ x,
                         const float* __restrict__ ln1w, const float* __restrict__ ln1b,
                         const float* __restrict__ mnw,  const float* __restrict__ mnb,
                         bf16* __restrict__ XNbf) {
    __shared__ float xt[DIM][TP + 1];
    __shared__ float rs[8][TP], rss[8][TP];
    __shared__ float uu[TP], rr[TP];
    int p0 = blockIdx.x * TP;
    int b = p0 >> 12, l0 = p0 & (L_SEQ - 1);
    int t = threadIdx.x;
    int tg = t >> 5, li = t & 31;

    for (int idx = t; idx < DIM * TP; idx += 256) {
        int c = idx >> 5, q = idx & 31;
        xt[c][q] = x[((size_t)(b * DIM + c)) * L_SEQ + l0 + q];
    }
    __syncthreads();
    {
        float s = 0.f, ss = 0.f;
        for (int c = tg; c < DIM; c += 8) { float v = xt[c][li]; s += v; ss += v * v; }
        rs[tg][li] = s; rss[tg][li] = ss;
    }
    __syncthreads();
    if (t < TP) {
        float s = 0.f, ss = 0.f;
#pragma unroll
        for (int g = 0; g < 8; g++) { s += rs[g][t]; ss += rss[g][t]; }
        float u = s / DIM;
        uu[t] = u; rr[t] = rsqrtf(ss / DIM - u * u + 1e-6f);
    }
    __syncthreads();
    {
        float u = uu[li], r = rr[li];
        float s2 = 0.f, ss2 = 0.f;
        for (int c = tg; c < DIM; c += 8) {
            float tv = ln1w[c] * (xt[c][li] - u) * r + ln1b[c];
            xt[c][li] = tv;
            s2 += tv; ss2 += tv * tv;
        }
        rs[tg][li] = s2; rss[tg][li] = ss2;
    }
    __syncthreads();
    if (t < TP) {
        float s = 0.f, ss = 0.f;
#pragma unroll
        for (int g = 0; g < 8; g++) { s += rs[g][t]; ss += rss[g][t]; }
        float u = s / DIM;
        uu[t] = u; rr[t] = rsqrtf(ss / DIM - u * u + 1e-5f);
    }
    __syncthreads();
    for (int idx = t; idx < DIM * TP; idx += 256) {
        int q = idx / DIM, c = idx % DIM;
        XNbf[(size_t)(p0 + q) * DIM + c] =
            __float2bfloat16((xt[c][q] - uu[q]) * rr[q] * mnw[c] + mnb[c]);
    }
}

// ---------------------------------------------------------------------------
// MFMA NT GEMM, 2-dir batched via blockIdx.z.
// ---------------------------------------------------------------------------
__global__ void mfma_nt_dir(const bf16* __restrict__ A0, const bf16* __restrict__ A1,
                            const bf16* __restrict__ W0, const bf16* __restrict__ W1,
                            void* __restrict__ C0, void* __restrict__ C1,
                            int M, int N, int K, int ldc, int pad6, int obf) {
    int z = blockIdx.z;
    const bf16* A = z ? A1 : A0;
    const bf16* W = z ? W1 : W0;
    void* C = z ? C1 : C0;
    int wave = threadIdx.x >> 6, lane = threadIdx.x & 63;
    int m0 = blockIdx.x * 64 + wave * 16;
    int n0 = blockIdx.y * 64;
    int lm = lane & 15, quad = lane >> 4;
    const short* Ap = (const short*)A + (size_t)(m0 + lm) * K + quad * 8;
    const short* Wp = (const short*)W;
    floatx4 acc[4];
#pragma unroll
    for (int t = 0; t < 4; t++) acc[t] = (floatx4){0.f, 0.f, 0.f, 0.f};
    for (int k0 = 0; k0 < K; k0 += 32) {
        short8 a = *(const short8*)(Ap + k0);
#pragma unroll
        for (int t = 0; t < 4; t++) {
            int n = n0 + t * 16 + lm;
            short8 b = (n < N) ? *(const short8*)(Wp + (size_t)n * K + k0 + quad * 8)
                               : (short8){0,0,0,0,0,0,0,0};
            acc[t] = __builtin_amdgcn_mfma_f32_16x16x32_bf16(a, b, acc[t], 0, 0, 0);
        }
    }
#pragma unroll
    for (int t = 0; t < 4; t++) {
        int n = n0 + t * 16 + lm;
        if (n < N) {
            int nn = (pad6 && n >= 6) ? n + 2 : n;
#pragma unroll
            for (int r = 0; r < 4; r++) {
                int m = m0 + quad * 4 + r;
                if (obf) ((bf16*)C)[(size_t)m * ldc + nn] = __float2bfloat16(acc[t][r]);
                else     ((float*)C)[(size_t)m * ldc + nn] = acc[t][r];
            }
        }
    }
}

// ---------------------------------------------------------------------------
// MFMA NT single-matrix (msff in-projection): C = A @ W^T, bf16 out.
// ---------------------------------------------------------------------------
__global__ void mfma_nt(const bf16* __restrict__ A, const bf16* __restrict__ W,
                        bf16* __restrict__ C, int M, int N, int K, int ldc) {
    int wave = threadIdx.x >> 6, lane = threadIdx.x & 63;
    int m0 = blockIdx.x * 64 + wave * 16;
    int n0 = blockIdx.y * 64;
    int lm = lane & 15, quad = lane >> 4;
    const short* Ap = (const short*)A + (size_t)(m0 + lm) * K + quad * 8;
    const short* Wp = (const short*)W;
    floatx4 acc[4];
#pragma unroll
    for (int t = 0; t < 4; t++) acc[t] = (floatx4){0.f, 0.f, 0.f, 0.f};
    for (int k0 = 0; k0 < K; k0 += 32) {
        short8 a = *(const short8*)(Ap + k0);
#pragma unroll
        for (int t = 0; t < 4; t++) {
            int n = n0 + t * 16 + lm;
            short8 b = (n < N) ? *(const short8*)(Wp + (size_t)n * K + k0 + quad * 8)
                               : (short8){0,0,0,0,0,0,0,0};
            acc[t] = __builtin_amdgcn_mfma_f32_16x16x32_bf16(a, b, acc[t], 0, 0, 0);
        }
    }
#pragma unroll
    for (int t = 0; t < 4; t++) {
        int n = n0 + t * 16 + lm;
        if (n < N) {
#pragma unroll
            for (int r = 0; r < 4; r++) {
                int m = m0 + quad * 4 + r;
                C[(size_t)m * ldc + n] = __float2bfloat16(acc[t][r]);
            }
        }
    }
}

// ---------------------------------------------------------------------------
// Out-projection, dual-A: YO = (Y1+Y2) @ Wout^T, f32 channel-last out.
// ---------------------------------------------------------------------------
__global__ void mfma_out(const bf16* __restrict__ Y1, const bf16* __restrict__ Y2,
                         const bf16* __restrict__ W, float* __restrict__ C,
                         int M, int N, int K, int ldc) {
    int wave = threadIdx.x >> 6, lane = threadIdx.x & 63;
    int m0 = blockIdx.x * 64 + wave * 16;
    int n0 = blockIdx.y * 64;
    int lm = lane & 15, quad = lane >> 4;
    const short* A1p = (const short*)Y1 + (size_t)(m0 + lm) * K + quad * 8;
    const short* A2p = (const short*)Y2 + (size_t)(m0 + lm) * K + quad * 8;
    const short* Wp  = (const short*)W;
    floatx4 acc[4];
#pragma unroll
    for (int t = 0; t < 4; t++) acc[t] = (floatx4){0.f, 0.f, 0.f, 0.f};
    for (int k0 = 0; k0 < K; k0 += 32) {
        short8 a1 = *(const short8*)(A1p + k0);
        short8 a2 = *(const short8*)(A2p + k0);
#pragma unroll
        for (int t = 0; t < 4; t++) {
            int n = n0 + t * 16 + lm;
            short8 b = (n < N) ? *(const short8*)(Wp + (size_t)n * K + k0 + quad * 8)
                               : (short8){0,0,0,0,0,0,0,0};
            acc[t] = __builtin_amdgcn_mfma_f32_16x16x32_bf16(a1, b, acc[t], 0, 0, 0);
            acc[t] = __builtin_amdgcn_mfma_f32_16x16x32_bf16(a2, b, acc[t], 0, 0, 0);
        }
    }
#pragma unroll
    for (int t = 0; t < 4; t++) {
        int n = n0 + t * 16 + lm;
        if (n < N) {
#pragma unroll
            for (int r = 0; r < 4; r++) {
                int m = m0 + quad * 4 + r;
                C[(size_t)m * ldc + n] = acc[t][r];
            }
        }
    }
}

// ---------------------------------------------------------------------------
// msff out-projection + fused final residual (planar f32 out).
// ---------------------------------------------------------------------------
__global__ void mfma_msffout(const bf16* __restrict__ A, const bf16* __restrict__ Bm,
                             const float* __restrict__ XMID, const float* __restrict__ gamma2,
                             float* __restrict__ out, int M, int K) {
    int wave = threadIdx.x >> 6, lane = threadIdx.x & 63;
    int m0 = blockIdx.x * 64 + wave * 16;
    int n0 = blockIdx.y * 64;
    int lm = lane & 15, quad = lane >> 4;
    int am = m0 + lm;
    bool aval = am < M;
    const short* Ap = (const short*)A + (size_t)am * K + quad * 8;
    const short* Bp = (const short*)Bm;
    floatx4 acc[4];
#pragma unroll
    for (int t = 0; t < 4; t++) acc[t] = (floatx4){0.f, 0.f, 0.f, 0.f};
    for (int k0 = 0; k0 < K; k0 += 32) {
        short8 a = aval ? *(const short8*)(Ap + k0) : (short8){0,0,0,0,0,0,0,0};
#pragma unroll
        for (int t = 0; t < 4; t++) {
            int n = n0 + t * 16 + lm;
            short8 b = *(const short8*)(Bp + (size_t)n * K + k0 + quad * 8);
            acc[t] = __builtin_amdgcn_mfma_f32_16x16x32_bf16(a, b, acc[t], 0, 0, 0);
        }
    }
#pragma unroll
    for (int t = 0; t < 4; t++) {
        int n = n0 + t * 16 + lm;
        int b = n >> 12, l = n & (L_SEQ - 1);
#pragma unroll
        for (int r = 0; r < 4; r++) {
            int m = m0 + quad * 4 + r;
            if (m < M) {
                size_t idx = ((size_t)(b * M + m)) * L_SEQ + l;
                out[idx] = XMID[idx] + gamma2[m] * acc[t][r];
            }
        }
    }
}

// ---------------------------------------------------------------------------
// K3: dwconv1d k=4 + bias + silu, vectorized 8 channels/thread.
// ---------------------------------------------------------------------------
__global__ void k_conv_v(const bf16* __restrict__ XZF, const bf16* __restrict__ XZB,
                         const float* __restrict__ fw, const float* __restrict__ fb,
                         const float* __restrict__ bw, const float* __restrict__ bb,
                         bf16* __restrict__ XSF, bf16* __restrict__ XSB) {
    int dirb = blockIdx.y;
    int i = blockIdx.x * blockDim.x + threadIdx.x;   // NPOS*24
    int dg = i % 24;
    int p = i / 24;
    int b = p >> 12, l = p & (L_SEQ - 1);
    int d0 = dg * 8;
    const bf16* XZ = dirb ? XZB : XZF;
    const float* cw = dirb ? bw : fw;
    const float* cb = dirb ? bb : fb;

    float4 w[8];
#pragma unroll
    for (int j = 0; j < 8; j++) w[j] = *(const float4*)(cw + (d0 + j) * 4);
    float acc[8];
#pragma unroll
    for (int j = 0; j < 8; j++) acc[j] = cb[d0 + j];

#pragma unroll
    for (int k = 0; k < 4; k++) {
        int ls = dirb ? (l + 3 - k) : (l - 3 + k);
        if (ls >= 0 && ls < L_SEQ) {
            ushort8 xv = *(const ushort8*)((const unsigned short*)XZ +
                           ((size_t)(b * L_SEQ + ls)) * 384 + d0);
#pragma unroll
            for (int j = 0; j < 8; j++) {
                float wk = (k == 0) ? w[j].x : (k == 1) ? w[j].y : (k == 2) ? w[j].z : w[j].w;
                acc[j] += wk * us2f(xv[j]);
            }
        }
    }
    ushort8 ov;
#pragma unroll
    for (int j = 0; j < 8; j++) {
        bf16 t = __float2bfloat16(silu_f(acc[j]));
        ov[j] = *(unsigned short*)&t;
    }
    *(ushort8*)((unsigned short*)(dirb ? XSB : XSF) + (size_t)p * DI + d0) = ov;
}

// ---------------------------------------------------------------------------
// Chunked parallel scan, CHUNK=8, NCH=512, A2 table-driven, P/Q fp16.
// Thread map p1/p3: t = g*DI + d, g = dirb*NCH + chunk.
// ---------------------------------------------------------------------------
__global__ void k_scan_p1(const float* __restrict__ DBLF, const float* __restrict__ DBLB,
                          const bf16* __restrict__ XSF,  const bf16* __restrict__ XSB,
                          const float* __restrict__ fWdt, const float* __restrict__ fbdt,
                          const float* __restrict__ bWdt, const float* __restrict__ bbdt,
                          const float* __restrict__ a2tab,
                          f16* __restrict__ P, f16* __restrict__ Q) {
    int t = blockIdx.x * blockDim.x + threadIdx.x;   // 393216
    int d = t % DI;
    int g = t / DI;                                   // 0..2047
    int chunk = g & (NCH - 1);
    int dirb = g >> 9;
    int b = dirb & 1, dir = dirb >> 1;

    const float* DBL = dir ? DBLB : DBLF;
    const bf16*  XS  = dir ? XSB  : XSF;
    const float* wdt = (dir ? bWdt : fWdt) + d * 6;
    float bdtv = (dir ? bbdt : fbdt)[d];

    float wd[6];
#pragma unroll
    for (int r = 0; r < 6; r++) wd[r] = wdt[r];
    const float* a2p = a2tab + (dir * DI + d) * 16;
    float A2[16], h[16];
#pragma unroll
    for (int v = 0; v < 4; v++) {
        float4 a2v = *(const float4*)(a2p + 4 * v);
        A2[4*v] = a2v.x; A2[4*v+1] = a2v.y; A2[4*v+2] = a2v.z; A2[4*v+3] = a2v.w;
    }
#pragma unroll
    for (int s = 0; s < 16; s++) h[s] = 0.f;

    int l = dir ? (L_SEQ - 1 - chunk * CHUNK) : chunk * CHUNK;
    int stp = dir ? -1 : 1;
    float sumdel = 0.f;

    for (int i = 0; i < CHUNK; i++) {
        size_t p = (size_t)b * L_SEQ + l;
        const float* row = DBL + p * LDBL;
        float dtv = bdtv;
#pragma unroll
        for (int r = 0; r < 6; r++) dtv += row[r] * wd[r];
        float del = softplus_f(dtv);
        float xs  = b2f(XS[p * DI + d]);
        const float4* bm = (const float4*)(row + 8);
        float4 B0 = bm[0], B1 = bm[1], B2 = bm[2], B3 = bm[3];
        float Bm[16] = {B0.x,B0.y,B0.z,B0.w, B1.x,B1.y,B1.z,B1.w,
                        B2.x,B2.y,B2.z,B2.w, B3.x,B3.y,B3.z,B3.w};
        float dx = del * xs;
        sumdel += del;
#pragma unroll
        for (int s = 0; s < 16; s++) {
            float dA = exp2f(del * A2[s]);
            h[s] = dA * h[s] + dx * Bm[s];
        }
        l += stp;
    }
    size_t idx = ((size_t)g * DI + d) * 16;
    f16x8 q0, q1, p0, p1;
#pragma unroll
    for (int j = 0; j < 8; j++) {
        q0[j] = (f16)h[j];
        q1[j] = (f16)h[8 + j];
        p0[j] = (f16)exp2f(A2[j] * sumdel);
        p1[j] = (f16)exp2f(A2[8 + j] * sumdel);
    }
    *(f16x8*)(Q + idx)     = q0;
    *(f16x8*)(Q + idx + 8) = q1;
    *(f16x8*)(P + idx)     = p0;
    *(f16x8*)(P + idx + 8) = p1;
}

// p2a: compose GRP consecutive chunk ops into one group op (f32).
// thread: t = ((dirb*NGRP + grp)*DI + d)*2 + s8   (24576 threads)
__global__ void k_scan_p2a(const f16* __restrict__ P, const f16* __restrict__ Q,
                           float* __restrict__ Pg, float* __restrict__ Qg) {
    int t = blockIdx.x * blockDim.x + threadIdx.x;
    int s8 = t & 1;
    int d = (t >> 1) % DI;
    int rest = t / (DI * 2);
    int grp = rest % NGRP;
    int dirb = rest / NGRP;

    float Pr[8], Qr[8];
#pragma unroll
    for (int j = 0; j < 8; j++) { Pr[j] = 1.f; Qr[j] = 0.f; }

    size_t base = (((size_t)(dirb * NCH + grp * GRP)) * DI + d) * 16 + s8 * 8;
    for (int i = 0; i < GRP; i++) {
        size_t idx = base + (size_t)i * (DI * 16);
        f16x8 p8 = *(const f16x8*)(P + idx);
        f16x8 q8 = *(const f16x8*)(Q + idx);
#pragma unroll
        for (int j = 0; j < 8; j++) {
            float pv = (float)p8[j], qv = (float)q8[j];
            Qr[j] = pv * Qr[j] + qv;
            Pr[j] *= pv;
        }
    }
    size_t gidx = (((size_t)(dirb * NGRP + grp)) * DI + d) * 16 + s8 * 8;
#pragma unroll
    for (int v = 0; v < 2; v++) {
        *(float4*)(Pg + gidx + 4 * v) = make_float4(Pr[4*v], Pr[4*v+1], Pr[4*v+2], Pr[4*v+3]);
        *(float4*)(Qg + gidx + 4 * v) = make_float4(Qr[4*v], Qr[4*v+1], Qr[4*v+2], Qr[4*v+3]);
    }
}

// p2b: exclusive scan over NGRP group ops per (dirb,d,s); Qg <- exclusive Q.
__global__ void k_scan_p2b(const float* __restrict__ Pg, float* __restrict__ Qg) {
    int u = blockIdx.x * blockDim.x + threadIdx.x;   // 12288
    int s = u & 15;
    int dd = (u >> 4) % DI;
    int dirb = u / (DI * 16);
    float runQ = 0.f;
#pragma unroll
    for (int g = 0; g < NGRP; g++) {
        size_t i = (((size_t)(dirb * NGRP + g)) * DI + dd) * 16 + s;
        float pg = Pg[i], qg = Qg[i];
        Qg[i] = runQ;
        runQ = pg * runQ + qg;
    }
}

// p2c: replay GRP chunks from the group's exclusive prefix; Q[chunk] <- state
// at chunk start (f16).
__global__ void k_scan_p2c(const f16* __restrict__ P, f16* __restrict__ Q,
                           const float* __restrict__ Qg) {
    int t = blockIdx.x * blockDim.x + threadIdx.x;
    int s8 = t & 1;
    int d = (t >> 1) % DI;
    int rest = t / (DI * 2);
    int grp = rest % NGRP;
    int dirb = rest / NGRP;

    size_t gidx = (((size_t)(dirb * NGRP + grp)) * DI + d) * 16 + s8 * 8;
    float runQ[8];
#pragma unroll
    for (int v = 0; v < 2; v++) {
        float4 qv = *(const float4*)(Qg + gidx + 4 * v);
        runQ[4*v] = qv.x; runQ[4*v+1] = qv.y; runQ[4*v+2] = qv.z; runQ[4*v+3] = qv.w;
    }

    size_t base = (((size_t)(dirb * NCH + grp * GRP)) * DI + d) * 16 + s8 * 8;
    for (int i = 0; i < GRP; i++) {
        size_t idx = base + (size_t)i * (DI * 16);
        f16x8 p8 = *(const f16x8*)(P + idx);
        f16x8 q8 = *(const f16x8*)(Q + idx);
        f16x8 o8;
#pragma unroll
        for (int j = 0; j < 8; j++) {
            o8[j] = (f16)runQ[j];
            runQ[j] = (float)p8[j] * runQ[j] + (float)q8[j];
        }
        *(f16x8*)(Q + idx) = o8;
    }
}

__global__ void k_scan_p3(const float* __restrict__ DBLF, const float* __restrict__ DBLB,
                          const bf16* __restrict__ XSF,  const bf16* __restrict__ XSB,
                          const bf16* __restrict__ XZF,  const bf16* __restrict__ XZB,
                          const float* __restrict__ fWdt, const float* __restrict__ fbdt,
                          const float* __restrict__ bWdt, const float* __restrict__ bbdt,
                          const float* __restrict__ a2tab,
                          const float* __restrict__ fD,    const float* __restrict__ bD,
                          const f16* __restrict__ Q,
                          bf16* __restrict__ YSF, bf16* __restrict__ YSB) {
    int t = blockIdx.x * blockDim.x + threadIdx.x;   // 393216
    int d = t % DI;
    int g = t / DI;
    int chunk = g & (NCH - 1);
    int dirb = g >> 9;
    int b = dirb & 1, dir = dirb >> 1;

    const float* DBL = dir ? DBLB : DBLF;
    const bf16*  XS  = dir ? XSB  : XSF;
    const bf16*  XZ  = dir ? XZB  : XZF;
    const float* wdt = (dir ? bWdt : fWdt) + d * 6;
    float bdtv = (dir ? bbdt : fbdt)[d];
    float Dp = dir ? bD[d] : fD[d];
    bf16* Y = dir ? YSB : YSF;

    float wd[6];
#pragma unroll
    for (int r = 0; r < 6; r++) wd[r] = wdt[r];
    const float* a2p = a2tab + (dir * DI + d) * 16;
    float A2[16], h[16];
#pragma unroll
    for (int v = 0; v < 4; v++) {
        float4 a2v = *(const float4*)(a2p + 4 * v);
        A2[4*v] = a2v.x; A2[4*v+1] = a2v.y; A2[4*v+2] = a2v.z; A2[4*v+3] = a2v.w;
    }
    size_t idx = ((size_t)g * DI + d) * 16;
    f16x8 q0 = *(const f16x8*)(Q + idx);
    f16x8 q1 = *(const f16x8*)(Q + idx + 8);
#pragma unroll
    for (int j = 0; j < 8; j++) { h[j] = (float)q0[j]; h[8 + j] = (float)q1[j]; }

    int l = dir ? (L_SEQ - 1 - chunk * CHUNK) : chunk * CHUNK;
    int stp = dir ? -1 : 1;

    for (int i = 0; i < CHUNK; i++) {
        size_t p = (size_t)b * L_SEQ + l;
        const float* row = DBL + p * LDBL;
        float dtv = bdtv;
#pragma unroll
        for (int r = 0; r < 6; r++) dtv += row[r] * wd[r];
        float del = softplus_f(dtv);
        float xs  = b2f(XS[p * DI + d]);
        float z   = b2f(XZ[p * 384 + 192 + d]);
        const float4* bm = (const float4*)(row + 8);
        float4 B0 = bm[0], B1 = bm[1], B2 = bm[2], B3 = bm[3];
        float4 C0 = bm[4], C1 = bm[5], C2 = bm[6], C3 = bm[7];
        float Bm[16] = {B0.x,B0.y,B0.z,B0.w, B1.x,B1.y,B1.z,B1.w,
                        B2.x,B2.y,B2.z,B2.w, B3.x,B3.y,B3.z,B3.w};
        float Cm[16] = {C0.x,C0.y,C0.z,C0.w, C1.x,C1.y,C1.z,C1.w,
                        C2.x,C2.y,C2.z,C2.w, C3.x,C3.y,C3.z,C3.w};
        float dx = del * xs;
        float pr = 0.f;
#pragma unroll
        for (int s = 0; s < 16; s++) {
            float dA = exp2f(del * A2[s]);
            h[s] = dA * h[s] + dx * Bm[s];
            pr += h[s] * Cm[s];
        }
        Y[p * DI + d] = __float2bfloat16((pr + xs * Dp) * silu_f(z));
        l += stp;
    }
}

// ---------------------------------------------------------------------------
// K9: LDS-tiled mid with inline LN1 recompute:
// x2 = x + gamma1*(yo + ln_cf(x)); XMID planar f32; XM2cl = ln_cf(x2) bf16 cl.
// ---------------------------------------------------------------------------
__global__ void k_mid_t(const float* __restrict__ x, const float* __restrict__ YO,
                        const float* __restrict__ gamma1,
                        const float* __restrict__ ln1w, const float* __restrict__ ln1b,
                        float* __restrict__ XMID, bf16* __restrict__ XM2cl) {
    __shared__ float xt[DIM][TP + 1];
    __shared__ float yt[DIM][TP + 1];
    __shared__ float rs[8][TP], rss[8][TP];
    __shared__ float uu[TP], rr[TP];
    int p0 = blockIdx.x * TP;
    int b = p0 >> 12, l0 = p0 & (L_SEQ - 1);
    int t = threadIdx.x;
    int tg = t >> 5, li = t & 31;

    // load x (planar, coalesced) and YO (channel-last)
    for (int idx = t; idx < DIM * TP; idx += 256) {
        int c = idx >> 5, q = idx & 31;
        xt[c][q] = x[((size_t)(b * DIM + c)) * L_SEQ + l0 + q];
    }
    for (int idx = t; idx < DIM * TP; idx += 256) {
        int q = idx / DIM, c = idx % DIM;
        yt[c][q] = YO[(size_t)(p0 + q) * DIM + c];
    }
    __syncthreads();
    // stats of x (LN1)
    {
        float s = 0.f, ss = 0.f;
        for (int c = tg; c < DIM; c += 8) { float v = xt[c][li]; s += v; ss += v * v; }
        rs[tg][li] = s; rss[tg][li] = ss;
    }
    __syncthreads();
    if (t < TP) {
        float s = 0.f, ss = 0.f;
#pragma unroll
        for (int g = 0; g < 8; g++) { s += rs[g][t]; ss += rss[g][t]; }
        float u = s / DIM;
        uu[t] = u; rr[t] = rsqrtf(ss / DIM - u * u + 1e-6f);
    }
    __syncthreads();
    // v = x + gamma1*(yo + ln1(x)); stats of v
    {
        float u = uu[li], r = rr[li];
        float s = 0.f, ss = 0.f;
        for (int c = tg; c < DIM; c += 8) {
            float xv = xt[c][li];
            float x1 = ln1w[c] * (xv - u) * r + ln1b[c];
            float v = xv + gamma1[c] * (yt[c][li] + x1);
            XMID[((size_t)(b * DIM + c)) * L_SEQ + l0 + li] = v;
            xt[c][li] = v;
            s += v; ss += v * v;
        }
        rs[tg][li] = s; rss[tg][li] = ss;
    }
    __syncthreads();
    if (t < TP) {
        float s = 0.f, ss = 0.f;
#pragma unroll
        for (int g = 0; g < 8; g++) { s += rs[g][t]; ss += rss[g][t]; }
        float u = s / DIM;
        uu[t] = u; rr[t] = rsqrtf(ss / DIM - u * u + 1e-6f);
    }
    __syncthreads();
    for (int idx = t; idx < DIM * TP; idx += 256) {
        int q = idx / DIM, c = idx % DIM;
        XM2cl[(size_t)(p0 + q) * DIM + c] =
            __float2bfloat16(ln1w[c] * (xt[c][q] - uu[q]) * rr[q] + ln1b[c]);
    }
}

// ---------------------------------------------------------------------------
// K11: fused dilated dwconvs + GELU gate, vectorized 8 channels/thread.
// ---------------------------------------------------------------------------
__global__ void k_msff_v(const bf16* __restrict__ H, const float* __restrict__ mdwt,
                         bf16* __restrict__ G) {
    int i = blockIdx.x * blockDim.x + threadIdx.x;   // NPOS*24
    int cg = i % 24;
    int p = i / 24;
    int c0 = cg * 8;
    int b = p >> 12, l = p & (L_SEQ - 1);
    int y = l >> 6, xc = l & 63;
    float a1[8] = {}, a2[8] = {}, a3[8] = {};
    const unsigned short* Hu = (const unsigned short*)H;

#pragma unroll
    for (int ky = 0; ky < 3; ky++) {
#pragma unroll
        for (int kx = 0; kx < 3; kx++) {
            int tap = ky * 3 + kx;
            {
                int y1 = y + (ky - 1), x1 = xc + (kx - 1);
                if (y1 >= 0 && y1 < 64 && x1 >= 0 && x1 < 64) {
                    float4 w0 = *(const float4*)(mdwt + tap * 192 + c0);
                    float4 w1 = *(const float4*)(mdwt + tap * 192 + c0 + 4);
                    ushort8 hv = *(const ushort8*)(Hu +
                        ((size_t)(b * L_SEQ + y1 * 64 + x1)) * 576 + c0);
                    float wv[8] = {w0.x,w0.y,w0.z,w0.w, w1.x,w1.y,w1.z,w1.w};
#pragma unroll
                    for (int j = 0; j < 8; j++) a1[j] += wv[j] * us2f(hv[j]);
                }
            }
            {
                int y2 = y + (ky - 1) * 2, x2 = xc + (kx - 1) * 2;
                if (y2 >= 0 && y2 < 64 && x2 >= 0 && x2 < 64) {
                    float4 w0 = *(const float4*)(mdwt + (9 + tap) * 192 + c0);
                    float4 w1 = *(const float4*)(mdwt + (9 + tap) * 192 + c0 + 4);
                    ushort8 hv = *(const ushort8*)(Hu +
                        ((size_t)(b * L_SEQ + y2 * 64 + x2)) * 576 + 192 + c0);
                    float wv[8] = {w0.x,w0.y,w0.z,w0.w, w1.x,w1.y,w1.z,w1.w};
#pragma unroll
                    for (int j = 0; j < 8; j++) a2[j] += wv[j] * us2f(hv[j]);
                }
            }
            {
                int y3 = y + (ky - 1) * 3, x3 = xc + (kx - 1) * 3;
                if (y3 >= 0 && y3 < 64 && x3 >= 0 && x3 < 64) {
                    float4 w0 = *(const float4*)(mdwt + (18 + tap) * 192 + c0);
                    float4 w1 = *(const float4*)(mdwt + (18 + tap) * 192 + c0 + 4);
                    ushort8 hv = *(const ushort8*)(Hu +
                        ((size_t)(b * L_SEQ + y3 * 64 + x3)) * 576 + 384 + c0);
                    float wv[8] = {w0.x,w0.y,w0.z,w0.w, w1.x,w1.y,w1.z,w1.w};
#pragma unroll
                    for (int j = 0; j < 8; j++) a3[j] += wv[j] * us2f(hv[j]);
                }
            }
        }
    }
    ushort8 ov;
#pragma unroll
    for (int j = 0; j < 8; j++) {
        float ge = 0.5f * a1[j] * (1.f + erff(a1[j] * 0.70710678118f));
        bf16 t = __float2bfloat16(ge * a2[j] * a3[j]);
        ov[j] = *(unsigned short*)&t;
    }
    *(ushort8*)((unsigned short*)G + (size_t)p * HID + c0) = ov;
}

// ---------------------------------------------------------------------------
extern "C" void kernel_launch(void* const* d_in, const int* in_sizes, int n_in,
                              void* d_out, int out_size, void* d_ws, size_t ws_size,
                              hipStream_t stream) {
    const float* x      = (const float*)d_in[0];
    const float* gamma1 = (const float*)d_in[1];
    const float* gamma2 = (const float*)d_in[2];
    const float* ln1w   = (const float*)d_in[3];
    const float* ln1b   = (const float*)d_in[4];
    const float* mnw    = (const float*)d_in[5];
    const float* mnb    = (const float*)d_in[6];
    const float* fWin   = (const float*)d_in[7];
    const float* fconvw = (const float*)d_in[8];
    const float* fconvb = (const float*)d_in[9];
    const float* fWx    = (const float*)d_in[10];
    const float* fWdt   = (const float*)d_in[11];
    const float* fbdt   = (const float*)d_in[12];
    const float* fAlog  = (const float*)d_in[13];
    const float* fD     = (const float*)d_in[14];
    const float* bWin   = (const float*)d_in[15];
    const float* bconvw = (const float*)d_in[16];
    const float* bconvb = (const float*)d_in[17];
    const float* bWx    = (const float*)d_in[18];
    const float* bWdt   = (const float*)d_in[19];
    const float* bbdt   = (const float*)d_in[20];
    const float* bAlog  = (const float*)d_in[21];
    const float* bD     = (const float*)d_in[22];
    const float* Wout   = (const float*)d_in[23];
    const float* mwin   = (const float*)d_in[24];
    const float* mdw1   = (const float*)d_in[25];
    const float* mdw2   = (const float*)d_in[26];
    const float* mdw3   = (const float*)d_in[27];
    const float* mwout  = (const float*)d_in[28];
    float* out = (float*)d_out;

    float* ws = (float*)d_ws;
    // Fully dedicated regions (no overlays). float offsets; total ~77 MB.
    bf16*  XNbf  = (bf16*)(ws);              // 786432 bf16 (393216 f)
    bf16*  XZF   = (bf16*)(ws + 393216);     // 3145728 bf16 (1572864 f)
    bf16*  XZB   = (bf16*)(ws + 1966080);    // 3145728 bf16
    bf16*  XSF   = (bf16*)(ws + 3538944);    // 1572864 bf16 (786432 f)
    bf16*  XSB   = (bf16*)(ws + 4325376);    // 1572864 bf16
    float* DBLF  = ws + 5111808;             // 327680
    float* DBLB  = ws + 5439488;             // 327680
    f16*   Ph    = (f16*)(ws + 5767168);     // 6291456 f16 (3145728 f)
    f16*   Qh    = (f16*)(ws + 8912896);     // 6291456 f16
    bf16*  YSFbf = (bf16*)(ws + 12058624);   // 1572864 bf16
    bf16*  YSBbf = (bf16*)(ws + 12845056);   // 1572864 bf16
    float* YO    = ws + 13631488;            // 786432
    float* XMID  = ws + 14417920;            // 786432
    bf16*  XM2cl = (bf16*)(ws + 15204352);   // 786432 bf16 (393216 f)
    bf16*  Hcl   = (bf16*)(ws + 15597568);   // 4718592 bf16 (2359296 f)
    bf16*  Gcl   = (bf16*)(ws + 17956864);   // 1572864 bf16 (786432 f)
    bf16*  WAR   = (bf16*)(ws + 18743296);   // 180480 bf16 (90240 f)
    float* A2tab = ws + 18833536;            // 6144
    float* MDWT  = ws + 18839680;            // 5184
    float* Pgb   = ws + 18844864;            // 196608 (4*NGRP*DI*16)
    float* Qgb   = ws + 19041472;            // 196608 -> end 19238080 (~77 MB)

    const bf16* fWinB  = WAR;
    const bf16* bWinB  = WAR + 36864;
    const bf16* fWxB   = WAR + 73728;
    const bf16* bWxB   = WAR + 81024;
    const bf16* WoutB  = WAR + 88320;
    const bf16* mwinB  = WAR + 106752;
    const bf16* mwoutB = WAR + 162048;

    // 0. prep
    k_prep<<<750, 256, 0, stream>>>(fWin, bWin, fWx, bWx, Wout, mwin, mwout,
                                    fAlog, bAlog, mdw1, mdw2, mdw3,
                                    WAR, A2tab, MDWT);
    // 1. double LN (LDS-tiled, no X1 store)
    k_ln12_t<<<NPOS / TP, 256, 0, stream>>>(x, ln1w, ln1b, mnw, mnb, XNbf);
    // 2. in-projections, both dirs
    mfma_nt_dir<<<dim3(128, 6, 2), 256, 0, stream>>>(XNbf, XNbf, fWinB, bWinB,
                                                     XZF, XZB, NPOS, 384, DIM, 384, 0, 1);
    // 3. dwconv + silu (vectorized, both dirs)
    k_conv_v<<<dim3(NPOS * 24 / 256, 2), 256, 0, stream>>>(XZF, XZB, fconvw, fconvb,
                                                           bconvw, bconvb, XSF, XSB);
    // 4. x_dbl projections, both dirs (padded LDBL rows)
    mfma_nt_dir<<<dim3(128, 1, 2), 256, 0, stream>>>(XSF, XSB, fWxB, bWxB,
                                                     DBLF, DBLB, NPOS, 38, DI, LDBL, 1, 0);
    // 5-9. chunked parallel scan (CHUNK=8) with hierarchical p2
    k_scan_p1<<<NREC * NCH / 256, 256, 0, stream>>>(DBLF, DBLB, XSF, XSB,
                                                    fWdt, fbdt, bWdt, bbdt,
                                                    A2tab, Ph, Qh);
    k_scan_p2a<<<4 * NGRP * DI * 2 / 256, 256, 0, stream>>>(Ph, Qh, Pgb, Qgb);
    k_scan_p2b<<<NREC * 16 / 256, 256, 0, stream>>>(Pgb, Qgb);
    k_scan_p2c<<<4 * NGRP * DI * 2 / 256, 256, 0, stream>>>(Ph, Qh, Qgb);
    k_scan_p3<<<NREC * NCH / 256, 256, 0, stream>>>(DBLF, DBLB, XSF, XSB, XZF, XZB,
                                                    fWdt, fbdt, bWdt, bbdt,
                                                    A2tab, fD, bD, Qh,
                                                    YSFbf, YSBbf);
    // 10. out-projection (dual-A MFMA, f32 channel-last YO)
    mfma_out<<<dim3(128, 2), 256, 0, stream>>>(YSFbf, YSBbf, WoutB, YO, NPOS, DIM, DI, DIM);
    // 11. residual + LN (LDS-tiled, LN1 recomputed inline)
    k_mid_t<<<NPOS / TP, 256, 0, stream>>>(x, YO, gamma1, ln1w, ln1b, XMID, XM2cl);
    // 12. msff in-projection (MFMA, bf16 channel-last H)
    mfma_nt<<<dim3(128, 9), 256, 0, stream>>>(XM2cl, mwinB, Hcl, NPOS, 576, DIM, 576);
    // 13. fused dilated dwconvs + GELU gate (vectorized)
    k_msff_v<<<NPOS * 24 / 256, 256, 0, stream>>>(Hcl, MDWT, Gcl);
    // 14. msff out-projection + fused final residual -> out
    mfma_msffout<<<dim3(2, 128), 256, 0, stream>>>(mwoutB, Gcl, XMID, gamma2, out, DIM, HID);
}